// Round 10
// baseline (304.734 us; speedup 1.0000x reference)
//
#include <hip/hip_runtime.h>
#include <hip/hip_bf16.h>

#define L_SEQ  2048
#define NBATCH 2
#define DMODEL 1024
#define DINNER 2048
#define DSTATE 16
#define DTRANK 64
#define MROWS  (L_SEQ * NBATCH)   // 4096
#define NCHUNK 64
#define LCHUNK 32                 // L_SEQ / NCHUNK
#define LOG2E  1.44269504f

using bf16 = __hip_bfloat16;
typedef short s16x8 __attribute__((ext_vector_type(8)));   // 8 bf16 = 16B
typedef float f32x4 __attribute__((ext_vector_type(4)));
typedef float f32x2 __attribute__((ext_vector_type(2)));   // v_pk_*_f32

__device__ __forceinline__ void gload_lds16(const bf16* g, bf16* l) {
    __builtin_amdgcn_global_load_lds(
        (const __attribute__((address_space(1))) void*)g,
        (__attribute__((address_space(3))) void*)l, 16, 0, 0);
}

__device__ __forceinline__ float bf2f(short v) {
    return __uint_as_float(((unsigned)(unsigned short)v) << 16);
}

// ---------------------------------------------------------------------------
// 256x256 8-phase MFMA GEMM (T2 swizzle + T3/T4 counted vmcnt + T5 setprio),
// fragment reuse: quadrant order (0,0)->(0,1)->(1,1)->(1,0), 24 ds_read_b128
// per wave per K-tile. C(M,N) = A(M,K) @ Bt(N,K)^T, bf16 in/out, fp32 acc.
// ---------------------------------------------------------------------------
__global__ __launch_bounds__(512, 2)
void gemm256(const bf16* __restrict__ A, const bf16* __restrict__ Bt,
             bf16* __restrict__ C, int N, int K, int lda, int ldb)
{
    __shared__ __align__(16) bf16 As[2][256 * 64];
    __shared__ __align__(16) bf16 Bs[2][256 * 64];

    const int tid  = threadIdx.x;
    const int wid  = tid >> 6;
    const int lane = tid & 63;
    const int wr = wid >> 2, wc = wid & 3;       // 2x4 wave grid
    const int fr = lane & 15, fk = lane >> 4;

    const int nbx = gridDim.x;
    const int nwg = nbx * gridDim.y;
    int id = blockIdx.y * nbx + blockIdx.x;
    int cpx = nwg >> 3;
    id = (id & 7) * cpx + (id >> 3);
    const long bm = (long)(id / nbx) * 256;
    const long bn = (long)(id % nbx) * 256;

    const int q0 = tid, q1 = tid + 512;
    const int r0 = q0 >> 3, r1 = q1 >> 3;
    const int c0 = ((q0 & 7) ^ (r0 & 7)) << 3;
    const int c1 = ((q1 & 7) ^ (r1 & 7)) << 3;
    const bf16* sA0h0 = A  + (bm + r0)       * (long)lda + c0;
    const bf16* sA1h0 = A  + (bm + r1)       * (long)lda + c1;
    const bf16* sA0h1 = A  + (bm + 128 + r0) * (long)lda + c0;
    const bf16* sA1h1 = A  + (bm + 128 + r1) * (long)lda + c1;
    const bf16* sB0h0 = Bt + (bn + r0)       * (long)ldb + c0;
    const bf16* sB1h0 = Bt + (bn + r1)       * (long)ldb + c1;
    const bf16* sB0h1 = Bt + (bn + 128 + r0) * (long)ldb + c0;
    const bf16* sB1h1 = Bt + (bn + 128 + r1) * (long)ldb + c1;
    const int dst0 = wid * 512;
    const int dst1 = 4096 + wid * 512;

    const int o0   = ((fk ^ (fr & 7)) << 3);
    const int o1   = o0 ^ 32;
    const int rA64 = (wr * 64 + fr) * 64;
    const int rB64 = (wc * 32 + fr) * 64;

    f32x4 acc[8][4] = {};
    s16x8 af[4][2], bf0[2][2], bf1[2][2];
    const int nt = K >> 6;

#define STAGE(ARR, BUF, H, P0, P1) do {                    \
        gload_lds16(P0, &ARR[BUF][(H) * 8192 + dst0]);     \
        gload_lds16(P1, &ARR[BUF][(H) * 8192 + dst1]);     \
        P0 += 64; P1 += 64;                                \
    } while (0)

#define LOADA(MH, CUR) do {                                   \
        const bf16* ab = &As[CUR][rA64 + (MH) * 8192];        \
        _Pragma("unroll") for (int m = 0; m < 4; ++m) {       \
            af[m][0] = *(const s16x8*)&ab[m * 1024 + o0];     \
            af[m][1] = *(const s16x8*)&ab[m * 1024 + o1]; }   \
    } while (0)

#define LOADB(NH, CUR, BF) do {                               \
        const bf16* bb = &Bs[CUR][rB64 + (NH) * 8192];        \
        _Pragma("unroll") for (int n = 0; n < 2; ++n) {       \
            BF[n][0] = *(const s16x8*)&bb[n * 1024 + o0];     \
            BF[n][1] = *(const s16x8*)&bb[n * 1024 + o1]; }   \
    } while (0)

#define MFMAQ(MH, NH, BF) do {                                               \
        __builtin_amdgcn_s_setprio(1);                                       \
        _Pragma("unroll") for (int ks = 0; ks < 2; ++ks)                     \
        _Pragma("unroll") for (int m = 0; m < 4; ++m)                        \
        _Pragma("unroll") for (int n = 0; n < 2; ++n)                        \
            acc[(MH) * 4 + m][(NH) * 2 + n] =                                \
                __builtin_amdgcn_mfma_f32_16x16x32_bf16(                     \
                    af[m][ks], BF[n][ks], acc[(MH) * 4 + m][(NH) * 2 + n],   \
                    0, 0, 0);                                                \
        __builtin_amdgcn_s_setprio(0);                                       \
    } while (0)

#define WB(NV) asm volatile("s_waitcnt vmcnt(" #NV ")\n\ts_barrier" ::: "memory")

    STAGE(As, 0, 0, sA0h0, sA1h0);
    STAGE(Bs, 0, 0, sB0h0, sB1h0);
    STAGE(Bs, 0, 1, sB0h1, sB1h1);
    STAGE(As, 0, 1, sA0h1, sA1h1);
    WB(4);                                   // A-h0, B-h0 ready

    int cur = 0;
    for (int t = 0; t < nt - 1; ++t) {
        STAGE(As, cur ^ 1, 0, sA0h0, sA1h0);
        LOADA(0, cur); LOADB(0, cur, bf0);
        MFMAQ(0, 0, bf0);  WB(4);            // B-h1 ready
        STAGE(Bs, cur ^ 1, 0, sB0h0, sB1h0);
        LOADB(1, cur, bf1);
        MFMAQ(0, 1, bf1);  WB(4);            // A-h1 ready
        STAGE(Bs, cur ^ 1, 1, sB0h1, sB1h1);
        LOADA(1, cur);
        MFMAQ(1, 1, bf1);                    // no wait
        STAGE(As, cur ^ 1, 1, sA0h1, sA1h1);
        MFMAQ(1, 0, bf0);  WB(4);            // next A-h0, B-h0 ready
        cur ^= 1;
    }
    LOADA(0, cur); LOADB(0, cur, bf0);
    MFMAQ(0, 0, bf0);  WB(2);
    LOADB(1, cur, bf1);
    MFMAQ(0, 1, bf1);  WB(0);
    LOADA(1, cur);
    MFMAQ(1, 1, bf1);
    MFMAQ(1, 0, bf0);

#undef STAGE
#undef LOADA
#undef LOADB
#undef MFMAQ
#undef WB

    #pragma unroll
    for (int mh = 0; mh < 2; ++mh)
    #pragma unroll
    for (int m = 0; m < 4; ++m)
    #pragma unroll
    for (int nh = 0; nh < 2; ++nh)
    #pragma unroll
    for (int n = 0; n < 2; ++n) {
        f32x4 v = acc[mh * 4 + m][nh * 2 + n];
        long row0 = bm + wr * 64 + mh * 128 + m * 16 + fk * 4;
        long col  = bn + wc * 32 + nh * 128 + n * 16 + fr;
        #pragma unroll
        for (int j = 0; j < 4; ++j)
            C[(row0 + j) * N + col] = __float2bfloat16(v[j]);
    }
}

// ---------------------------------------------------------------------------
// MFMA bf16 GEMM: 128x128 tile, BK=32, 2-phase double-buffered (small shapes).
// ---------------------------------------------------------------------------
template<typename OutT, int EPI, bool SPLITK = false>
__global__ __launch_bounds__(256)
void gemm_bt(const bf16* __restrict__ A, const bf16* __restrict__ Bt,
             OutT* __restrict__ C, const float* __restrict__ bias,
             int M, int N, int K, int lda, int ldb)
{
    __shared__ __align__(16) bf16 As[2][128 * 32];
    __shared__ __align__(16) bf16 Bs[2][128 * 32];

    const int tid  = threadIdx.x;
    const int wave = tid >> 6;
    const int lane = tid & 63;
    const int wr = wave >> 1, wc = wave & 1;
    const int fr = lane & 15, fk = lane >> 4;

    const int nbx = gridDim.x;
    const int nwg = nbx * gridDim.y;
    int id  = blockIdx.y * nbx + blockIdx.x;
    if (nwg >= 8) {
        int cpx = nwg >> 3;
        id = (id & 7) * cpx + (id >> 3);
    }
    const int bxi = id % nbx, byi = id / nbx;
    const long bm = (long)byi * 128;
    const long bn = (long)bxi * 128;

    if constexpr (SPLITK) {
        long ko = (long)blockIdx.z * K;
        A  += ko;
        Bt += ko;
        C  += (size_t)blockIdx.z * M * N;
    }

    const int r0 = tid >> 2,         c0 = (tid & 3) << 3;
    const int r1 = (256 + tid) >> 2, c1 = c0;
    const bf16* pA0 = A  + (bm + r0) * (long)lda + c0;
    const bf16* pA1 = A  + (bm + r1) * (long)lda + c1;
    const bf16* pB0 = Bt + (bn + r0) * (long)ldb + c0;
    const bf16* pB1 = Bt + (bn + r1) * (long)ldb + c1;
    const size_t ld0 = (size_t)(wave * 64) * 8;
    const size_t ld1 = (size_t)(256 + wave * 64) * 8;

    f32x4 acc[4][4] = {};
    const int nt = K >> 5;

    gload_lds16(pA0, &As[0][ld0]);
    gload_lds16(pB0, &Bs[0][ld0]);
    gload_lds16(pA1, &As[0][ld1]);
    gload_lds16(pB1, &Bs[0][ld1]);
    pA0 += 32; pA1 += 32; pB0 += 32; pB1 += 32;
    __syncthreads();

    int cur = 0;
    for (int t = 0; t < nt; ++t) {
        if (t + 1 < nt) {
            gload_lds16(pA0, &As[cur ^ 1][ld0]);
            gload_lds16(pB0, &Bs[cur ^ 1][ld0]);
            gload_lds16(pA1, &As[cur ^ 1][ld1]);
            gload_lds16(pB1, &Bs[cur ^ 1][ld1]);
            pA0 += 32; pA1 += 32; pB0 += 32; pB1 += 32;
        }

        s16x8 afrag[4], bfrag[4];
        #pragma unroll
        for (int m = 0; m < 4; ++m)
            afrag[m] = *(const s16x8*)&As[cur][(wr * 64 + m * 16 + fr) * 32 + fk * 8];
        #pragma unroll
        for (int n = 0; n < 4; ++n)
            bfrag[n] = *(const s16x8*)&Bs[cur][(wc * 64 + n * 16 + fr) * 32 + fk * 8];

        #pragma unroll
        for (int m = 0; m < 4; ++m)
            #pragma unroll
            for (int n = 0; n < 4; ++n)
                acc[m][n] = __builtin_amdgcn_mfma_f32_16x16x32_bf16(
                    afrag[m], bfrag[n], acc[m][n], 0, 0, 0);

        __syncthreads();
        cur ^= 1;
    }

    #pragma unroll
    for (int m = 0; m < 4; ++m)
        #pragma unroll
        for (int n = 0; n < 4; ++n) {
            f32x4 v = acc[m][n];
            long row0 = bm + wr * 64 + m * 16 + fk * 4;
            long col  = bn + wc * 64 + n * 16 + fr;
            #pragma unroll
            for (int j = 0; j < 4; ++j) {
                float val = v[j];
                if (EPI == 1) {
                    val += bias[col];
                    val = (val > 20.f) ? val : log1pf(__expf(val));
                }
                if constexpr (sizeof(OutT) == 2)
                    C[(row0 + j) * N + col] = __float2bfloat16(val);
                else
                    C[(row0 + j) * N + col] = val;
            }
        }
}

// ---------------------------------------------------------------------------
__global__ void transpose_bf16(const float* __restrict__ in, bf16* __restrict__ out,
                               int R, int C, int Cpad)
{
    __shared__ float tile[32][33];
    int cb = blockIdx.x * 32, rb = blockIdx.y * 32;
    int tx = threadIdx.x, ty = threadIdx.y;
    #pragma unroll
    for (int i = 0; i < 4; ++i) {
        int r = rb + ty + i * 8, c = cb + tx;
        tile[ty + i * 8][tx] = (r < R && c < C) ? in[(long)r * C + c] : 0.f;
    }
    __syncthreads();
    #pragma unroll
    for (int i = 0; i < 4; ++i) {
        int oc = cb + ty + i * 8;
        int orow = rb + tx;
        if (oc < Cpad && orow < R)
            out[(long)oc * R + orow] = __float2bfloat16(tile[tx][ty + i * 8]);
    }
}

__global__ void convert_x_kernel(const float* __restrict__ x, bf16* __restrict__ Xb)
{
    int idx = blockIdx.x * 256 + threadIdx.x;
    int c   = idx & (DMODEL - 1);
    int row = idx >> 10;
    int l   = row & (L_SEQ - 1);
    int b   = row >> 11;
    Xb[idx] = __float2bfloat16(x[((l * NBATCH + b) << 10) | c]);
}

// depthwise causal conv (d_conv=4) + silu, 8 channels per thread (vectorized)
__global__ void conv_silu_kernel(const bf16* __restrict__ xr, const float* __restrict__ Wc,
                                 const float* __restrict__ bc, bf16* __restrict__ u)
{
    int idx = blockIdx.x * 256 + threadIdx.x;   // MROWS*DINNER/8 threads
    int g   = idx & 255;
    int row = idx >> 8;
    int c   = g << 3;
    int l   = row & (L_SEQ - 1);

    float acc[8];
    f32x4 bi0 = *(const f32x4*)(bc + c);
    f32x4 bi1 = *(const f32x4*)(bc + c + 4);
    #pragma unroll
    for (int j = 0; j < 4; ++j) { acc[j] = bi0[j]; acc[4 + j] = bi1[j]; }

    f32x4 w[8];
    #pragma unroll
    for (int j = 0; j < 8; ++j) w[j] = *(const f32x4*)(Wc + (c + j) * 4);

    #pragma unroll
    for (int t = 0; t < 4; ++t) {
        int ll = l - 3 + t;
        if (ll >= 0) {
            s16x8 v = *(const s16x8*)(xr + (long)(row - 3 + t) * 4096 + c);
            #pragma unroll
            for (int j = 0; j < 8; ++j)
                acc[j] += bf2f(v[j]) * w[j][t];
        }
    }
    s16x8 o;
    #pragma unroll
    for (int j = 0; j < 8; ++j) {
        float a = acc[j];
        float s = a / (1.f + __builtin_amdgcn_exp2f(-LOG2E * a));
        bf16 h = __float2bfloat16(s);
        o[j] = *(short*)&h;
    }
    *(s16x8*)(u + (long)row * DINNER + c) = o;
}

__global__ void reduce_xdbl(const float* __restrict__ part, float* __restrict__ xdbl,
                            bf16* __restrict__ drbf)
{
    int idx = blockIdx.x * 256 + threadIdx.x;
    const size_t stride = (size_t)MROWS * 128;
    float v = part[idx] + part[idx + stride] + part[idx + 2 * stride]
            + part[idx + 3 * stride];
    xdbl[idx] = v;
    int col = idx & 127;
    if (col < 64)
        drbf[(idx >> 7) * 64 + col] = __float2bfloat16(v);
}

__global__ void reduce_out(const float* __restrict__ part, float* __restrict__ out)
{
    int i = blockIdx.x * 256 + threadIdx.x;
    f32x4 a = ((const f32x4*)part)[i];
    f32x4 b = ((const f32x4*)(part + (size_t)MROWS * DMODEL))[i];
    ((f32x4*)out)[i] = a + b;
}

// ---------------------------------------------------------------------------
// Chunked parallel selective scan — 2 threads per (channel, chunk), 8 states
// each, f32x2 packed math (v_pk_fma_f32). delta is bf16. FAST PATH (runtime-
// checked): A[d][n] = -(n+1) => decays are powers of exp(-dl).
// ---------------------------------------------------------------------------
__global__ __launch_bounds__(256)
void scan_phase1(const bf16* __restrict__ delta, const bf16* __restrict__ u,
                 const float* __restrict__ xdbl, const float* __restrict__ A_log,
                 float* __restrict__ AS)
{
    const int idx   = blockIdx.x * 256 + threadIdx.x;
    const int half  = idx & 1;
    const int ch    = idx >> 1;
    const int chunk = blockIdx.y;
    const int d     = ch & (DINNER - 1);
    const int b     = ch >> 11;
    const int n0    = half * 8;

    float A2[8];
    const f32x4* Arow = (const f32x4*)(A_log + d * DSTATE + n0);
    #pragma unroll
    for (int q = 0; q < 2; ++q) {
        f32x4 v = Arow[q];
        #pragma unroll
        for (int j = 0; j < 4; ++j) A2[q * 4 + j] = -__expf(v[j]) * LOG2E;
    }
    f32x2 s01 = {0.f, 0.f}, s23 = {0.f, 0.f}, s45 = {0.f, 0.f}, s67 = {0.f, 0.f};
    float sdl = 0.f;

    bool fastA = true;
    #pragma unroll
    for (int j = 0; j < 8; ++j)
        fastA &= fabsf(A2[j] + (float)(n0 + j + 1) * LOG2E)
                 < 0.01f * (float)(n0 + j + 1);

    const long row0 = (long)b * L_SEQ + chunk * LCHUNK;
    const bf16*  pD = delta + row0 * DINNER + d;
    const bf16*  pU = u     + row0 * DINNER + d;
    const f32x4* pB = (const f32x4*)(xdbl + row0 * 128 + 64 + n0);

    if (fastA) {
        #pragma unroll 4
        for (int l = 0; l < LCHUNK; ++l) {
            float dl = __bfloat162float(*pD);
            float uv = __bfloat162float(*pU);
            f32x4 B0 = pB[0], B1 = pB[1];
            pD += DINNER; pU += DINNER; pB += 32;
            float dbu = dl * uv;
            sdl += dl;
            float b1 = __builtin_amdgcn_exp2f(-LOG2E * dl);   // exp(-dl)
            float b2 = b1 * b1;
            f32x2 bb  = {b2, b2};
            f32x2 e01 = {b1, b2};
            f32x2 e23 = e01 * bb;
            f32x2 e45 = e23 * bb;
            f32x2 e67 = e45 * bb;
            float pr  = half ? e67.y : 1.f;
            f32x2 pr2 = {pr, pr};
            e01 *= pr2; e23 *= pr2; e45 *= pr2; e67 *= pr2;
            f32x2 db = {dbu, dbu};
            s01 = e01 * s01 + db * (f32x2){B0[0], B0[1]};
            s23 = e23 * s23 + db * (f32x2){B0[2], B0[3]};
            s45 = e45 * s45 + db * (f32x2){B1[0], B1[1]};
            s67 = e67 * s67 + db * (f32x2){B1[2], B1[3]};
        }
    } else {
        #pragma unroll 4
        for (int l = 0; l < LCHUNK; ++l) {
            float dl = __bfloat162float(*pD);
            float uv = __bfloat162float(*pU);
            f32x4 B0 = pB[0], B1 = pB[1];
            pD += DINNER; pU += DINNER; pB += 32;
            float dbu = dl * uv;
            sdl += dl;
            f32x2 db = {dbu, dbu};
            f32x2 e01 = {__builtin_amdgcn_exp2f(dl * A2[0]),
                         __builtin_amdgcn_exp2f(dl * A2[1])};
            f32x2 e23 = {__builtin_amdgcn_exp2f(dl * A2[2]),
                         __builtin_amdgcn_exp2f(dl * A2[3])};
            f32x2 e45 = {__builtin_amdgcn_exp2f(dl * A2[4]),
                         __builtin_amdgcn_exp2f(dl * A2[5])};
            f32x2 e67 = {__builtin_amdgcn_exp2f(dl * A2[6]),
                         __builtin_amdgcn_exp2f(dl * A2[7])};
            s01 = e01 * s01 + db * (f32x2){B0[0], B0[1]};
            s23 = e23 * s23 + db * (f32x2){B0[2], B0[3]};
            s45 = e45 * s45 + db * (f32x2){B1[0], B1[1]};
            s67 = e67 * s67 + db * (f32x2){B1[2], B1[3]};
        }
    }
    float ap[8];
    #pragma unroll
    for (int n = 0; n < 8; ++n) ap[n] = __builtin_amdgcn_exp2f(sdl * A2[n]);

    float* o = AS + ((size_t)chunk * 4096 + ch) * 32 + n0;
    *(f32x4*)(o)      = *(f32x4*)&ap[0];
    *(f32x4*)(o + 4)  = *(f32x4*)&ap[4];
    *(f32x4*)(o + 16) = (f32x4){s01.x, s01.y, s23.x, s23.y};
    *(f32x4*)(o + 20) = (f32x4){s45.x, s45.y, s67.x, s67.y};
}

__global__ __launch_bounds__(256)
void scan_phase2(float* __restrict__ AS)
{
    const int idx = blockIdx.x * 256 + threadIdx.x;
    const int n   = idx & 15;
    const int ch  = idx >> 4;

    float s = 0.f;
    for (int cb = 0; cb < NCHUNK; cb += 16) {
        float av[16], sv[16];
        #pragma unroll
        for (int j = 0; j < 16; ++j) {
            size_t r = ((size_t)(cb + j) * 4096 + ch) * 32 + n;
            av[j] = AS[r];
            sv[j] = AS[r + 16];
        }
        #pragma unroll
        for (int j = 0; j < 16; ++j) {
            AS[((size_t)(cb + j) * 4096 + ch) * 32 + 16 + n] = s;
            s = av[j] * s + sv[j];
        }
    }
}

__global__ __launch_bounds__(256)
void scan_phase3(const bf16* __restrict__ delta, const bf16* __restrict__ u,
                 const float* __restrict__ xdbl, const bf16* __restrict__ xr,
                 const float* __restrict__ AS, const float* __restrict__ A_log,
                 const float* __restrict__ Dp, bf16* __restrict__ ybf)
{
    const int idx   = blockIdx.x * 256 + threadIdx.x;
    const int half  = idx & 1;
    const int ch    = idx >> 1;
    const int chunk = blockIdx.y;
    const int d     = ch & (DINNER - 1);
    const int b     = ch >> 11;
    const int n0    = half * 8;

    float A2[8];
    const f32x4* Arow = (const f32x4*)(A_log + d * DSTATE + n0);
    #pragma unroll
    for (int q = 0; q < 2; ++q) {
        f32x4 v = Arow[q];
        #pragma unroll
        for (int j = 0; j < 4; ++j) A2[q * 4 + j] = -__expf(v[j]) * LOG2E;
    }
    const float* ip = AS + ((size_t)chunk * 4096 + ch) * 32 + 16 + n0;
    f32x4 i0 = *(const f32x4*)(ip);
    f32x4 i1 = *(const f32x4*)(ip + 4);
    f32x2 s01 = {i0[0], i0[1]}, s23 = {i0[2], i0[3]};
    f32x2 s45 = {i1[0], i1[1]}, s67 = {i1[2], i1[3]};

    bool fastA = true;
    #pragma unroll
    for (int j = 0; j < 8; ++j)
        fastA &= fabsf(A2[j] + (float)(n0 + j + 1) * LOG2E)
                 < 0.01f * (float)(n0 + j + 1);

    const float Dd  = Dp[d];
    const long row0 = (long)b * L_SEQ + chunk * LCHUNK;

    const bf16*  pD = delta + row0 * DINNER + d;
    const bf16*  pU = u     + row0 * DINNER + d;
    const bf16*  pR = xr    + row0 * 4096 + 2048 + d;
    const f32x4* pB = (const f32x4*)(xdbl + row0 * 128 + 64 + n0);
    bf16*        pY = ybf   + row0 * DINNER + d;

    if (fastA) {
        #pragma unroll 4
        for (int l = 0; l < LCHUNK; ++l) {
            float dl = __bfloat162float(*pD);
            float uv = __bfloat162float(*pU);
            float rs = __bfloat162float(*pR);
            f32x4 B0 = pB[0], B1 = pB[1];
            f32x4 C0 = pB[4], C1 = pB[5];
            pD += DINNER; pU += DINNER; pR += 4096; pB += 32;
            float dbu = dl * uv;
            float b1 = __builtin_amdgcn_exp2f(-LOG2E * dl);   // exp(-dl)
            float b2 = b1 * b1;
            f32x2 bb  = {b2, b2};
            f32x2 e01 = {b1, b2};
            f32x2 e23 = e01 * bb;
            f32x2 e45 = e23 * bb;
            f32x2 e67 = e45 * bb;
            float pr  = half ? e67.y : 1.f;
            f32x2 pr2 = {pr, pr};
            e01 *= pr2; e23 *= pr2; e45 *= pr2; e67 *= pr2;
            f32x2 db = {dbu, dbu};
            s01 = e01 * s01 + db * (f32x2){B0[0], B0[1]};
            s23 = e23 * s23 + db * (f32x2){B0[2], B0[3]};
            s45 = e45 * s45 + db * (f32x2){B1[0], B1[1]};
            s67 = e67 * s67 + db * (f32x2){B1[2], B1[3]};
            f32x2 y2 = s01 * (f32x2){C0[0], C0[1]};
            y2 = s23 * (f32x2){C0[2], C0[3]} + y2;
            y2 = s45 * (f32x2){C1[0], C1[1]} + y2;
            y2 = s67 * (f32x2){C1[2], C1[3]} + y2;
            float yh = y2.x + y2.y;
            float yt = yh + __shfl_xor(yh, 1);
            if (half == 0) {
                float yf = yt + uv * Dd;
                yf *= rs / (1.f + __builtin_amdgcn_exp2f(-LOG2E * rs));
                *pY = __float2bfloat16(yf);
            }
            pY += DINNER;
        }
    } else {
        #pragma unroll 4
        for (int l = 0; l < LCHUNK; ++l) {
            float dl = __bfloat162float(*pD);
            float uv = __bfloat162float(*pU);
            float rs = __bfloat162float(*pR);
            f32x4 B0 = pB[0], B1 = pB[1];
            f32x4 C0 = pB[4], C1 = pB[5];
            pD += DINNER; pU += DINNER; pR += 4096; pB += 32;
            float dbu = dl * uv;
            f32x2 db = {dbu, dbu};
            f32x2 e01 = {__builtin_amdgcn_exp2f(dl * A2[0]),
                         __builtin_amdgcn_exp2f(dl * A2[1])};
            f32x2 e23 = {__builtin_amdgcn_exp2f(dl * A2[2]),
                         __builtin_amdgcn_exp2f(dl * A2[3])};
            f32x2 e45 = {__builtin_amdgcn_exp2f(dl * A2[4]),
                         __builtin_amdgcn_exp2f(dl * A2[5])};
            f32x2 e67 = {__builtin_amdgcn_exp2f(dl * A2[6]),
                         __builtin_amdgcn_exp2f(dl * A2[7])};
            s01 = e01 * s01 + db * (f32x2){B0[0], B0[1]};
            s23 = e23 * s23 + db * (f32x2){B0[2], B0[3]};
            s45 = e45 * s45 + db * (f32x2){B1[0], B1[1]};
            s67 = e67 * s67 + db * (f32x2){B1[2], B1[3]};
            f32x2 y2 = s01 * (f32x2){C0[0], C0[1]};
            y2 = s23 * (f32x2){C0[2], C0[3]} + y2;
            y2 = s45 * (f32x2){C1[0], C1[1]} + y2;
            y2 = s67 * (f32x2){C1[2], C1[3]} + y2;
            float yh = y2.x + y2.y;
            float yt = yh + __shfl_xor(yh, 1);
            if (half == 0) {
                float yf = yt + uv * Dd;
                yf *= rs / (1.f + __builtin_amdgcn_exp2f(-LOG2E * rs));
                *pY = __float2bfloat16(yf);
            }
            pY += DINNER;
        }
    }
}

// ---------------------------------------------------------------------------
extern "C" void kernel_launch(void* const* d_in, const int* in_sizes, int n_in,
                              void* d_out, int out_size, void* d_ws, size_t ws_size,
                              hipStream_t stream)
{
    const float* x      = (const float*)d_in[0];
    const float* W_in   = (const float*)d_in[1];
    const float* W_conv = (const float*)d_in[2];
    const float* b_conv = (const float*)d_in[3];
    const float* W_x    = (const float*)d_in[4];
    const float* W_dt   = (const float*)d_in[5];
    const float* b_dt   = (const float*)d_in[6];
    const float* A_log  = (const float*)d_in[7];
    const float* Dp     = (const float*)d_in[8];
    const float* W_out  = (const float*)d_in[9];
    float* out = (float*)d_out;

    char* ws = (char*)d_ws;
    size_t off = 0;
    auto alloc = [&](size_t bytes) {
        void* p = ws + off;
        off = (off + bytes + 255) & ~(size_t)255;
        return p;
    };
    bf16*  Xb    = (bf16*) alloc((size_t)MROWS * DMODEL * 2);
    bf16*  WinT  = (bf16*) alloc((size_t)4096  * DMODEL * 2);
    bf16*  xr    = (bf16*) alloc((size_t)MROWS * 4096  * 2);
    bf16*  ubf   = (bf16*) alloc((size_t)MROWS * DINNER * 2);
    bf16*  WxT   = (bf16*) alloc((size_t)128   * DINNER * 2);
    float* xdbl  = (float*)alloc((size_t)MROWS * 128 * 4);
    float* xdblp = (float*)alloc((size_t)4 * MROWS * 128 * 4);
    bf16*  drbf  = (bf16*) alloc((size_t)MROWS * 64 * 2);
    bf16*  WdtT  = (bf16*) alloc((size_t)DINNER * 64 * 2);
    bf16*  delta = (bf16*) alloc((size_t)MROWS * DINNER * 2);   // bf16 now
    bf16*  ybf   = (bf16*) alloc((size_t)MROWS * DINNER * 2);
    bf16*  WoutT = (bf16*) alloc((size_t)DMODEL * DINNER * 2);
    float* AS    = (float*)alloc((size_t)NCHUNK * 4096 * 32 * 4); // 32MB; reused
                                                                  // as GEMM4 partials

    dim3 tb(32, 8);
    transpose_bf16<<<dim3(128, 32), tb, 0, stream>>>(W_in,  WinT,  1024, 4096, 4096);
    transpose_bf16<<<dim3(4, 64),   tb, 0, stream>>>(W_x,   WxT,   2048, 96,   128);
    transpose_bf16<<<dim3(64, 2),   tb, 0, stream>>>(W_dt,  WdtT,  64,   2048, 2048);
    transpose_bf16<<<dim3(32, 64),  tb, 0, stream>>>(W_out, WoutT, 2048, 1024, 1024);
    convert_x_kernel<<<(MROWS * DMODEL) / 256, 256, 0, stream>>>(x, Xb);

    // GEMM1: x_and_res = Xb @ W_in -> xr bf16 (4096,4096) — 256² 8-phase
    gemm256<<<dim3(4096 / 256, MROWS / 256), 512, 0, stream>>>(
        Xb, WinT, xr, 4096, 1024, 1024, 1024);
    // conv + silu -> u bf16 (vectorized, 8 ch/thread)
    conv_silu_kernel<<<(MROWS * DINNER / 8) / 256, 256, 0, stream>>>(
        xr, W_conv, b_conv, ubf);
    // GEMM2: x_dbl = u @ W_x, split-K x4 -> partials
    gemm_bt<float, 0, true><<<dim3(1, MROWS / 128, 4), 256, 0, stream>>>(
        ubf, WxT, xdblp, nullptr, MROWS, 128, 512, 2048, 2048);
    reduce_xdbl<<<(MROWS * 128) / 256, 256, 0, stream>>>(xdblp, xdbl, drbf);
    // GEMM3: delta = softplus(delta_r @ W_dt + b_dt) -> bf16
    gemm_bt<bf16, 1><<<dim3(DINNER / 128, MROWS / 128), 256, 0, stream>>>(
        drbf, WdtT, delta, b_dt, MROWS, DINNER, 64, 64, 64);
    // chunked parallel selective scan -> ybf bf16
    scan_phase1<<<dim3(32, NCHUNK), 256, 0, stream>>>(delta, ubf, xdbl, A_log, AS);
    scan_phase2<<<256, 256, 0, stream>>>(AS);
    scan_phase3<<<dim3(32, NCHUNK), 256, 0, stream>>>(delta, ubf, xdbl, xr, AS,
                                                      A_log, Dp, ybf);
    // GEMM4: out = y @ W_out, split-K x2 into AS (free after scan), then reduce
    gemm_bt<float, 0, true><<<dim3(DMODEL / 128, MROWS / 128, 2), 256, 0, stream>>>(
        ybf, WoutT, (float*)AS, nullptr, MROWS, DMODEL, 1024, 2048, 2048);
    reduce_out<<<(MROWS * DMODEL) / 1024, 256, 0, stream>>>((float*)AS, out);
}

// Round 11
// 288.171 us; speedup vs baseline: 1.0575x; 1.0575x over previous
//
#include <hip/hip_runtime.h>
#include <hip/hip_bf16.h>

#define L_SEQ  2048
#define NBATCH 2
#define DMODEL 1024
#define DINNER 2048
#define DSTATE 16
#define DTRANK 64
#define MROWS  (L_SEQ * NBATCH)   // 4096
#define NCHUNK 64
#define LCHUNK 32                 // L_SEQ / NCHUNK
#define LOG2E  1.44269504f

using bf16 = __hip_bfloat16;
typedef short s16x8 __attribute__((ext_vector_type(8)));   // 8 bf16 = 16B
typedef float f32x4 __attribute__((ext_vector_type(4)));

__device__ __forceinline__ void gload_lds16(const bf16* g, bf16* l) {
    __builtin_amdgcn_global_load_lds(
        (const __attribute__((address_space(1))) void*)g,
        (__attribute__((address_space(3))) void*)l, 16, 0, 0);
}

__device__ __forceinline__ float bf2f(short v) {
    return __uint_as_float(((unsigned)(unsigned short)v) << 16);
}

// ---------------------------------------------------------------------------
// 256x256 8-phase MFMA GEMM (T2 swizzle + T3/T4 counted vmcnt + T5 setprio),
// fragment reuse: quadrant order (0,0)->(0,1)->(1,1)->(1,0), 24 ds_read_b128
// per wave per K-tile. C(M,N) = A(M,K) @ Bt(N,K)^T, bf16 in/out, fp32 acc.
// ---------------------------------------------------------------------------
__global__ __launch_bounds__(512, 2)
void gemm256(const bf16* __restrict__ A, const bf16* __restrict__ Bt,
             bf16* __restrict__ C, int N, int K, int lda, int ldb)
{
    __shared__ __align__(16) bf16 As[2][256 * 64];
    __shared__ __align__(16) bf16 Bs[2][256 * 64];

    const int tid  = threadIdx.x;
    const int wid  = tid >> 6;
    const int lane = tid & 63;
    const int wr = wid >> 2, wc = wid & 3;       // 2x4 wave grid
    const int fr = lane & 15, fk = lane >> 4;

    const int nbx = gridDim.x;
    const int nwg = nbx * gridDim.y;
    int id = blockIdx.y * nbx + blockIdx.x;
    int cpx = nwg >> 3;
    id = (id & 7) * cpx + (id >> 3);
    const long bm = (long)(id / nbx) * 256;
    const long bn = (long)(id % nbx) * 256;

    const int q0 = tid, q1 = tid + 512;
    const int r0 = q0 >> 3, r1 = q1 >> 3;
    const int c0 = ((q0 & 7) ^ (r0 & 7)) << 3;
    const int c1 = ((q1 & 7) ^ (r1 & 7)) << 3;
    const bf16* sA0h0 = A  + (bm + r0)       * (long)lda + c0;
    const bf16* sA1h0 = A  + (bm + r1)       * (long)lda + c1;
    const bf16* sA0h1 = A  + (bm + 128 + r0) * (long)lda + c0;
    const bf16* sA1h1 = A  + (bm + 128 + r1) * (long)lda + c1;
    const bf16* sB0h0 = Bt + (bn + r0)       * (long)ldb + c0;
    const bf16* sB1h0 = Bt + (bn + r1)       * (long)ldb + c1;
    const bf16* sB0h1 = Bt + (bn + 128 + r0) * (long)ldb + c0;
    const bf16* sB1h1 = Bt + (bn + 128 + r1) * (long)ldb + c1;
    const int dst0 = wid * 512;
    const int dst1 = 4096 + wid * 512;

    const int o0   = ((fk ^ (fr & 7)) << 3);
    const int o1   = o0 ^ 32;
    const int rA64 = (wr * 64 + fr) * 64;
    const int rB64 = (wc * 32 + fr) * 64;

    f32x4 acc[8][4] = {};
    s16x8 af[4][2], bf0[2][2], bf1[2][2];
    const int nt = K >> 6;

#define STAGE(ARR, BUF, H, P0, P1) do {                    \
        gload_lds16(P0, &ARR[BUF][(H) * 8192 + dst0]);     \
        gload_lds16(P1, &ARR[BUF][(H) * 8192 + dst1]);     \
        P0 += 64; P1 += 64;                                \
    } while (0)

#define LOADA(MH, CUR) do {                                   \
        const bf16* ab = &As[CUR][rA64 + (MH) * 8192];        \
        _Pragma("unroll") for (int m = 0; m < 4; ++m) {       \
            af[m][0] = *(const s16x8*)&ab[m * 1024 + o0];     \
            af[m][1] = *(const s16x8*)&ab[m * 1024 + o1]; }   \
    } while (0)

#define LOADB(NH, CUR, BF) do {                               \
        const bf16* bb = &Bs[CUR][rB64 + (NH) * 8192];        \
        _Pragma("unroll") for (int n = 0; n < 2; ++n) {       \
            BF[n][0] = *(const s16x8*)&bb[n * 1024 + o0];     \
            BF[n][1] = *(const s16x8*)&bb[n * 1024 + o1]; }   \
    } while (0)

#define MFMAQ(MH, NH, BF) do {                                               \
        __builtin_amdgcn_s_setprio(1);                                       \
        _Pragma("unroll") for (int ks = 0; ks < 2; ++ks)                     \
        _Pragma("unroll") for (int m = 0; m < 4; ++m)                        \
        _Pragma("unroll") for (int n = 0; n < 2; ++n)                        \
            acc[(MH) * 4 + m][(NH) * 2 + n] =                                \
                __builtin_amdgcn_mfma_f32_16x16x32_bf16(                     \
                    af[m][ks], BF[n][ks], acc[(MH) * 4 + m][(NH) * 2 + n],   \
                    0, 0, 0);                                                \
        __builtin_amdgcn_s_setprio(0);                                       \
    } while (0)

#define WB(NV) asm volatile("s_waitcnt vmcnt(" #NV ")\n\ts_barrier" ::: "memory")

    STAGE(As, 0, 0, sA0h0, sA1h0);
    STAGE(Bs, 0, 0, sB0h0, sB1h0);
    STAGE(Bs, 0, 1, sB0h1, sB1h1);
    STAGE(As, 0, 1, sA0h1, sA1h1);
    WB(4);                                   // A-h0, B-h0 ready

    int cur = 0;
    for (int t = 0; t < nt - 1; ++t) {
        STAGE(As, cur ^ 1, 0, sA0h0, sA1h0);
        LOADA(0, cur); LOADB(0, cur, bf0);
        MFMAQ(0, 0, bf0);  WB(4);            // B-h1 ready
        STAGE(Bs, cur ^ 1, 0, sB0h0, sB1h0);
        LOADB(1, cur, bf1);
        MFMAQ(0, 1, bf1);  WB(4);            // A-h1 ready
        STAGE(Bs, cur ^ 1, 1, sB0h1, sB1h1);
        LOADA(1, cur);
        MFMAQ(1, 1, bf1);                    // no wait
        STAGE(As, cur ^ 1, 1, sA0h1, sA1h1);
        MFMAQ(1, 0, bf0);  WB(4);            // next A-h0, B-h0 ready
        cur ^= 1;
    }
    LOADA(0, cur); LOADB(0, cur, bf0);
    MFMAQ(0, 0, bf0);  WB(2);
    LOADB(1, cur, bf1);
    MFMAQ(0, 1, bf1);  WB(0);
    LOADA(1, cur);
    MFMAQ(1, 1, bf1);
    MFMAQ(1, 0, bf0);

#undef STAGE
#undef LOADA
#undef LOADB
#undef MFMAQ
#undef WB

    #pragma unroll
    for (int mh = 0; mh < 2; ++mh)
    #pragma unroll
    for (int m = 0; m < 4; ++m)
    #pragma unroll
    for (int nh = 0; nh < 2; ++nh)
    #pragma unroll
    for (int n = 0; n < 2; ++n) {
        f32x4 v = acc[mh * 4 + m][nh * 2 + n];
        long row0 = bm + wr * 64 + mh * 128 + m * 16 + fk * 4;
        long col  = bn + wc * 32 + nh * 128 + n * 16 + fr;
        #pragma unroll
        for (int j = 0; j < 4; ++j)
            C[(row0 + j) * N + col] = __float2bfloat16(v[j]);
    }
}

// ---------------------------------------------------------------------------
// MFMA bf16 GEMM: 128x128 tile, BK=32, 2-phase double-buffered (small shapes).
// ---------------------------------------------------------------------------
template<typename OutT, int EPI, bool SPLITK = false>
__global__ __launch_bounds__(256)
void gemm_bt(const bf16* __restrict__ A, const bf16* __restrict__ Bt,
             OutT* __restrict__ C, const float* __restrict__ bias,
             int M, int N, int K, int lda, int ldb)
{
    __shared__ __align__(16) bf16 As[2][128 * 32];
    __shared__ __align__(16) bf16 Bs[2][128 * 32];

    const int tid  = threadIdx.x;
    const int wave = tid >> 6;
    const int lane = tid & 63;
    const int wr = wave >> 1, wc = wave & 1;
    const int fr = lane & 15, fk = lane >> 4;

    const int nbx = gridDim.x;
    const int nwg = nbx * gridDim.y;
    int id  = blockIdx.y * nbx + blockIdx.x;
    if (nwg >= 8) {
        int cpx = nwg >> 3;
        id = (id & 7) * cpx + (id >> 3);
    }
    const int bxi = id % nbx, byi = id / nbx;
    const long bm = (long)byi * 128;
    const long bn = (long)bxi * 128;

    if constexpr (SPLITK) {
        long ko = (long)blockIdx.z * K;
        A  += ko;
        Bt += ko;
        C  += (size_t)blockIdx.z * M * N;
    }

    const int r0 = tid >> 2,         c0 = (tid & 3) << 3;
    const int r1 = (256 + tid) >> 2, c1 = c0;
    const bf16* pA0 = A  + (bm + r0) * (long)lda + c0;
    const bf16* pA1 = A  + (bm + r1) * (long)lda + c1;
    const bf16* pB0 = Bt + (bn + r0) * (long)ldb + c0;
    const bf16* pB1 = Bt + (bn + r1) * (long)ldb + c1;
    const size_t ld0 = (size_t)(wave * 64) * 8;
    const size_t ld1 = (size_t)(256 + wave * 64) * 8;

    f32x4 acc[4][4] = {};
    const int nt = K >> 5;

    gload_lds16(pA0, &As[0][ld0]);
    gload_lds16(pB0, &Bs[0][ld0]);
    gload_lds16(pA1, &As[0][ld1]);
    gload_lds16(pB1, &Bs[0][ld1]);
    pA0 += 32; pA1 += 32; pB0 += 32; pB1 += 32;
    __syncthreads();

    int cur = 0;
    for (int t = 0; t < nt; ++t) {
        if (t + 1 < nt) {
            gload_lds16(pA0, &As[cur ^ 1][ld0]);
            gload_lds16(pB0, &Bs[cur ^ 1][ld0]);
            gload_lds16(pA1, &As[cur ^ 1][ld1]);
            gload_lds16(pB1, &Bs[cur ^ 1][ld1]);
            pA0 += 32; pA1 += 32; pB0 += 32; pB1 += 32;
        }

        s16x8 afrag[4], bfrag[4];
        #pragma unroll
        for (int m = 0; m < 4; ++m)
            afrag[m] = *(const s16x8*)&As[cur][(wr * 64 + m * 16 + fr) * 32 + fk * 8];
        #pragma unroll
        for (int n = 0; n < 4; ++n)
            bfrag[n] = *(const s16x8*)&Bs[cur][(wc * 64 + n * 16 + fr) * 32 + fk * 8];

        #pragma unroll
        for (int m = 0; m < 4; ++m)
            #pragma unroll
            for (int n = 0; n < 4; ++n)
                acc[m][n] = __builtin_amdgcn_mfma_f32_16x16x32_bf16(
                    afrag[m], bfrag[n], acc[m][n], 0, 0, 0);

        __syncthreads();
        cur ^= 1;
    }

    #pragma unroll
    for (int m = 0; m < 4; ++m)
        #pragma unroll
        for (int n = 0; n < 4; ++n) {
            f32x4 v = acc[m][n];
            long row0 = bm + wr * 64 + m * 16 + fk * 4;
            long col  = bn + wc * 64 + n * 16 + fr;
            #pragma unroll
            for (int j = 0; j < 4; ++j) {
                float val = v[j];
                if (EPI == 1) {
                    val += bias[col];
                    val = (val > 20.f) ? val : log1pf(__expf(val));
                }
                if constexpr (sizeof(OutT) == 2)
                    C[(row0 + j) * N + col] = __float2bfloat16(val);
                else
                    C[(row0 + j) * N + col] = val;
            }
        }
}

// ---------------------------------------------------------------------------
__global__ void transpose_bf16(const float* __restrict__ in, bf16* __restrict__ out,
                               int R, int C, int Cpad)
{
    __shared__ float tile[32][33];
    int cb = blockIdx.x * 32, rb = blockIdx.y * 32;
    int tx = threadIdx.x, ty = threadIdx.y;
    #pragma unroll
    for (int i = 0; i < 4; ++i) {
        int r = rb + ty + i * 8, c = cb + tx;
        tile[ty + i * 8][tx] = (r < R && c < C) ? in[(long)r * C + c] : 0.f;
    }
    __syncthreads();
    #pragma unroll
    for (int i = 0; i < 4; ++i) {
        int oc = cb + ty + i * 8;
        int orow = rb + tx;
        if (oc < Cpad && orow < R)
            out[(long)oc * R + orow] = __float2bfloat16(tile[tx][ty + i * 8]);
    }
}

__global__ void convert_x_kernel(const float* __restrict__ x, bf16* __restrict__ Xb)
{
    int idx = blockIdx.x * 256 + threadIdx.x;
    int c   = idx & (DMODEL - 1);
    int row = idx >> 10;
    int l   = row & (L_SEQ - 1);
    int b   = row >> 11;
    Xb[idx] = __float2bfloat16(x[((l * NBATCH + b) << 10) | c]);
}

// depthwise causal conv (d_conv=4) + silu, 8 channels per thread (vectorized)
__global__ void conv_silu_kernel(const bf16* __restrict__ xr, const float* __restrict__ Wc,
                                 const float* __restrict__ bc, bf16* __restrict__ u)
{
    int idx = blockIdx.x * 256 + threadIdx.x;   // MROWS*DINNER/8 threads
    int g   = idx & 255;
    int row = idx >> 8;
    int c   = g << 3;
    int l   = row & (L_SEQ - 1);

    float acc[8];
    f32x4 bi0 = *(const f32x4*)(bc + c);
    f32x4 bi1 = *(const f32x4*)(bc + c + 4);
    #pragma unroll
    for (int j = 0; j < 4; ++j) { acc[j] = bi0[j]; acc[4 + j] = bi1[j]; }

    f32x4 w[8];
    #pragma unroll
    for (int j = 0; j < 8; ++j) w[j] = *(const f32x4*)(Wc + (c + j) * 4);

    #pragma unroll
    for (int t = 0; t < 4; ++t) {
        int ll = l - 3 + t;
        if (ll >= 0) {
            s16x8 v = *(const s16x8*)(xr + (long)(row - 3 + t) * 4096 + c);
            #pragma unroll
            for (int j = 0; j < 8; ++j)
                acc[j] += bf2f(v[j]) * w[j][t];
        }
    }
    s16x8 o;
    #pragma unroll
    for (int j = 0; j < 8; ++j) {
        float a = acc[j];
        float s = a / (1.f + __builtin_amdgcn_exp2f(-LOG2E * a));
        bf16 h = __float2bfloat16(s);
        o[j] = *(short*)&h;
    }
    *(s16x8*)(u + (long)row * DINNER + c) = o;
}

__global__ void reduce_xdbl(const float* __restrict__ part, float* __restrict__ xdbl,
                            bf16* __restrict__ drbf)
{
    int idx = blockIdx.x * 256 + threadIdx.x;
    const size_t stride = (size_t)MROWS * 128;
    float v = part[idx] + part[idx + stride] + part[idx + 2 * stride]
            + part[idx + 3 * stride];
    xdbl[idx] = v;
    int col = idx & 127;
    if (col < 64)
        drbf[(idx >> 7) * 64 + col] = __float2bfloat16(v);
}

__global__ void reduce_out(const float* __restrict__ part, float* __restrict__ out)
{
    int i = blockIdx.x * 256 + threadIdx.x;
    f32x4 a = ((const f32x4*)part)[i];
    f32x4 b = ((const f32x4*)(part + (size_t)MROWS * DMODEL))[i];
    ((f32x4*)out)[i] = a + b;
}

// ---------------------------------------------------------------------------
// Chunked parallel selective scan — 2 threads per (channel, chunk), 8 states
// each (round-9 scalar form) + 2-deep software pipeline: step l+1's
// {delta, u, B0, B1} loads issue before step l's compute (hides L2/HBM
// latency under the ~150cy compute). FAST PATH (runtime-checked):
// A[d][n] = -(n+1) => decays are powers of exp(-dl).
// ---------------------------------------------------------------------------
__global__ __launch_bounds__(256)
void scan_phase1(const float* __restrict__ delta, const bf16* __restrict__ u,
                 const float* __restrict__ xdbl, const float* __restrict__ A_log,
                 float* __restrict__ AS)
{
    const int idx   = blockIdx.x * 256 + threadIdx.x;
    const int half  = idx & 1;
    const int ch    = idx >> 1;
    const int chunk = blockIdx.y;
    const int d     = ch & (DINNER - 1);
    const int b     = ch >> 11;
    const int n0    = half * 8;

    float A2[8], s[8];
    const f32x4* Arow = (const f32x4*)(A_log + d * DSTATE + n0);
    #pragma unroll
    for (int q = 0; q < 2; ++q) {
        f32x4 v = Arow[q];
        #pragma unroll
        for (int j = 0; j < 4; ++j) A2[q * 4 + j] = -__expf(v[j]) * LOG2E;
    }
    #pragma unroll
    for (int n = 0; n < 8; ++n) s[n] = 0.f;
    float sdl = 0.f;

    bool fastA = true;
    #pragma unroll
    for (int j = 0; j < 8; ++j)
        fastA &= fabsf(A2[j] + (float)(n0 + j + 1) * LOG2E)
                 < 0.01f * (float)(n0 + j + 1);

    const long row0 = (long)b * L_SEQ + chunk * LCHUNK;
    const float* pD = delta + row0 * DINNER + d;
    const bf16*  pU = u     + row0 * DINNER + d;
    const f32x4* pB = (const f32x4*)(xdbl + row0 * 128 + 64 + n0);

    if (fastA) {
        float dlA, uvA, dlB, uvB;
        f32x4 B0A, B1A, B0B, B1B;

#define P1LOAD(DL, UV, B0V, B1V) do {                        \
        DL = *pD; UV = __bfloat162float(*pU);                \
        B0V = pB[0]; B1V = pB[1];                            \
        pD += DINNER; pU += DINNER; pB += 32;                \
    } while (0)

#define P1COMP(DL, UV, B0V, B1V) do {                        \
        float dbu = DL * UV;                                 \
        sdl += DL;                                           \
        float b1 = __builtin_amdgcn_exp2f(-LOG2E * DL);      \
        float b2 = b1 * b1, b3 = b2 * b1, b4 = b2 * b2;      \
        float b5 = b4 * b1, b6 = b4 * b2, b7 = b4 * b3, b8 = b4 * b4; \
        float pre = half ? b8 : 1.f;                         \
        s[0] = pre * b1 * s[0] + dbu * B0V[0];               \
        s[1] = pre * b2 * s[1] + dbu * B0V[1];               \
        s[2] = pre * b3 * s[2] + dbu * B0V[2];               \
        s[3] = pre * b4 * s[3] + dbu * B0V[3];               \
        s[4] = pre * b5 * s[4] + dbu * B1V[0];               \
        s[5] = pre * b6 * s[5] + dbu * B1V[1];               \
        s[6] = pre * b7 * s[6] + dbu * B1V[2];               \
        s[7] = pre * b8 * s[7] + dbu * B1V[3];               \
    } while (0)

        P1LOAD(dlA, uvA, B0A, B1A);                          // step 0
        #pragma unroll 5
        for (int l = 0; l < LCHUNK - 2; l += 2) {
            P1LOAD(dlB, uvB, B0B, B1B);                      // step l+1
            P1COMP(dlA, uvA, B0A, B1A);                      // step l
            P1LOAD(dlA, uvA, B0A, B1A);                      // step l+2
            P1COMP(dlB, uvB, B0B, B1B);                      // step l+1
        }
        P1LOAD(dlB, uvB, B0B, B1B);                          // step 31
        P1COMP(dlA, uvA, B0A, B1A);                          // step 30
        P1COMP(dlB, uvB, B0B, B1B);                          // step 31
#undef P1LOAD
#undef P1COMP
    } else {
        for (int l = 0; l < LCHUNK; ++l) {
            float dl = *pD;
            float uv = __bfloat162float(*pU);
            f32x4 B0 = pB[0], B1 = pB[1];
            pD += DINNER; pU += DINNER; pB += 32;
            float dbu = dl * uv;
            sdl += dl;
            #pragma unroll
            for (int j = 0; j < 4; ++j) {
                float e = __builtin_amdgcn_exp2f(dl * A2[j]);
                s[j] = e * s[j] + dbu * B0[j];
            }
            #pragma unroll
            for (int j = 0; j < 4; ++j) {
                float e = __builtin_amdgcn_exp2f(dl * A2[4 + j]);
                s[4 + j] = e * s[4 + j] + dbu * B1[j];
            }
        }
    }
    float ap[8];
    #pragma unroll
    for (int n = 0; n < 8; ++n) ap[n] = __builtin_amdgcn_exp2f(sdl * A2[n]);

    float* o = AS + ((size_t)chunk * 4096 + ch) * 32 + n0;
    *(f32x4*)(o)      = *(f32x4*)&ap[0];
    *(f32x4*)(o + 4)  = *(f32x4*)&ap[4];
    *(f32x4*)(o + 16) = *(f32x4*)&s[0];
    *(f32x4*)(o + 20) = *(f32x4*)&s[4];
}

__global__ __launch_bounds__(256)
void scan_phase2(float* __restrict__ AS)
{
    const int idx = blockIdx.x * 256 + threadIdx.x;
    const int n   = idx & 15;
    const int ch  = idx >> 4;

    float s = 0.f;
    for (int cb = 0; cb < NCHUNK; cb += 16) {
        float av[16], sv[16];
        #pragma unroll
        for (int j = 0; j < 16; ++j) {
            size_t r = ((size_t)(cb + j) * 4096 + ch) * 32 + n;
            av[j] = AS[r];
            sv[j] = AS[r + 16];
        }
        #pragma unroll
        for (int j = 0; j < 16; ++j) {
            AS[((size_t)(cb + j) * 4096 + ch) * 32 + 16 + n] = s;
            s = av[j] * s + sv[j];
        }
    }
}

__global__ __launch_bounds__(256)
void scan_phase3(const float* __restrict__ delta, const bf16* __restrict__ u,
                 const float* __restrict__ xdbl, const bf16* __restrict__ xr,
                 const float* __restrict__ AS, const float* __restrict__ A_log,
                 const float* __restrict__ Dp, bf16* __restrict__ ybf)
{
    const int idx   = blockIdx.x * 256 + threadIdx.x;
    const int half  = idx & 1;
    const int ch    = idx >> 1;
    const int chunk = blockIdx.y;
    const int d     = ch & (DINNER - 1);
    const int b     = ch >> 11;
    const int n0    = half * 8;

    float A2[8], s[8];
    const f32x4* Arow = (const f32x4*)(A_log + d * DSTATE + n0);
    #pragma unroll
    for (int q = 0; q < 2; ++q) {
        f32x4 v = Arow[q];
        #pragma unroll
        for (int j = 0; j < 4; ++j) A2[q * 4 + j] = -__expf(v[j]) * LOG2E;
    }
    const float* ip = AS + ((size_t)chunk * 4096 + ch) * 32 + 16 + n0;
    *(f32x4*)&s[0] = *(const f32x4*)(ip);
    *(f32x4*)&s[4] = *(const f32x4*)(ip + 4);

    bool fastA = true;
    #pragma unroll
    for (int j = 0; j < 8; ++j)
        fastA &= fabsf(A2[j] + (float)(n0 + j + 1) * LOG2E)
                 < 0.01f * (float)(n0 + j + 1);

    const float Dd  = Dp[d];
    const long row0 = (long)b * L_SEQ + chunk * LCHUNK;

    const float* pD = delta + row0 * DINNER + d;
    const bf16*  pU = u     + row0 * DINNER + d;
    const bf16*  pR = xr    + row0 * 4096 + 2048 + d;
    const f32x4* pB = (const f32x4*)(xdbl + row0 * 128 + 64 + n0);  // B (lead)
    const f32x4* pC = (const f32x4*)(xdbl + row0 * 128 + 80 + n0);  // C (lag)
    bf16*        pY = ybf   + row0 * DINNER + d;

    if (fastA) {
        float dlA, uvA, dlB, uvB;
        f32x4 B0A, B1A, B0B, B1B;

#define P3LOAD(DL, UV, B0V, B1V) do {                        \
        DL = *pD; UV = __bfloat162float(*pU);                \
        B0V = pB[0]; B1V = pB[1];                            \
        pD += DINNER; pU += DINNER; pB += 32;                \
    } while (0)

#define P3COMP(DL, UV, B0V, B1V) do {                        \
        float dbu = DL * UV;                                 \
        float b1 = __builtin_amdgcn_exp2f(-LOG2E * DL);      \
        float b2 = b1 * b1, b3 = b2 * b1, b4 = b2 * b2;      \
        float b5 = b4 * b1, b6 = b4 * b2, b7 = b4 * b3, b8 = b4 * b4; \
        float pre = half ? b8 : 1.f;                         \
        f32x4 C0v = pC[0], C1v = pC[1];                      \
        float rs = __bfloat162float(*pR);                    \
        pC += 32; pR += 4096;                                \
        float y0 = 0.f, y1 = 0.f;                            \
        s[0] = pre * b1 * s[0] + dbu * B0V[0];  y0 += s[0] * C0v[0]; \
        s[1] = pre * b2 * s[1] + dbu * B0V[1];  y0 += s[1] * C0v[1]; \
        s[2] = pre * b3 * s[2] + dbu * B0V[2];  y0 += s[2] * C0v[2]; \
        s[3] = pre * b4 * s[3] + dbu * B0V[3];  y0 += s[3] * C0v[3]; \
        s[4] = pre * b5 * s[4] + dbu * B1V[0];  y1 += s[4] * C1v[0]; \
        s[5] = pre * b6 * s[5] + dbu * B1V[1];  y1 += s[5] * C1v[1]; \
        s[6] = pre * b7 * s[6] + dbu * B1V[2];  y1 += s[6] * C1v[2]; \
        s[7] = pre * b8 * s[7] + dbu * B1V[3];  y1 += s[7] * C1v[3]; \
        float yh = y0 + y1;                                  \
        float yt = yh + __shfl_xor(yh, 1);                   \
        if (half == 0) {                                     \
            float yf = yt + UV * Dd;                         \
            yf *= rs / (1.f + __builtin_amdgcn_exp2f(-LOG2E * rs)); \
            *pY = __float2bfloat16(yf);                      \
        }                                                    \
        pY += DINNER;                                        \
    } while (0)

        P3LOAD(dlA, uvA, B0A, B1A);                          // step 0
        #pragma unroll 5
        for (int l = 0; l < LCHUNK - 2; l += 2) {
            P3LOAD(dlB, uvB, B0B, B1B);                      // step l+1
            P3COMP(dlA, uvA, B0A, B1A);                      // step l
            P3LOAD(dlA, uvA, B0A, B1A);                      // step l+2
            P3COMP(dlB, uvB, B0B, B1B);                      // step l+1
        }
        P3LOAD(dlB, uvB, B0B, B1B);                          // step 31
        P3COMP(dlA, uvA, B0A, B1A);                          // step 30
        P3COMP(dlB, uvB, B0B, B1B);                          // step 31
#undef P3LOAD
#undef P3COMP
    } else {
        for (int l = 0; l < LCHUNK; ++l) {
            float dl = *pD;
            float uv = __bfloat162float(*pU);
            float rs = __bfloat162float(*pR);
            f32x4 B0 = pB[0], B1 = pB[1];
            f32x4 C0 = pC[0], C1 = pC[1];
            pD += DINNER; pU += DINNER; pR += 4096; pB += 32; pC += 32;
            float dbu = dl * uv;
            float y0 = 0.f, y1 = 0.f;
            #pragma unroll
            for (int j = 0; j < 4; ++j) {
                float e = __builtin_amdgcn_exp2f(dl * A2[j]);
                s[j] = e * s[j] + dbu * B0[j];
                y0 += s[j] * C0[j];
            }
            #pragma unroll
            for (int j = 0; j < 4; ++j) {
                float e = __builtin_amdgcn_exp2f(dl * A2[4 + j]);
                s[4 + j] = e * s[4 + j] + dbu * B1[j];
                y1 += s[4 + j] * C1[j];
            }
            float yh = y0 + y1;
            float yt = yh + __shfl_xor(yh, 1);
            if (half == 0) {
                float yf = yt + uv * Dd;
                yf *= rs / (1.f + __builtin_amdgcn_exp2f(-LOG2E * rs));
                *pY = __float2bfloat16(yf);
            }
            pY += DINNER;
        }
    }
}

// ---------------------------------------------------------------------------
extern "C" void kernel_launch(void* const* d_in, const int* in_sizes, int n_in,
                              void* d_out, int out_size, void* d_ws, size_t ws_size,
                              hipStream_t stream)
{
    const float* x      = (const float*)d_in[0];
    const float* W_in   = (const float*)d_in[1];
    const float* W_conv = (const float*)d_in[2];
    const float* b_conv = (const float*)d_in[3];
    const float* W_x    = (const float*)d_in[4];
    const float* W_dt   = (const float*)d_in[5];
    const float* b_dt   = (const float*)d_in[6];
    const float* A_log  = (const float*)d_in[7];
    const float* Dp     = (const float*)d_in[8];
    const float* W_out  = (const float*)d_in[9];
    float* out = (float*)d_out;

    char* ws = (char*)d_ws;
    size_t off = 0;
    auto alloc = [&](size_t bytes) {
        void* p = ws + off;
        off = (off + bytes + 255) & ~(size_t)255;
        return p;
    };
    bf16*  Xb    = (bf16*) alloc((size_t)MROWS * DMODEL * 2);
    bf16*  WinT  = (bf16*) alloc((size_t)4096  * DMODEL * 2);
    bf16*  xr    = (bf16*) alloc((size_t)MROWS * 4096  * 2);
    bf16*  ubf   = (bf16*) alloc((size_t)MROWS * DINNER * 2);
    bf16*  WxT   = (bf16*) alloc((size_t)128   * DINNER * 2);
    float* xdbl  = (float*)alloc((size_t)MROWS * 128 * 4);
    float* xdblp = (float*)alloc((size_t)4 * MROWS * 128 * 4);
    bf16*  drbf  = (bf16*) alloc((size_t)MROWS * 64 * 2);
    bf16*  WdtT  = (bf16*) alloc((size_t)DINNER * 64 * 2);
    float* delta = (float*)alloc((size_t)MROWS * DINNER * 4);   // fp32 (revert)
    bf16*  ybf   = (bf16*) alloc((size_t)MROWS * DINNER * 2);
    bf16*  WoutT = (bf16*) alloc((size_t)DMODEL * DINNER * 2);
    float* AS    = (float*)alloc((size_t)NCHUNK * 4096 * 32 * 4); // 32MB; reused
                                                                  // as GEMM4 partials

    dim3 tb(32, 8);
    transpose_bf16<<<dim3(128, 32), tb, 0, stream>>>(W_in,  WinT,  1024, 4096, 4096);
    transpose_bf16<<<dim3(4, 64),   tb, 0, stream>>>(W_x,   WxT,   2048, 96,   128);
    transpose_bf16<<<dim3(64, 2),   tb, 0, stream>>>(W_dt,  WdtT,  64,   2048, 2048);
    transpose_bf16<<<dim3(32, 64),  tb, 0, stream>>>(W_out, WoutT, 2048, 1024, 1024);
    convert_x_kernel<<<(MROWS * DMODEL) / 256, 256, 0, stream>>>(x, Xb);

    // GEMM1: x_and_res = Xb @ W_in -> xr bf16 (4096,4096) — 256² 8-phase
    gemm256<<<dim3(4096 / 256, MROWS / 256), 512, 0, stream>>>(
        Xb, WinT, xr, 4096, 1024, 1024, 1024);
    // conv + silu -> u bf16 (vectorized, 8 ch/thread)
    conv_silu_kernel<<<(MROWS * DINNER / 8) / 256, 256, 0, stream>>>(
        xr, W_conv, b_conv, ubf);
    // GEMM2: x_dbl = u @ W_x, split-K x4 -> partials
    gemm_bt<float, 0, true><<<dim3(1, MROWS / 128, 4), 256, 0, stream>>>(
        ubf, WxT, xdblp, nullptr, MROWS, 128, 512, 2048, 2048);
    reduce_xdbl<<<(MROWS * 128) / 256, 256, 0, stream>>>(xdblp, xdbl, drbf);
    // GEMM3: delta = softplus(delta_r @ W_dt + b_dt) -> fp32
    gemm_bt<float, 1><<<dim3(DINNER / 128, MROWS / 128), 256, 0, stream>>>(
        drbf, WdtT, delta, b_dt, MROWS, DINNER, 64, 64, 64);
    // chunked parallel selective scan -> ybf bf16
    scan_phase1<<<dim3(32, NCHUNK), 256, 0, stream>>>(delta, ubf, xdbl, A_log, AS);
    scan_phase2<<<256, 256, 0, stream>>>(AS);
    scan_phase3<<<dim3(32, NCHUNK), 256, 0, stream>>>(delta, ubf, xdbl, xr, AS,
                                                      A_log, Dp, ybf);
    // GEMM4: out = y @ W_out, split-K x2 into AS (free after scan), then reduce
    gemm_bt<float, 0, true><<<dim3(DMODEL / 128, MROWS / 128, 2), 256, 0, stream>>>(
        ybf, WoutT, (float*)AS, nullptr, MROWS, DMODEL, 1024, 2048, 2048);
    reduce_out<<<(MROWS * DMODEL) / 1024, 256, 0, stream>>>((float*)AS, out);
}

// Round 12
// 271.922 us; speedup vs baseline: 1.1207x; 1.0598x over previous
//
#include <hip/hip_runtime.h>
#include <hip/hip_bf16.h>

#define L_SEQ  2048
#define NBATCH 2
#define DMODEL 1024
#define DINNER 2048
#define DSTATE 16
#define DTRANK 64
#define MROWS  (L_SEQ * NBATCH)   // 4096
#define NCHUNK 64
#define LCHUNK 32                 // L_SEQ / NCHUNK
#define LOG2E  1.44269504f

using bf16 = __hip_bfloat16;
typedef short s16x8 __attribute__((ext_vector_type(8)));   // 8 bf16 = 16B
typedef float f32x4 __attribute__((ext_vector_type(4)));

__device__ __forceinline__ void gload_lds16(const bf16* g, bf16* l) {
    __builtin_amdgcn_global_load_lds(
        (const __attribute__((address_space(1))) void*)g,
        (__attribute__((address_space(3))) void*)l, 16, 0, 0);
}

__device__ __forceinline__ float bf2f(short v) {
    return __uint_as_float(((unsigned)(unsigned short)v) << 16);
}

// ---------------------------------------------------------------------------
// 256x256 8-phase MFMA GEMM (T2 swizzle + counted vmcnt + T5 setprio),
// fragment reuse, and DEEP PREFETCH: all 4 STAGEs of tile t+1 issue at the
// top of iteration t, waits WB(10)/WB(8)/WB(4) release exactly the half-tile
// the next phase consumes with 4-6 phase issue->wait distance (~500-800 cy,
// HBM-latency tolerant). Ledger traced: steady in-flight 4 -> 12 -> 10 -> 8
// -> 4. C(M,N) = A(M,K) @ Bt(N,K)^T, bf16 in/out, fp32 acc.
// ---------------------------------------------------------------------------
__global__ __launch_bounds__(512, 2)
void gemm256(const bf16* __restrict__ A, const bf16* __restrict__ Bt,
             bf16* __restrict__ C, int N, int K, int lda, int ldb)
{
    __shared__ __align__(16) bf16 As[2][256 * 64];
    __shared__ __align__(16) bf16 Bs[2][256 * 64];

    const int tid  = threadIdx.x;
    const int wid  = tid >> 6;
    const int lane = tid & 63;
    const int wr = wid >> 2, wc = wid & 3;       // 2x4 wave grid
    const int fr = lane & 15, fk = lane >> 4;

    const int nbx = gridDim.x;
    const int nwg = nbx * gridDim.y;
    int id = blockIdx.y * nbx + blockIdx.x;
    int cpx = nwg >> 3;
    id = (id & 7) * cpx + (id >> 3);
    const long bm = (long)(id / nbx) * 256;
    const long bn = (long)(id % nbx) * 256;

    const int q0 = tid, q1 = tid + 512;
    const int r0 = q0 >> 3, r1 = q1 >> 3;
    const int c0 = ((q0 & 7) ^ (r0 & 7)) << 3;
    const int c1 = ((q1 & 7) ^ (r1 & 7)) << 3;
    const bf16* sA0h0 = A  + (bm + r0)       * (long)lda + c0;
    const bf16* sA1h0 = A  + (bm + r1)       * (long)lda + c1;
    const bf16* sA0h1 = A  + (bm + 128 + r0) * (long)lda + c0;
    const bf16* sA1h1 = A  + (bm + 128 + r1) * (long)lda + c1;
    const bf16* sB0h0 = Bt + (bn + r0)       * (long)ldb + c0;
    const bf16* sB1h0 = Bt + (bn + r1)       * (long)ldb + c1;
    const bf16* sB0h1 = Bt + (bn + 128 + r0) * (long)ldb + c0;
    const bf16* sB1h1 = Bt + (bn + 128 + r1) * (long)ldb + c1;
    const int dst0 = wid * 512;
    const int dst1 = 4096 + wid * 512;

    const int o0   = ((fk ^ (fr & 7)) << 3);
    const int o1   = o0 ^ 32;
    const int rA64 = (wr * 64 + fr) * 64;
    const int rB64 = (wc * 32 + fr) * 64;

    f32x4 acc[8][4] = {};
    s16x8 af[4][2], bf0[2][2], bf1[2][2];
    const int nt = K >> 6;

#define STAGE(ARR, BUF, H, P0, P1) do {                    \
        gload_lds16(P0, &ARR[BUF][(H) * 8192 + dst0]);     \
        gload_lds16(P1, &ARR[BUF][(H) * 8192 + dst1]);     \
        P0 += 64; P1 += 64;                                \
    } while (0)

#define LOADA(MH, CUR) do {                                   \
        const bf16* ab = &As[CUR][rA64 + (MH) * 8192];        \
        _Pragma("unroll") for (int m = 0; m < 4; ++m) {       \
            af[m][0] = *(const s16x8*)&ab[m * 1024 + o0];     \
            af[m][1] = *(const s16x8*)&ab[m * 1024 + o1]; }   \
    } while (0)

#define LOADB(NH, CUR, BF) do {                               \
        const bf16* bb = &Bs[CUR][rB64 + (NH) * 8192];        \
        _Pragma("unroll") for (int n = 0; n < 2; ++n) {       \
            BF[n][0] = *(const s16x8*)&bb[n * 1024 + o0];     \
            BF[n][1] = *(const s16x8*)&bb[n * 1024 + o1]; }   \
    } while (0)

#define MFMAQ(MH, NH, BF) do {                                               \
        __builtin_amdgcn_s_setprio(1);                                       \
        _Pragma("unroll") for (int ks = 0; ks < 2; ++ks)                     \
        _Pragma("unroll") for (int m = 0; m < 4; ++m)                        \
        _Pragma("unroll") for (int n = 0; n < 2; ++n)                        \
            acc[(MH) * 4 + m][(NH) * 2 + n] =                                \
                __builtin_amdgcn_mfma_f32_16x16x32_bf16(                     \
                    af[m][ks], BF[n][ks], acc[(MH) * 4 + m][(NH) * 2 + n],   \
                    0, 0, 0);                                                \
        __builtin_amdgcn_s_setprio(0);                                       \
    } while (0)

#define WB(NV) asm volatile("s_waitcnt vmcnt(" #NV ")\n\ts_barrier" ::: "memory")

    // prologue: stage tile 0 (order A0,B0,B1,A1) -> buf 0
    STAGE(As, 0, 0, sA0h0, sA1h0);
    STAGE(Bs, 0, 0, sB0h0, sB1h0);
    STAGE(Bs, 0, 1, sB0h1, sB1h1);
    STAGE(As, 0, 1, sA0h1, sA1h1);
    WB(4);                                   // A-h0, B-h0 of tile 0 ready

    int cur = 0;
    for (int t = 0; t < nt - 1; ++t) {
        // stage ALL of tile t+1 up-front: in-flight 4 -> 12
        STAGE(As, cur ^ 1, 0, sA0h0, sA1h0);
        STAGE(Bs, cur ^ 1, 0, sB0h0, sB1h0);
        STAGE(Bs, cur ^ 1, 1, sB0h1, sB1h1);
        STAGE(As, cur ^ 1, 1, sA0h1, sA1h1);
        LOADA(0, cur); LOADB(0, cur, bf0);
        MFMAQ(0, 0, bf0);  WB(10);           // B-h1 of t ready (issued iter t-1)
        LOADB(1, cur, bf1);
        MFMAQ(0, 1, bf1);  WB(8);            // A-h1 of t ready
        LOADA(1, cur);
        MFMAQ(1, 1, bf1);
        MFMAQ(1, 0, bf0);  WB(4);            // A-h0,B-h0 of t+1 ready (4-phase dist)
        cur ^= 1;
    }
    // last tile: no staging; drain progressively
    LOADA(0, cur); LOADB(0, cur, bf0);
    MFMAQ(0, 0, bf0);  WB(2);
    LOADB(1, cur, bf1);
    MFMAQ(0, 1, bf1);  WB(0);
    LOADA(1, cur);
    MFMAQ(1, 1, bf1);
    MFMAQ(1, 0, bf0);

#undef STAGE
#undef LOADA
#undef LOADB
#undef MFMAQ
#undef WB

    #pragma unroll
    for (int mh = 0; mh < 2; ++mh)
    #pragma unroll
    for (int m = 0; m < 4; ++m)
    #pragma unroll
    for (int nh = 0; nh < 2; ++nh)
    #pragma unroll
    for (int n = 0; n < 2; ++n) {
        f32x4 v = acc[mh * 4 + m][nh * 2 + n];
        long row0 = bm + wr * 64 + mh * 128 + m * 16 + fk * 4;
        long col  = bn + wc * 32 + nh * 128 + n * 16 + fr;
        #pragma unroll
        for (int j = 0; j < 4; ++j)
            C[(row0 + j) * N + col] = __float2bfloat16(v[j]);
    }
}

// ---------------------------------------------------------------------------
// MFMA bf16 GEMM: 128x128 tile, BK=32, 2-phase double-buffered (small shapes).
// ---------------------------------------------------------------------------
template<typename OutT, int EPI, bool SPLITK = false>
__global__ __launch_bounds__(256)
void gemm_bt(const bf16* __restrict__ A, const bf16* __restrict__ Bt,
             OutT* __restrict__ C, const float* __restrict__ bias,
             int M, int N, int K, int lda, int ldb)
{
    __shared__ __align__(16) bf16 As[2][128 * 32];
    __shared__ __align__(16) bf16 Bs[2][128 * 32];

    const int tid  = threadIdx.x;
    const int wave = tid >> 6;
    const int lane = tid & 63;
    const int wr = wave >> 1, wc = wave & 1;
    const int fr = lane & 15, fk = lane >> 4;

    const int nbx = gridDim.x;
    const int nwg = nbx * gridDim.y;
    int id  = blockIdx.y * nbx + blockIdx.x;
    if (nwg >= 8) {
        int cpx = nwg >> 3;
        id = (id & 7) * cpx + (id >> 3);
    }
    const int bxi = id % nbx, byi = id / nbx;
    const long bm = (long)byi * 128;
    const long bn = (long)bxi * 128;

    if constexpr (SPLITK) {
        long ko = (long)blockIdx.z * K;
        A  += ko;
        Bt += ko;
        C  += (size_t)blockIdx.z * M * N;
    }

    const int r0 = tid >> 2,         c0 = (tid & 3) << 3;
    const int r1 = (256 + tid) >> 2, c1 = c0;
    const bf16* pA0 = A  + (bm + r0) * (long)lda + c0;
    const bf16* pA1 = A  + (bm + r1) * (long)lda + c1;
    const bf16* pB0 = Bt + (bn + r0) * (long)ldb + c0;
    const bf16* pB1 = Bt + (bn + r1) * (long)ldb + c1;
    const size_t ld0 = (size_t)(wave * 64) * 8;
    const size_t ld1 = (size_t)(256 + wave * 64) * 8;

    f32x4 acc[4][4] = {};
    const int nt = K >> 5;

    gload_lds16(pA0, &As[0][ld0]);
    gload_lds16(pB0, &Bs[0][ld0]);
    gload_lds16(pA1, &As[0][ld1]);
    gload_lds16(pB1, &Bs[0][ld1]);
    pA0 += 32; pA1 += 32; pB0 += 32; pB1 += 32;
    __syncthreads();

    int cur = 0;
    for (int t = 0; t < nt; ++t) {
        if (t + 1 < nt) {
            gload_lds16(pA0, &As[cur ^ 1][ld0]);
            gload_lds16(pB0, &Bs[cur ^ 1][ld0]);
            gload_lds16(pA1, &As[cur ^ 1][ld1]);
            gload_lds16(pB1, &Bs[cur ^ 1][ld1]);
            pA0 += 32; pA1 += 32; pB0 += 32; pB1 += 32;
        }

        s16x8 afrag[4], bfrag[4];
        #pragma unroll
        for (int m = 0; m < 4; ++m)
            afrag[m] = *(const s16x8*)&As[cur][(wr * 64 + m * 16 + fr) * 32 + fk * 8];
        #pragma unroll
        for (int n = 0; n < 4; ++n)
            bfrag[n] = *(const s16x8*)&Bs[cur][(wc * 64 + n * 16 + fr) * 32 + fk * 8];

        #pragma unroll
        for (int m = 0; m < 4; ++m)
            #pragma unroll
            for (int n = 0; n < 4; ++n)
                acc[m][n] = __builtin_amdgcn_mfma_f32_16x16x32_bf16(
                    afrag[m], bfrag[n], acc[m][n], 0, 0, 0);

        __syncthreads();
        cur ^= 1;
    }

    #pragma unroll
    for (int m = 0; m < 4; ++m)
        #pragma unroll
        for (int n = 0; n < 4; ++n) {
            f32x4 v = acc[m][n];
            long row0 = bm + wr * 64 + m * 16 + fk * 4;
            long col  = bn + wc * 64 + n * 16 + fr;
            #pragma unroll
            for (int j = 0; j < 4; ++j) {
                float val = v[j];
                if (EPI == 1) {
                    val += bias[col];
                    val = (val > 20.f) ? val : log1pf(__expf(val));
                }
                if constexpr (sizeof(OutT) == 2)
                    C[(row0 + j) * N + col] = __float2bfloat16(val);
                else
                    C[(row0 + j) * N + col] = val;
            }
        }
}

// ---------------------------------------------------------------------------
__global__ void transpose_bf16(const float* __restrict__ in, bf16* __restrict__ out,
                               int R, int C, int Cpad)
{
    __shared__ float tile[32][33];
    int cb = blockIdx.x * 32, rb = blockIdx.y * 32;
    int tx = threadIdx.x, ty = threadIdx.y;
    #pragma unroll
    for (int i = 0; i < 4; ++i) {
        int r = rb + ty + i * 8, c = cb + tx;
        tile[ty + i * 8][tx] = (r < R && c < C) ? in[(long)r * C + c] : 0.f;
    }
    __syncthreads();
    #pragma unroll
    for (int i = 0; i < 4; ++i) {
        int oc = cb + ty + i * 8;
        int orow = rb + tx;
        if (oc < Cpad && orow < R)
            out[(long)oc * R + orow] = __float2bfloat16(tile[tx][ty + i * 8]);
    }
}

__global__ void convert_x_kernel(const float* __restrict__ x, bf16* __restrict__ Xb)
{
    int idx = blockIdx.x * 256 + threadIdx.x;
    int c   = idx & (DMODEL - 1);
    int row = idx >> 10;
    int l   = row & (L_SEQ - 1);
    int b   = row >> 11;
    Xb[idx] = __float2bfloat16(x[((l * NBATCH + b) << 10) | c]);
}

// depthwise causal conv (d_conv=4) + silu, 8 channels per thread (vectorized)
__global__ void conv_silu_kernel(const bf16* __restrict__ xr, const float* __restrict__ Wc,
                                 const float* __restrict__ bc, bf16* __restrict__ u)
{
    int idx = blockIdx.x * 256 + threadIdx.x;   // MROWS*DINNER/8 threads
    int g   = idx & 255;
    int row = idx >> 8;
    int c   = g << 3;
    int l   = row & (L_SEQ - 1);

    float acc[8];
    f32x4 bi0 = *(const f32x4*)(bc + c);
    f32x4 bi1 = *(const f32x4*)(bc + c + 4);
    #pragma unroll
    for (int j = 0; j < 4; ++j) { acc[j] = bi0[j]; acc[4 + j] = bi1[j]; }

    f32x4 w[8];
    #pragma unroll
    for (int j = 0; j < 8; ++j) w[j] = *(const f32x4*)(Wc + (c + j) * 4);

    #pragma unroll
    for (int t = 0; t < 4; ++t) {
        int ll = l - 3 + t;
        if (ll >= 0) {
            s16x8 v = *(const s16x8*)(xr + (long)(row - 3 + t) * 4096 + c);
            #pragma unroll
            for (int j = 0; j < 8; ++j)
                acc[j] += bf2f(v[j]) * w[j][t];
        }
    }
    s16x8 o;
    #pragma unroll
    for (int j = 0; j < 8; ++j) {
        float a = acc[j];
        float s = a / (1.f + __builtin_amdgcn_exp2f(-LOG2E * a));
        bf16 h = __float2bfloat16(s);
        o[j] = *(short*)&h;
    }
    *(s16x8*)(u + (long)row * DINNER + c) = o;
}

__global__ void reduce_xdbl(const float* __restrict__ part, float* __restrict__ xdbl,
                            bf16* __restrict__ drbf)
{
    int idx = blockIdx.x * 256 + threadIdx.x;
    const size_t stride = (size_t)MROWS * 128;
    float v = part[idx] + part[idx + stride] + part[idx + 2 * stride]
            + part[idx + 3 * stride];
    xdbl[idx] = v;
    int col = idx & 127;
    if (col < 64)
        drbf[(idx >> 7) * 64 + col] = __float2bfloat16(v);
}

__global__ void reduce_out(const float* __restrict__ part, float* __restrict__ out)
{
    int i = blockIdx.x * 256 + threadIdx.x;
    f32x4 a = ((const f32x4*)part)[i];
    f32x4 b = ((const f32x4*)(part + (size_t)MROWS * DMODEL))[i];
    ((f32x4*)out)[i] = a + b;
}

// ---------------------------------------------------------------------------
// Chunked parallel selective scan — round-9 form (best measured; manual
// restructures regressed twice). delta is bf16 (absmax-neutral, verified
// round 10). FAST PATH (runtime-checked): A[d][n] = -(n+1) => decays are
// powers of exp(-dl).
// ---------------------------------------------------------------------------
__global__ __launch_bounds__(256)
void scan_phase1(const bf16* __restrict__ delta, const bf16* __restrict__ u,
                 const float* __restrict__ xdbl, const float* __restrict__ A_log,
                 float* __restrict__ AS)
{
    const int idx   = blockIdx.x * 256 + threadIdx.x;
    const int half  = idx & 1;
    const int ch    = idx >> 1;
    const int chunk = blockIdx.y;
    const int d     = ch & (DINNER - 1);
    const int b     = ch >> 11;
    const int n0    = half * 8;

    float A2[8], s[8];
    const f32x4* Arow = (const f32x4*)(A_log + d * DSTATE + n0);
    #pragma unroll
    for (int q = 0; q < 2; ++q) {
        f32x4 v = Arow[q];
        #pragma unroll
        for (int j = 0; j < 4; ++j) A2[q * 4 + j] = -__expf(v[j]) * LOG2E;
    }
    #pragma unroll
    for (int n = 0; n < 8; ++n) s[n] = 0.f;
    float sdl = 0.f;

    bool fastA = true;
    #pragma unroll
    for (int j = 0; j < 8; ++j)
        fastA &= fabsf(A2[j] + (float)(n0 + j + 1) * LOG2E)
                 < 0.01f * (float)(n0 + j + 1);

    const long row0 = (long)b * L_SEQ + chunk * LCHUNK;
    const bf16*  pD = delta + row0 * DINNER + d;
    const bf16*  pU = u     + row0 * DINNER + d;
    const f32x4* pB = (const f32x4*)(xdbl + row0 * 128 + 64 + n0);

    if (fastA) {
        #pragma unroll 4
        for (int l = 0; l < LCHUNK; ++l) {
            float dl = __bfloat162float(*pD);
            float uv = __bfloat162float(*pU);
            f32x4 B0 = pB[0], B1 = pB[1];
            pD += DINNER; pU += DINNER; pB += 32;
            float dbu = dl * uv;
            sdl += dl;
            float b1 = __builtin_amdgcn_exp2f(-LOG2E * dl);   // exp(-dl)
            float b2 = b1 * b1, b3 = b2 * b1, b4 = b2 * b2;
            float b5 = b4 * b1, b6 = b4 * b2, b7 = b4 * b3, b8 = b4 * b4;
            float pre = half ? b8 : 1.f;
            s[0] = pre * b1 * s[0] + dbu * B0[0];
            s[1] = pre * b2 * s[1] + dbu * B0[1];
            s[2] = pre * b3 * s[2] + dbu * B0[2];
            s[3] = pre * b4 * s[3] + dbu * B0[3];
            s[4] = pre * b5 * s[4] + dbu * B1[0];
            s[5] = pre * b6 * s[5] + dbu * B1[1];
            s[6] = pre * b7 * s[6] + dbu * B1[2];
            s[7] = pre * b8 * s[7] + dbu * B1[3];
        }
    } else {
        #pragma unroll 4
        for (int l = 0; l < LCHUNK; ++l) {
            float dl = __bfloat162float(*pD);
            float uv = __bfloat162float(*pU);
            f32x4 B0 = pB[0], B1 = pB[1];
            pD += DINNER; pU += DINNER; pB += 32;
            float dbu = dl * uv;
            sdl += dl;
            #pragma unroll
            for (int j = 0; j < 4; ++j) {
                float e = __builtin_amdgcn_exp2f(dl * A2[j]);
                s[j] = e * s[j] + dbu * B0[j];
            }
            #pragma unroll
            for (int j = 0; j < 4; ++j) {
                float e = __builtin_amdgcn_exp2f(dl * A2[4 + j]);
                s[4 + j] = e * s[4 + j] + dbu * B1[j];
            }
        }
    }
    float ap[8];
    #pragma unroll
    for (int n = 0; n < 8; ++n) ap[n] = __builtin_amdgcn_exp2f(sdl * A2[n]);

    float* o = AS + ((size_t)chunk * 4096 + ch) * 32 + n0;
    *(f32x4*)(o)      = *(f32x4*)&ap[0];
    *(f32x4*)(o + 4)  = *(f32x4*)&ap[4];
    *(f32x4*)(o + 16) = *(f32x4*)&s[0];
    *(f32x4*)(o + 20) = *(f32x4*)&s[4];
}

__global__ __launch_bounds__(256)
void scan_phase2(float* __restrict__ AS)
{
    const int idx = blockIdx.x * 256 + threadIdx.x;
    const int n   = idx & 15;
    const int ch  = idx >> 4;

    float s = 0.f;
    for (int cb = 0; cb < NCHUNK; cb += 16) {
        float av[16], sv[16];
        #pragma unroll
        for (int j = 0; j < 16; ++j) {
            size_t r = ((size_t)(cb + j) * 4096 + ch) * 32 + n;
            av[j] = AS[r];
            sv[j] = AS[r + 16];
        }
        #pragma unroll
        for (int j = 0; j < 16; ++j) {
            AS[((size_t)(cb + j) * 4096 + ch) * 32 + 16 + n] = s;
            s = av[j] * s + sv[j];
        }
    }
}

__global__ __launch_bounds__(256)
void scan_phase3(const bf16* __restrict__ delta, const bf16* __restrict__ u,
                 const float* __restrict__ xdbl, const bf16* __restrict__ xr,
                 const float* __restrict__ AS, const float* __restrict__ A_log,
                 const float* __restrict__ Dp, bf16* __restrict__ ybf)
{
    const int idx   = blockIdx.x * 256 + threadIdx.x;
    const int half  = idx & 1;
    const int ch    = idx >> 1;
    const int chunk = blockIdx.y;
    const int d     = ch & (DINNER - 1);
    const int b     = ch >> 11;
    const int n0    = half * 8;

    float A2[8], s[8];
    const f32x4* Arow = (const f32x4*)(A_log + d * DSTATE + n0);
    #pragma unroll
    for (int q = 0; q < 2; ++q) {
        f32x4 v = Arow[q];
        #pragma unroll
        for (int j = 0; j < 4; ++j) A2[q * 4 + j] = -__expf(v[j]) * LOG2E;
    }
    const float* ip = AS + ((size_t)chunk * 4096 + ch) * 32 + 16 + n0;
    *(f32x4*)&s[0] = *(const f32x4*)(ip);
    *(f32x4*)&s[4] = *(const f32x4*)(ip + 4);

    bool fastA = true;
    #pragma unroll
    for (int j = 0; j < 8; ++j)
        fastA &= fabsf(A2[j] + (float)(n0 + j + 1) * LOG2E)
                 < 0.01f * (float)(n0 + j + 1);

    const float Dd  = Dp[d];
    const long row0 = (long)b * L_SEQ + chunk * LCHUNK;

    const bf16*  pD = delta + row0 * DINNER + d;
    const bf16*  pU = u     + row0 * DINNER + d;
    const bf16*  pR = xr    + row0 * 4096 + 2048 + d;
    const f32x4* pB = (const f32x4*)(xdbl + row0 * 128 + 64 + n0);
    bf16*        pY = ybf   + row0 * DINNER + d;

    if (fastA) {
        #pragma unroll 4
        for (int l = 0; l < LCHUNK; ++l) {
            float dl = __bfloat162float(*pD);
            float uv = __bfloat162float(*pU);
            float rs = __bfloat162float(*pR);
            f32x4 B0 = pB[0], B1 = pB[1];
            f32x4 C0 = pB[4], C1 = pB[5];
            pD += DINNER; pU += DINNER; pR += 4096; pB += 32;
            float dbu = dl * uv;
            float b1 = __builtin_amdgcn_exp2f(-LOG2E * dl);   // exp(-dl)
            float b2 = b1 * b1, b3 = b2 * b1, b4 = b2 * b2;
            float b5 = b4 * b1, b6 = b4 * b2, b7 = b4 * b3, b8 = b4 * b4;
            float pre = half ? b8 : 1.f;
            float y0 = 0.f, y1 = 0.f;
            s[0] = pre * b1 * s[0] + dbu * B0[0];  y0 += s[0] * C0[0];
            s[1] = pre * b2 * s[1] + dbu * B0[1];  y0 += s[1] * C0[1];
            s[2] = pre * b3 * s[2] + dbu * B0[2];  y0 += s[2] * C0[2];
            s[3] = pre * b4 * s[3] + dbu * B0[3];  y0 += s[3] * C0[3];
            s[4] = pre * b5 * s[4] + dbu * B1[0];  y1 += s[4] * C1[0];
            s[5] = pre * b6 * s[5] + dbu * B1[1];  y1 += s[5] * C1[1];
            s[6] = pre * b7 * s[6] + dbu * B1[2];  y1 += s[6] * C1[2];
            s[7] = pre * b8 * s[7] + dbu * B1[3];  y1 += s[7] * C1[3];
            float yh = y0 + y1;
            float yt = yh + __shfl_xor(yh, 1);
            if (half == 0) {
                float yf = yt + uv * Dd;
                yf *= rs / (1.f + __builtin_amdgcn_exp2f(-LOG2E * rs));
                *pY = __float2bfloat16(yf);
            }
            pY += DINNER;
        }
    } else {
        #pragma unroll 4
        for (int l = 0; l < LCHUNK; ++l) {
            float dl = __bfloat162float(*pD);
            float uv = __bfloat162float(*pU);
            float rs = __bfloat162float(*pR);
            f32x4 B0 = pB[0], B1 = pB[1];
            f32x4 C0 = pB[4], C1 = pB[5];
            pD += DINNER; pU += DINNER; pR += 4096; pB += 32;
            float dbu = dl * uv;
            float y0 = 0.f, y1 = 0.f;
            #pragma unroll
            for (int j = 0; j < 4; ++j) {
                float e = __builtin_amdgcn_exp2f(dl * A2[j]);
                s[j] = e * s[j] + dbu * B0[j];
                y0 += s[j] * C0[j];
            }
            #pragma unroll
            for (int j = 0; j < 4; ++j) {
                float e = __builtin_amdgcn_exp2f(dl * A2[4 + j]);
                s[4 + j] = e * s[4 + j] + dbu * B1[j];
                y1 += s[4 + j] * C1[j];
            }
            float yh = y0 + y1;
            float yt = yh + __shfl_xor(yh, 1);
            if (half == 0) {
                float yf = yt + uv * Dd;
                yf *= rs / (1.f + __builtin_amdgcn_exp2f(-LOG2E * rs));
                *pY = __float2bfloat16(yf);
            }
            pY += DINNER;
        }
    }
}

// ---------------------------------------------------------------------------
extern "C" void kernel_launch(void* const* d_in, const int* in_sizes, int n_in,
                              void* d_out, int out_size, void* d_ws, size_t ws_size,
                              hipStream_t stream)
{
    const float* x      = (const float*)d_in[0];
    const float* W_in   = (const float*)d_in[1];
    const float* W_conv = (const float*)d_in[2];
    const float* b_conv = (const float*)d_in[3];
    const float* W_x    = (const float*)d_in[4];
    const float* W_dt   = (const float*)d_in[5];
    const float* b_dt   = (const float*)d_in[6];
    const float* A_log  = (const float*)d_in[7];
    const float* Dp     = (const float*)d_in[8];
    const float* W_out  = (const float*)d_in[9];
    float* out = (float*)d_out;

    char* ws = (char*)d_ws;
    size_t off = 0;
    auto alloc = [&](size_t bytes) {
        void* p = ws + off;
        off = (off + bytes + 255) & ~(size_t)255;
        return p;
    };
    bf16*  Xb    = (bf16*) alloc((size_t)MROWS * DMODEL * 2);
    bf16*  WinT  = (bf16*) alloc((size_t)4096  * DMODEL * 2);
    bf16*  xr    = (bf16*) alloc((size_t)MROWS * 4096  * 2);
    bf16*  ubf   = (bf16*) alloc((size_t)MROWS * DINNER * 2);
    bf16*  WxT   = (bf16*) alloc((size_t)128   * DINNER * 2);
    float* xdbl  = (float*)alloc((size_t)MROWS * 128 * 4);
    float* xdblp = (float*)alloc((size_t)4 * MROWS * 128 * 4);
    bf16*  drbf  = (bf16*) alloc((size_t)MROWS * 64 * 2);
    bf16*  WdtT  = (bf16*) alloc((size_t)DINNER * 64 * 2);
    bf16*  delta = (bf16*) alloc((size_t)MROWS * DINNER * 2);   // bf16 (R10-verified)
    bf16*  ybf   = (bf16*) alloc((size_t)MROWS * DINNER * 2);
    bf16*  WoutT = (bf16*) alloc((size_t)DMODEL * DINNER * 2);
    float* AS    = (float*)alloc((size_t)NCHUNK * 4096 * 32 * 4); // 32MB; reused
                                                                  // as GEMM4 partials

    dim3 tb(32, 8);
    transpose_bf16<<<dim3(128, 32), tb, 0, stream>>>(W_in,  WinT,  1024, 4096, 4096);
    transpose_bf16<<<dim3(4, 64),   tb, 0, stream>>>(W_x,   WxT,   2048, 96,   128);
    transpose_bf16<<<dim3(64, 2),   tb, 0, stream>>>(W_dt,  WdtT,  64,   2048, 2048);
    transpose_bf16<<<dim3(32, 64),  tb, 0, stream>>>(W_out, WoutT, 2048, 1024, 1024);
    convert_x_kernel<<<(MROWS * DMODEL) / 256, 256, 0, stream>>>(x, Xb);

    // GEMM1: x_and_res = Xb @ W_in -> xr bf16 (4096,4096) — 256² deep-prefetch
    gemm256<<<dim3(4096 / 256, MROWS / 256), 512, 0, stream>>>(
        Xb, WinT, xr, 4096, 1024, 1024, 1024);
    // conv + silu -> u bf16 (vectorized, 8 ch/thread)
    conv_silu_kernel<<<(MROWS * DINNER / 8) / 256, 256, 0, stream>>>(
        xr, W_conv, b_conv, ubf);
    // GEMM2: x_dbl = u @ W_x, split-K x4 -> partials
    gemm_bt<float, 0, true><<<dim3(1, MROWS / 128, 4), 256, 0, stream>>>(
        ubf, WxT, xdblp, nullptr, MROWS, 128, 512, 2048, 2048);
    reduce_xdbl<<<(MROWS * 128) / 256, 256, 0, stream>>>(xdblp, xdbl, drbf);
    // GEMM3: delta = softplus(delta_r @ W_dt + b_dt) -> bf16
    gemm_bt<bf16, 1><<<dim3(DINNER / 128, MROWS / 128), 256, 0, stream>>>(
        drbf, WdtT, delta, b_dt, MROWS, DINNER, 64, 64, 64);
    // chunked parallel selective scan -> ybf bf16
    scan_phase1<<<dim3(32, NCHUNK), 256, 0, stream>>>(delta, ubf, xdbl, A_log, AS);
    scan_phase2<<<256, 256, 0, stream>>>(AS);
    scan_phase3<<<dim3(32, NCHUNK), 256, 0, stream>>>(delta, ubf, xdbl, xr, AS,
                                                      A_log, Dp, ybf);
    // GEMM4: out = y @ W_out, split-K x2 into AS (free after scan), then reduce
    gemm_bt<float, 0, true><<<dim3(DMODEL / 128, MROWS / 128, 2), 256, 0, stream>>>(
        ybf, WoutT, (float*)AS, nullptr, MROWS, DMODEL, 1024, 2048, 2048);
    reduce_out<<<(MROWS * DMODEL) / 1024, 256, 0, stream>>>((float*)AS, out);
}

// Round 13
// 263.119 us; speedup vs baseline: 1.1582x; 1.0335x over previous
//
#include <hip/hip_runtime.h>
#include <hip/hip_bf16.h>

#define L_SEQ  2048
#define NBATCH 2
#define DMODEL 1024
#define DINNER 2048
#define DSTATE 16
#define DTRANK 64
#define MROWS  (L_SEQ * NBATCH)   // 4096
#define NCHUNK 64
#define LCHUNK 32                 // L_SEQ / NCHUNK
#define LOG2E  1.44269504f

using bf16 = __hip_bfloat16;
typedef short s16x8 __attribute__((ext_vector_type(8)));   // 8 bf16 = 16B
typedef float f32x4 __attribute__((ext_vector_type(4)));

__device__ __forceinline__ void gload_lds16(const bf16* g, bf16* l) {
    __builtin_amdgcn_global_load_lds(
        (const __attribute__((address_space(1))) void*)g,
        (__attribute__((address_space(3))) void*)l, 16, 0, 0);
}

__device__ __forceinline__ float bf2f(short v) {
    return __uint_as_float(((unsigned)(unsigned short)v) << 16);
}

// ---------------------------------------------------------------------------
// 256x256 8-phase MFMA GEMM: T2 swizzle + counted vmcnt + setprio + fragment
// reuse + deep prefetch (all 4 STAGEs of tile t+1 at top of iter t; waits
// WB(10)/WB(8)/WB(4)). XCD RECT swizzle for the 16x16 grid: assuming
// round-robin block->XCD dispatch (XCD = orig%8), each XCD gets a 4x8
// sub-rect so its A(2MB)+B(4MB) panels ~fit the 4MB per-XCD L2 (vs 2x16
// slab = 9MB before). C(M,N) = A(M,K) @ Bt(N,K)^T, bf16 in/out, fp32 acc.
// ---------------------------------------------------------------------------
__global__ __launch_bounds__(512, 2)
void gemm256(const bf16* __restrict__ A, const bf16* __restrict__ Bt,
             bf16* __restrict__ C, int N, int K, int lda, int ldb)
{
    __shared__ __align__(16) bf16 As[2][256 * 64];
    __shared__ __align__(16) bf16 Bs[2][256 * 64];

    const int tid  = threadIdx.x;
    const int wid  = tid >> 6;
    const int lane = tid & 63;
    const int wr = wid >> 2, wc = wid & 3;       // 2x4 wave grid
    const int fr = lane & 15, fk = lane >> 4;

    // rect swizzle (grid is always 16x16 for GEMM1)
    const int orig = blockIdx.y * gridDim.x + blockIdx.x;
    const int xcd  = orig & 7, k = orig >> 3;    // k in [0,32)
    const int byi  = (xcd >> 1) * 4 + (k >> 3);  // 4-row band
    const int bxi  = (xcd & 1) * 8 + (k & 7);    // 8-col band
    const long bm = (long)byi * 256;
    const long bn = (long)bxi * 256;

    const int q0 = tid, q1 = tid + 512;
    const int r0 = q0 >> 3, r1 = q1 >> 3;
    const int c0 = ((q0 & 7) ^ (r0 & 7)) << 3;
    const int c1 = ((q1 & 7) ^ (r1 & 7)) << 3;
    const bf16* sA0h0 = A  + (bm + r0)       * (long)lda + c0;
    const bf16* sA1h0 = A  + (bm + r1)       * (long)lda + c1;
    const bf16* sA0h1 = A  + (bm + 128 + r0) * (long)lda + c0;
    const bf16* sA1h1 = A  + (bm + 128 + r1) * (long)lda + c1;
    const bf16* sB0h0 = Bt + (bn + r0)       * (long)ldb + c0;
    const bf16* sB1h0 = Bt + (bn + r1)       * (long)ldb + c1;
    const bf16* sB0h1 = Bt + (bn + 128 + r0) * (long)ldb + c0;
    const bf16* sB1h1 = Bt + (bn + 128 + r1) * (long)ldb + c1;
    const int dst0 = wid * 512;
    const int dst1 = 4096 + wid * 512;

    const int o0   = ((fk ^ (fr & 7)) << 3);
    const int o1   = o0 ^ 32;
    const int rA64 = (wr * 64 + fr) * 64;
    const int rB64 = (wc * 32 + fr) * 64;

    f32x4 acc[8][4] = {};
    s16x8 af[4][2], bf0[2][2], bf1[2][2];
    const int nt = K >> 6;

#define STAGE(ARR, BUF, H, P0, P1) do {                    \
        gload_lds16(P0, &ARR[BUF][(H) * 8192 + dst0]);     \
        gload_lds16(P1, &ARR[BUF][(H) * 8192 + dst1]);     \
        P0 += 64; P1 += 64;                                \
    } while (0)

#define LOADA(MH, CUR) do {                                   \
        const bf16* ab = &As[CUR][rA64 + (MH) * 8192];        \
        _Pragma("unroll") for (int m = 0; m < 4; ++m) {       \
            af[m][0] = *(const s16x8*)&ab[m * 1024 + o0];     \
            af[m][1] = *(const s16x8*)&ab[m * 1024 + o1]; }   \
    } while (0)

#define LOADB(NH, CUR, BF) do {                               \
        const bf16* bb = &Bs[CUR][rB64 + (NH) * 8192];        \
        _Pragma("unroll") for (int n = 0; n < 2; ++n) {       \
            BF[n][0] = *(const s16x8*)&bb[n * 1024 + o0];     \
            BF[n][1] = *(const s16x8*)&bb[n * 1024 + o1]; }   \
    } while (0)

#define MFMAQ(MH, NH, BF) do {                                               \
        __builtin_amdgcn_s_setprio(1);                                       \
        _Pragma("unroll") for (int ks = 0; ks < 2; ++ks)                     \
        _Pragma("unroll") for (int m = 0; m < 4; ++m)                        \
        _Pragma("unroll") for (int n = 0; n < 2; ++n)                        \
            acc[(MH) * 4 + m][(NH) * 2 + n] =                                \
                __builtin_amdgcn_mfma_f32_16x16x32_bf16(                     \
                    af[m][ks], BF[n][ks], acc[(MH) * 4 + m][(NH) * 2 + n],   \
                    0, 0, 0);                                                \
        __builtin_amdgcn_s_setprio(0);                                       \
    } while (0)

#define WB(NV) asm volatile("s_waitcnt vmcnt(" #NV ")\n\ts_barrier" ::: "memory")

    STAGE(As, 0, 0, sA0h0, sA1h0);
    STAGE(Bs, 0, 0, sB0h0, sB1h0);
    STAGE(Bs, 0, 1, sB0h1, sB1h1);
    STAGE(As, 0, 1, sA0h1, sA1h1);
    WB(4);                                   // A-h0, B-h0 of tile 0 ready

    int cur = 0;
    for (int t = 0; t < nt - 1; ++t) {
        STAGE(As, cur ^ 1, 0, sA0h0, sA1h0);
        STAGE(Bs, cur ^ 1, 0, sB0h0, sB1h0);
        STAGE(Bs, cur ^ 1, 1, sB0h1, sB1h1);
        STAGE(As, cur ^ 1, 1, sA0h1, sA1h1);
        LOADA(0, cur); LOADB(0, cur, bf0);
        MFMAQ(0, 0, bf0);  WB(10);           // B-h1 of t ready (issued iter t-1)
        LOADB(1, cur, bf1);
        MFMAQ(0, 1, bf1);  WB(8);            // A-h1 of t ready
        LOADA(1, cur);
        MFMAQ(1, 1, bf1);
        MFMAQ(1, 0, bf0);  WB(4);            // A-h0,B-h0 of t+1 ready
        cur ^= 1;
    }
    LOADA(0, cur); LOADB(0, cur, bf0);
    MFMAQ(0, 0, bf0);  WB(2);
    LOADB(1, cur, bf1);
    MFMAQ(0, 1, bf1);  WB(0);
    LOADA(1, cur);
    MFMAQ(1, 1, bf1);
    MFMAQ(1, 0, bf0);

#undef STAGE
#undef LOADA
#undef LOADB
#undef MFMAQ
#undef WB

    #pragma unroll
    for (int mh = 0; mh < 2; ++mh)
    #pragma unroll
    for (int m = 0; m < 4; ++m)
    #pragma unroll
    for (int nh = 0; nh < 2; ++nh)
    #pragma unroll
    for (int n = 0; n < 2; ++n) {
        f32x4 v = acc[mh * 4 + m][nh * 2 + n];
        long row0 = bm + wr * 64 + mh * 128 + m * 16 + fk * 4;
        long col  = bn + wc * 32 + nh * 128 + n * 16 + fr;
        #pragma unroll
        for (int j = 0; j < 4; ++j)
            C[(row0 + j) * N + col] = __float2bfloat16(v[j]);
    }
}

// ---------------------------------------------------------------------------
// MFMA bf16 GEMM: 128x128 tile, BK=32, 2-phase double-buffered (small shapes).
// ---------------------------------------------------------------------------
template<typename OutT, int EPI, bool SPLITK = false>
__global__ __launch_bounds__(256)
void gemm_bt(const bf16* __restrict__ A, const bf16* __restrict__ Bt,
             OutT* __restrict__ C, const float* __restrict__ bias,
             int M, int N, int K, int lda, int ldb)
{
    __shared__ __align__(16) bf16 As[2][128 * 32];
    __shared__ __align__(16) bf16 Bs[2][128 * 32];

    const int tid  = threadIdx.x;
    const int wave = tid >> 6;
    const int lane = tid & 63;
    const int wr = wave >> 1, wc = wave & 1;
    const int fr = lane & 15, fk = lane >> 4;

    const int nbx = gridDim.x;
    const int nwg = nbx * gridDim.y;
    int id  = blockIdx.y * nbx + blockIdx.x;
    if (nwg >= 8) {
        int cpx = nwg >> 3;
        id = (id & 7) * cpx + (id >> 3);
    }
    const int bxi = id % nbx, byi = id / nbx;
    const long bm = (long)byi * 128;
    const long bn = (long)bxi * 128;

    if constexpr (SPLITK) {
        long ko = (long)blockIdx.z * K;
        A  += ko;
        Bt += ko;
        C  += (size_t)blockIdx.z * M * N;
    }

    const int r0 = tid >> 2,         c0 = (tid & 3) << 3;
    const int r1 = (256 + tid) >> 2, c1 = c0;
    const bf16* pA0 = A  + (bm + r0) * (long)lda + c0;
    const bf16* pA1 = A  + (bm + r1) * (long)lda + c1;
    const bf16* pB0 = Bt + (bn + r0) * (long)ldb + c0;
    const bf16* pB1 = Bt + (bn + r1) * (long)ldb + c1;
    const size_t ld0 = (size_t)(wave * 64) * 8;
    const size_t ld1 = (size_t)(256 + wave * 64) * 8;

    f32x4 acc[4][4] = {};
    const int nt = K >> 5;

    gload_lds16(pA0, &As[0][ld0]);
    gload_lds16(pB0, &Bs[0][ld0]);
    gload_lds16(pA1, &As[0][ld1]);
    gload_lds16(pB1, &Bs[0][ld1]);
    pA0 += 32; pA1 += 32; pB0 += 32; pB1 += 32;
    __syncthreads();

    int cur = 0;
    for (int t = 0; t < nt; ++t) {
        if (t + 1 < nt) {
            gload_lds16(pA0, &As[cur ^ 1][ld0]);
            gload_lds16(pB0, &Bs[cur ^ 1][ld0]);
            gload_lds16(pA1, &As[cur ^ 1][ld1]);
            gload_lds16(pB1, &Bs[cur ^ 1][ld1]);
            pA0 += 32; pA1 += 32; pB0 += 32; pB1 += 32;
        }

        s16x8 afrag[4], bfrag[4];
        #pragma unroll
        for (int m = 0; m < 4; ++m)
            afrag[m] = *(const s16x8*)&As[cur][(wr * 64 + m * 16 + fr) * 32 + fk * 8];
        #pragma unroll
        for (int n = 0; n < 4; ++n)
            bfrag[n] = *(const s16x8*)&Bs[cur][(wc * 64 + n * 16 + fr) * 32 + fk * 8];

        #pragma unroll
        for (int m = 0; m < 4; ++m)
            #pragma unroll
            for (int n = 0; n < 4; ++n)
                acc[m][n] = __builtin_amdgcn_mfma_f32_16x16x32_bf16(
                    afrag[m], bfrag[n], acc[m][n], 0, 0, 0);

        __syncthreads();
        cur ^= 1;
    }

    #pragma unroll
    for (int m = 0; m < 4; ++m)
        #pragma unroll
        for (int n = 0; n < 4; ++n) {
            f32x4 v = acc[m][n];
            long row0 = bm + wr * 64 + m * 16 + fk * 4;
            long col  = bn + wc * 64 + n * 16 + fr;
            #pragma unroll
            for (int j = 0; j < 4; ++j) {
                float val = v[j];
                if (EPI == 1) {
                    val += bias[col];
                    val = (val > 20.f) ? val : log1pf(__expf(val));
                }
                if constexpr (sizeof(OutT) == 2)
                    C[(row0 + j) * N + col] = __float2bfloat16(val);
                else
                    C[(row0 + j) * N + col] = val;
            }
        }
}

// ---------------------------------------------------------------------------
// Fused preprocessing: 4 weight transposes + convert_x in ONE kernel
// (range-dispatched on blockIdx.x). Saves 4 dependent-launch gaps.
// ---------------------------------------------------------------------------
__device__ __forceinline__ void do_transpose(
    const float* __restrict__ in, bf16* __restrict__ out,
    int R, int C, int Cpad, int bx, int by, int tx, int ty)
{
    __shared__ float tile[32][33];
    int cb = bx * 32, rb = by * 32;
    #pragma unroll
    for (int i = 0; i < 4; ++i) {
        int r = rb + ty + i * 8, c = cb + tx;
        tile[ty + i * 8][tx] = (r < R && c < C) ? in[(long)r * C + c] : 0.f;
    }
    __syncthreads();
    #pragma unroll
    for (int i = 0; i < 4; ++i) {
        int oc = cb + ty + i * 8;
        int orow = rb + tx;
        if (oc < Cpad && orow < R)
            out[(long)oc * R + orow] = __float2bfloat16(tile[tx][ty + i * 8]);
    }
}

__global__ __launch_bounds__(256)
void prep_kernel(const float* __restrict__ W_in,  bf16* __restrict__ WinT,
                 const float* __restrict__ W_x,   bf16* __restrict__ WxT,
                 const float* __restrict__ W_dt,  bf16* __restrict__ WdtT,
                 const float* __restrict__ W_out, bf16* __restrict__ WoutT,
                 const float* __restrict__ x,     bf16* __restrict__ Xb)
{
    const int b  = blockIdx.x;
    const int t  = threadIdx.x;
    const int tx = t & 31, ty = t >> 5;

    if (b < 4096) {                       // W_in (1024,4096) -> (4096,1024)
        do_transpose(W_in, WinT, 1024, 4096, 4096, b & 127, b >> 7, tx, ty);
    } else if (b < 4352) {                // W_x (2048,96) -> (128,2048)
        int b2 = b - 4096;
        do_transpose(W_x, WxT, 2048, 96, 128, b2 & 3, b2 >> 2, tx, ty);
    } else if (b < 4480) {                // W_dt (64,2048) -> (2048,64)
        int b3 = b - 4352;
        do_transpose(W_dt, WdtT, 64, 2048, 2048, b3 & 63, b3 >> 6, tx, ty);
    } else if (b < 6528) {                // W_out (2048,1024) -> (1024,2048)
        int b4 = b - 4480;
        do_transpose(W_out, WoutT, 2048, 1024, 1024, b4 & 31, b4 >> 5, tx, ty);
    } else {                              // x (L,B,DM) -> Xb (B*L,DM) bf16
        int idx = (b - 6528) * 256 + t;   // MROWS*DMODEL ids
        int c   = idx & (DMODEL - 1);
        int row = idx >> 10;
        int l   = row & (L_SEQ - 1);
        int bb  = row >> 11;
        Xb[idx] = __float2bfloat16(x[((l * NBATCH + bb) << 10) | c]);
    }
}

// depthwise causal conv (d_conv=4) + silu, 8 channels per thread (vectorized)
__global__ void conv_silu_kernel(const bf16* __restrict__ xr, const float* __restrict__ Wc,
                                 const float* __restrict__ bc, bf16* __restrict__ u)
{
    int idx = blockIdx.x * 256 + threadIdx.x;   // MROWS*DINNER/8 threads
    int g   = idx & 255;
    int row = idx >> 8;
    int c   = g << 3;
    int l   = row & (L_SEQ - 1);

    float acc[8];
    f32x4 bi0 = *(const f32x4*)(bc + c);
    f32x4 bi1 = *(const f32x4*)(bc + c + 4);
    #pragma unroll
    for (int j = 0; j < 4; ++j) { acc[j] = bi0[j]; acc[4 + j] = bi1[j]; }

    f32x4 w[8];
    #pragma unroll
    for (int j = 0; j < 8; ++j) w[j] = *(const f32x4*)(Wc + (c + j) * 4);

    #pragma unroll
    for (int t = 0; t < 4; ++t) {
        int ll = l - 3 + t;
        if (ll >= 0) {
            s16x8 v = *(const s16x8*)(xr + (long)(row - 3 + t) * 4096 + c);
            #pragma unroll
            for (int j = 0; j < 8; ++j)
                acc[j] += bf2f(v[j]) * w[j][t];
        }
    }
    s16x8 o;
    #pragma unroll
    for (int j = 0; j < 8; ++j) {
        float a = acc[j];
        float s = a / (1.f + __builtin_amdgcn_exp2f(-LOG2E * a));
        bf16 h = __float2bfloat16(s);
        o[j] = *(short*)&h;
    }
    *(s16x8*)(u + (long)row * DINNER + c) = o;
}

__global__ void reduce_xdbl(const float* __restrict__ part, float* __restrict__ xdbl,
                            bf16* __restrict__ drbf)
{
    int idx = blockIdx.x * 256 + threadIdx.x;
    const size_t stride = (size_t)MROWS * 128;
    float v = part[idx] + part[idx + stride] + part[idx + 2 * stride]
            + part[idx + 3 * stride];
    xdbl[idx] = v;
    int col = idx & 127;
    if (col < 64)
        drbf[(idx >> 7) * 64 + col] = __float2bfloat16(v);
}

__global__ void reduce_out(const float* __restrict__ part, float* __restrict__ out)
{
    int i = blockIdx.x * 256 + threadIdx.x;
    f32x4 a = ((const f32x4*)part)[i];
    f32x4 b = ((const f32x4*)(part + (size_t)MROWS * DMODEL))[i];
    ((f32x4*)out)[i] = a + b;
}

// ---------------------------------------------------------------------------
// Chunked parallel selective scan — round-9 form (frozen; two restructures
// regressed). delta bf16 (verified absmax-neutral). FAST PATH (runtime-
// checked): A[d][n] = -(n+1) => decays are powers of exp(-dl).
// ---------------------------------------------------------------------------
__global__ __launch_bounds__(256)
void scan_phase1(const bf16* __restrict__ delta, const bf16* __restrict__ u,
                 const float* __restrict__ xdbl, const float* __restrict__ A_log,
                 float* __restrict__ AS)
{
    const int idx   = blockIdx.x * 256 + threadIdx.x;
    const int half  = idx & 1;
    const int ch    = idx >> 1;
    const int chunk = blockIdx.y;
    const int d     = ch & (DINNER - 1);
    const int b     = ch >> 11;
    const int n0    = half * 8;

    float A2[8], s[8];
    const f32x4* Arow = (const f32x4*)(A_log + d * DSTATE + n0);
    #pragma unroll
    for (int q = 0; q < 2; ++q) {
        f32x4 v = Arow[q];
        #pragma unroll
        for (int j = 0; j < 4; ++j) A2[q * 4 + j] = -__expf(v[j]) * LOG2E;
    }
    #pragma unroll
    for (int n = 0; n < 8; ++n) s[n] = 0.f;
    float sdl = 0.f;

    bool fastA = true;
    #pragma unroll
    for (int j = 0; j < 8; ++j)
        fastA &= fabsf(A2[j] + (float)(n0 + j + 1) * LOG2E)
                 < 0.01f * (float)(n0 + j + 1);

    const long row0 = (long)b * L_SEQ + chunk * LCHUNK;
    const bf16*  pD = delta + row0 * DINNER + d;
    const bf16*  pU = u     + row0 * DINNER + d;
    const f32x4* pB = (const f32x4*)(xdbl + row0 * 128 + 64 + n0);

    if (fastA) {
        #pragma unroll 4
        for (int l = 0; l < LCHUNK; ++l) {
            float dl = __bfloat162float(*pD);
            float uv = __bfloat162float(*pU);
            f32x4 B0 = pB[0], B1 = pB[1];
            pD += DINNER; pU += DINNER; pB += 32;
            float dbu = dl * uv;
            sdl += dl;
            float b1 = __builtin_amdgcn_exp2f(-LOG2E * dl);   // exp(-dl)
            float b2 = b1 * b1, b3 = b2 * b1, b4 = b2 * b2;
            float b5 = b4 * b1, b6 = b4 * b2, b7 = b4 * b3, b8 = b4 * b4;
            float pre = half ? b8 : 1.f;
            s[0] = pre * b1 * s[0] + dbu * B0[0];
            s[1] = pre * b2 * s[1] + dbu * B0[1];
            s[2] = pre * b3 * s[2] + dbu * B0[2];
            s[3] = pre * b4 * s[3] + dbu * B0[3];
            s[4] = pre * b5 * s[4] + dbu * B1[0];
            s[5] = pre * b6 * s[5] + dbu * B1[1];
            s[6] = pre * b7 * s[6] + dbu * B1[2];
            s[7] = pre * b8 * s[7] + dbu * B1[3];
        }
    } else {
        #pragma unroll 4
        for (int l = 0; l < LCHUNK; ++l) {
            float dl = __bfloat162float(*pD);
            float uv = __bfloat162float(*pU);
            f32x4 B0 = pB[0], B1 = pB[1];
            pD += DINNER; pU += DINNER; pB += 32;
            float dbu = dl * uv;
            sdl += dl;
            #pragma unroll
            for (int j = 0; j < 4; ++j) {
                float e = __builtin_amdgcn_exp2f(dl * A2[j]);
                s[j] = e * s[j] + dbu * B0[j];
            }
            #pragma unroll
            for (int j = 0; j < 4; ++j) {
                float e = __builtin_amdgcn_exp2f(dl * A2[4 + j]);
                s[4 + j] = e * s[4 + j] + dbu * B1[j];
            }
        }
    }
    float ap[8];
    #pragma unroll
    for (int n = 0; n < 8; ++n) ap[n] = __builtin_amdgcn_exp2f(sdl * A2[n]);

    float* o = AS + ((size_t)chunk * 4096 + ch) * 32 + n0;
    *(f32x4*)(o)      = *(f32x4*)&ap[0];
    *(f32x4*)(o + 4)  = *(f32x4*)&ap[4];
    *(f32x4*)(o + 16) = *(f32x4*)&s[0];
    *(f32x4*)(o + 20) = *(f32x4*)&s[4];
}

__global__ __launch_bounds__(256)
void scan_phase2(float* __restrict__ AS)
{
    const int idx = blockIdx.x * 256 + threadIdx.x;
    const int n   = idx & 15;
    const int ch  = idx >> 4;

    float s = 0.f;
    for (int cb = 0; cb < NCHUNK; cb += 16) {
        float av[16], sv[16];
        #pragma unroll
        for (int j = 0; j < 16; ++j) {
            size_t r = ((size_t)(cb + j) * 4096 + ch) * 32 + n;
            av[j] = AS[r];
            sv[j] = AS[r + 16];
        }
        #pragma unroll
        for (int j = 0; j < 16; ++j) {
            AS[((size_t)(cb + j) * 4096 + ch) * 32 + 16 + n] = s;
            s = av[j] * s + sv[j];
        }
    }
}

__global__ __launch_bounds__(256)
void scan_phase3(const bf16* __restrict__ delta, const bf16* __restrict__ u,
                 const float* __restrict__ xdbl, const bf16* __restrict__ xr,
                 const float* __restrict__ AS, const float* __restrict__ A_log,
                 const float* __restrict__ Dp, bf16* __restrict__ ybf)
{
    const int idx   = blockIdx.x * 256 + threadIdx.x;
    const int half  = idx & 1;
    const int ch    = idx >> 1;
    const int chunk = blockIdx.y;
    const int d     = ch & (DINNER - 1);
    const int b     = ch >> 11;
    const int n0    = half * 8;

    float A2[8], s[8];
    const f32x4* Arow = (const f32x4*)(A_log + d * DSTATE + n0);
    #pragma unroll
    for (int q = 0; q < 2; ++q) {
        f32x4 v = Arow[q];
        #pragma unroll
        for (int j = 0; j < 4; ++j) A2[q * 4 + j] = -__expf(v[j]) * LOG2E;
    }
    const float* ip = AS + ((size_t)chunk * 4096 + ch) * 32 + 16 + n0;
    *(f32x4*)&s[0] = *(const f32x4*)(ip);
    *(f32x4*)&s[4] = *(const f32x4*)(ip + 4);

    bool fastA = true;
    #pragma unroll
    for (int j = 0; j < 8; ++j)
        fastA &= fabsf(A2[j] + (float)(n0 + j + 1) * LOG2E)
                 < 0.01f * (float)(n0 + j + 1);

    const float Dd  = Dp[d];
    const long row0 = (long)b * L_SEQ + chunk * LCHUNK;

    const bf16*  pD = delta + row0 * DINNER + d;
    const bf16*  pU = u     + row0 * DINNER + d;
    const bf16*  pR = xr    + row0 * 4096 + 2048 + d;
    const f32x4* pB = (const f32x4*)(xdbl + row0 * 128 + 64 + n0);
    bf16*        pY = ybf   + row0 * DINNER + d;

    if (fastA) {
        #pragma unroll 4
        for (int l = 0; l < LCHUNK; ++l) {
            float dl = __bfloat162float(*pD);
            float uv = __bfloat162float(*pU);
            float rs = __bfloat162float(*pR);
            f32x4 B0 = pB[0], B1 = pB[1];
            f32x4 C0 = pB[4], C1 = pB[5];
            pD += DINNER; pU += DINNER; pR += 4096; pB += 32;
            float dbu = dl * uv;
            float b1 = __builtin_amdgcn_exp2f(-LOG2E * dl);   // exp(-dl)
            float b2 = b1 * b1, b3 = b2 * b1, b4 = b2 * b2;
            float b5 = b4 * b1, b6 = b4 * b2, b7 = b4 * b3, b8 = b4 * b4;
            float pre = half ? b8 : 1.f;
            float y0 = 0.f, y1 = 0.f;
            s[0] = pre * b1 * s[0] + dbu * B0[0];  y0 += s[0] * C0[0];
            s[1] = pre * b2 * s[1] + dbu * B0[1];  y0 += s[1] * C0[1];
            s[2] = pre * b3 * s[2] + dbu * B0[2];  y0 += s[2] * C0[2];
            s[3] = pre * b4 * s[3] + dbu * B0[3];  y0 += s[3] * C0[3];
            s[4] = pre * b5 * s[4] + dbu * B1[0];  y1 += s[4] * C1[0];
            s[5] = pre * b6 * s[5] + dbu * B1[1];  y1 += s[5] * C1[1];
            s[6] = pre * b7 * s[6] + dbu * B1[2];  y1 += s[6] * C1[2];
            s[7] = pre * b8 * s[7] + dbu * B1[3];  y1 += s[7] * C1[3];
            float yh = y0 + y1;
            float yt = yh + __shfl_xor(yh, 1);
            if (half == 0) {
                float yf = yt + uv * Dd;
                yf *= rs / (1.f + __builtin_amdgcn_exp2f(-LOG2E * rs));
                *pY = __float2bfloat16(yf);
            }
            pY += DINNER;
        }
    } else {
        #pragma unroll 4
        for (int l = 0; l < LCHUNK; ++l) {
            float dl = __bfloat162float(*pD);
            float uv = __bfloat162float(*pU);
            float rs = __bfloat162float(*pR);
            f32x4 B0 = pB[0], B1 = pB[1];
            f32x4 C0 = pB[4], C1 = pB[5];
            pD += DINNER; pU += DINNER; pR += 4096; pB += 32;
            float dbu = dl * uv;
            float y0 = 0.f, y1 = 0.f;
            #pragma unroll
            for (int j = 0; j < 4; ++j) {
                float e = __builtin_amdgcn_exp2f(dl * A2[j]);
                s[j] = e * s[j] + dbu * B0[j];
                y0 += s[j] * C0[j];
            }
            #pragma unroll
            for (int j = 0; j < 4; ++j) {
                float e = __builtin_amdgcn_exp2f(dl * A2[4 + j]);
                s[4 + j] = e * s[4 + j] + dbu * B1[j];
                y1 += s[4 + j] * C1[j];
            }
            float yh = y0 + y1;
            float yt = yh + __shfl_xor(yh, 1);
            if (half == 0) {
                float yf = yt + uv * Dd;
                yf *= rs / (1.f + __builtin_amdgcn_exp2f(-LOG2E * rs));
                *pY = __float2bfloat16(yf);
            }
            pY += DINNER;
        }
    }
}

// ---------------------------------------------------------------------------
extern "C" void kernel_launch(void* const* d_in, const int* in_sizes, int n_in,
                              void* d_out, int out_size, void* d_ws, size_t ws_size,
                              hipStream_t stream)
{
    const float* x      = (const float*)d_in[0];
    const float* W_in   = (const float*)d_in[1];
    const float* W_conv = (const float*)d_in[2];
    const float* b_conv = (const float*)d_in[3];
    const float* W_x    = (const float*)d_in[4];
    const float* W_dt   = (const float*)d_in[5];
    const float* b_dt   = (const float*)d_in[6];
    const float* A_log  = (const float*)d_in[7];
    const float* Dp     = (const float*)d_in[8];
    const float* W_out  = (const float*)d_in[9];
    float* out = (float*)d_out;

    char* ws = (char*)d_ws;
    size_t off = 0;
    auto alloc = [&](size_t bytes) {
        void* p = ws + off;
        off = (off + bytes + 255) & ~(size_t)255;
        return p;
    };
    bf16*  Xb    = (bf16*) alloc((size_t)MROWS * DMODEL * 2);
    bf16*  WinT  = (bf16*) alloc((size_t)4096  * DMODEL * 2);
    bf16*  xr    = (bf16*) alloc((size_t)MROWS * 4096  * 2);
    bf16*  ubf   = (bf16*) alloc((size_t)MROWS * DINNER * 2);
    bf16*  WxT   = (bf16*) alloc((size_t)128   * DINNER * 2);
    float* xdbl  = (float*)alloc((size_t)MROWS * 128 * 4);
    float* xdblp = (float*)alloc((size_t)4 * MROWS * 128 * 4);
    bf16*  drbf  = (bf16*) alloc((size_t)MROWS * 64 * 2);
    bf16*  WdtT  = (bf16*) alloc((size_t)DINNER * 64 * 2);
    bf16*  delta = (bf16*) alloc((size_t)MROWS * DINNER * 2);   // bf16
    bf16*  ybf   = (bf16*) alloc((size_t)MROWS * DINNER * 2);
    bf16*  WoutT = (bf16*) alloc((size_t)DMODEL * DINNER * 2);
    float* AS    = (float*)alloc((size_t)NCHUNK * 4096 * 32 * 4); // 32MB; reused
                                                                  // as GEMM4 partials

    // fused prep: 4 transposes + convert_x (6528 + 16384 blocks)
    prep_kernel<<<6528 + (MROWS * DMODEL) / 256, 256, 0, stream>>>(
        W_in, WinT, W_x, WxT, W_dt, WdtT, W_out, WoutT, x, Xb);

    // GEMM1: x_and_res = Xb @ W_in -> xr bf16 (4096,4096) — 256² deep-prefetch
    gemm256<<<dim3(4096 / 256, MROWS / 256), 512, 0, stream>>>(
        Xb, WinT, xr, 4096, 1024, 1024, 1024);
    // conv + silu -> u bf16 (vectorized, 8 ch/thread)
    conv_silu_kernel<<<(MROWS * DINNER / 8) / 256, 256, 0, stream>>>(
        xr, W_conv, b_conv, ubf);
    // GEMM2: x_dbl = u @ W_x, split-K x4 -> partials
    gemm_bt<float, 0, true><<<dim3(1, MROWS / 128, 4), 256, 0, stream>>>(
        ubf, WxT, xdblp, nullptr, MROWS, 128, 512, 2048, 2048);
    reduce_xdbl<<<(MROWS * 128) / 256, 256, 0, stream>>>(xdblp, xdbl, drbf);
    // GEMM3: delta = softplus(delta_r @ W_dt + b_dt) -> bf16
    gemm_bt<bf16, 1><<<dim3(DINNER / 128, MROWS / 128), 256, 0, stream>>>(
        drbf, WdtT, delta, b_dt, MROWS, DINNER, 64, 64, 64);
    // chunked parallel selective scan -> ybf bf16
    scan_phase1<<<dim3(32, NCHUNK), 256, 0, stream>>>(delta, ubf, xdbl, A_log, AS);
    scan_phase2<<<256, 256, 0, stream>>>(AS);
    scan_phase3<<<dim3(32, NCHUNK), 256, 0, stream>>>(delta, ubf, xdbl, xr, AS,
                                                      A_log, Dp, ybf);
    // GEMM4: out = y @ W_out, split-K x2 into AS (free after scan), then reduce
    gemm_bt<float, 0, true><<<dim3(DMODEL / 128, MROWS / 128, 2), 256, 0, stream>>>(
        ybf, WoutT, (float*)AS, nullptr, MROWS, DMODEL, 1024, 2048, 2048);
    reduce_out<<<(MROWS * DMODEL) / 1024, 256, 0, stream>>>((float*)AS, out);
}

// Round 14
// 260.761 us; speedup vs baseline: 1.1686x; 1.0090x over previous
//
#include <hip/hip_runtime.h>
#include <hip/hip_bf16.h>

#define L_SEQ  2048
#define NBATCH 2
#define DMODEL 1024
#define DINNER 2048
#define DSTATE 16
#define DTRANK 64
#define MROWS  (L_SEQ * NBATCH)   // 4096
#define NCHUNK 64
#define LCHUNK 32                 // L_SEQ / NCHUNK
#define LOG2E  1.44269504f

using bf16 = __hip_bfloat16;
typedef short s16x8 __attribute__((ext_vector_type(8)));   // 8 bf16 = 16B
typedef float f32x4 __attribute__((ext_vector_type(4)));

__device__ __forceinline__ void gload_lds16(const bf16* g, bf16* l) {
    __builtin_amdgcn_global_load_lds(
        (const __attribute__((address_space(1))) void*)g,
        (__attribute__((address_space(3))) void*)l, 16, 0, 0);
}

__device__ __forceinline__ float bf2f(short v) {
    return __uint_as_float(((unsigned)(unsigned short)v) << 16);
}

// ---------------------------------------------------------------------------
// 256x256 8-phase MFMA GEMM: T2 swizzle + counted vmcnt + setprio + fragment
// reuse + deep prefetch (all 4 STAGEs of tile t+1 at top of iter t; waits
// WB(10)/WB(8)/WB(4)). XCD RECT swizzle: each XCD gets a 4x8 sub-rect of the
// 16x16 grid. C(M,N) = A(M,K) @ Bt(N,K)^T, bf16 in/out, fp32 acc.
// ---------------------------------------------------------------------------
__global__ __launch_bounds__(512, 2)
void gemm256(const bf16* __restrict__ A, const bf16* __restrict__ Bt,
             bf16* __restrict__ C, int N, int K, int lda, int ldb)
{
    __shared__ __align__(16) bf16 As[2][256 * 64];
    __shared__ __align__(16) bf16 Bs[2][256 * 64];

    const int tid  = threadIdx.x;
    const int wid  = tid >> 6;
    const int lane = tid & 63;
    const int wr = wid >> 2, wc = wid & 3;       // 2x4 wave grid
    const int fr = lane & 15, fk = lane >> 4;

    // rect swizzle (grid is always 16x16 for GEMM1)
    const int orig = blockIdx.y * gridDim.x + blockIdx.x;
    const int xcd  = orig & 7, k = orig >> 3;    // k in [0,32)
    const int byi  = (xcd >> 1) * 4 + (k >> 3);  // 4-row band
    const int bxi  = (xcd & 1) * 8 + (k & 7);    // 8-col band
    const long bm = (long)byi * 256;
    const long bn = (long)bxi * 256;

    const int q0 = tid, q1 = tid + 512;
    const int r0 = q0 >> 3, r1 = q1 >> 3;
    const int c0 = ((q0 & 7) ^ (r0 & 7)) << 3;
    const int c1 = ((q1 & 7) ^ (r1 & 7)) << 3;
    const bf16* sA0h0 = A  + (bm + r0)       * (long)lda + c0;
    const bf16* sA1h0 = A  + (bm + r1)       * (long)lda + c1;
    const bf16* sA0h1 = A  + (bm + 128 + r0) * (long)lda + c0;
    const bf16* sA1h1 = A  + (bm + 128 + r1) * (long)lda + c1;
    const bf16* sB0h0 = Bt + (bn + r0)       * (long)ldb + c0;
    const bf16* sB1h0 = Bt + (bn + r1)       * (long)ldb + c1;
    const bf16* sB0h1 = Bt + (bn + 128 + r0) * (long)ldb + c0;
    const bf16* sB1h1 = Bt + (bn + 128 + r1) * (long)ldb + c1;
    const int dst0 = wid * 512;
    const int dst1 = 4096 + wid * 512;

    const int o0   = ((fk ^ (fr & 7)) << 3);
    const int o1   = o0 ^ 32;
    const int rA64 = (wr * 64 + fr) * 64;
    const int rB64 = (wc * 32 + fr) * 64;

    f32x4 acc[8][4] = {};
    s16x8 af[4][2], bf0[2][2], bf1[2][2];
    const int nt = K >> 6;

#define STAGE(ARR, BUF, H, P0, P1) do {                    \
        gload_lds16(P0, &ARR[BUF][(H) * 8192 + dst0]);     \
        gload_lds16(P1, &ARR[BUF][(H) * 8192 + dst1]);     \
        P0 += 64; P1 += 64;                                \
    } while (0)

#define LOADA(MH, CUR) do {                                   \
        const bf16* ab = &As[CUR][rA64 + (MH) * 8192];        \
        _Pragma("unroll") for (int m = 0; m < 4; ++m) {       \
            af[m][0] = *(const s16x8*)&ab[m * 1024 + o0];     \
            af[m][1] = *(const s16x8*)&ab[m * 1024 + o1]; }   \
    } while (0)

#define LOADB(NH, CUR, BF) do {                               \
        const bf16* bb = &Bs[CUR][rB64 + (NH) * 8192];        \
        _Pragma("unroll") for (int n = 0; n < 2; ++n) {       \
            BF[n][0] = *(const s16x8*)&bb[n * 1024 + o0];     \
            BF[n][1] = *(const s16x8*)&bb[n * 1024 + o1]; }   \
    } while (0)

#define MFMAQ(MH, NH, BF) do {                                               \
        __builtin_amdgcn_s_setprio(1);                                       \
        _Pragma("unroll") for (int ks = 0; ks < 2; ++ks)                     \
        _Pragma("unroll") for (int m = 0; m < 4; ++m)                        \
        _Pragma("unroll") for (int n = 0; n < 2; ++n)                        \
            acc[(MH) * 4 + m][(NH) * 2 + n] =                                \
                __builtin_amdgcn_mfma_f32_16x16x32_bf16(                     \
                    af[m][ks], BF[n][ks], acc[(MH) * 4 + m][(NH) * 2 + n],   \
                    0, 0, 0);                                                \
        __builtin_amdgcn_s_setprio(0);                                       \
    } while (0)

#define WB(NV) asm volatile("s_waitcnt vmcnt(" #NV ")\n\ts_barrier" ::: "memory")

    STAGE(As, 0, 0, sA0h0, sA1h0);
    STAGE(Bs, 0, 0, sB0h0, sB1h0);
    STAGE(Bs, 0, 1, sB0h1, sB1h1);
    STAGE(As, 0, 1, sA0h1, sA1h1);
    WB(4);                                   // A-h0, B-h0 of tile 0 ready

    int cur = 0;
    for (int t = 0; t < nt - 1; ++t) {
        STAGE(As, cur ^ 1, 0, sA0h0, sA1h0);
        STAGE(Bs, cur ^ 1, 0, sB0h0, sB1h0);
        STAGE(Bs, cur ^ 1, 1, sB0h1, sB1h1);
        STAGE(As, cur ^ 1, 1, sA0h1, sA1h1);
        LOADA(0, cur); LOADB(0, cur, bf0);
        MFMAQ(0, 0, bf0);  WB(10);           // B-h1 of t ready (issued iter t-1)
        LOADB(1, cur, bf1);
        MFMAQ(0, 1, bf1);  WB(8);            // A-h1 of t ready
        LOADA(1, cur);
        MFMAQ(1, 1, bf1);
        MFMAQ(1, 0, bf0);  WB(4);            // A-h0,B-h0 of t+1 ready
        cur ^= 1;
    }
    LOADA(0, cur); LOADB(0, cur, bf0);
    MFMAQ(0, 0, bf0);  WB(2);
    LOADB(1, cur, bf1);
    MFMAQ(0, 1, bf1);  WB(0);
    LOADA(1, cur);
    MFMAQ(1, 1, bf1);
    MFMAQ(1, 0, bf0);

#undef STAGE
#undef LOADA
#undef LOADB
#undef MFMAQ
#undef WB

    #pragma unroll
    for (int mh = 0; mh < 2; ++mh)
    #pragma unroll
    for (int m = 0; m < 4; ++m)
    #pragma unroll
    for (int nh = 0; nh < 2; ++nh)
    #pragma unroll
    for (int n = 0; n < 2; ++n) {
        f32x4 v = acc[mh * 4 + m][nh * 2 + n];
        long row0 = bm + wr * 64 + mh * 128 + m * 16 + fk * 4;
        long col  = bn + wc * 32 + nh * 128 + n * 16 + fr;
        #pragma unroll
        for (int j = 0; j < 4; ++j)
            C[(row0 + j) * N + col] = __float2bfloat16(v[j]);
    }
}

// ---------------------------------------------------------------------------
// MFMA bf16 GEMM: 128x128 tile, BK=32, COUNTED 2-deep pipeline (no vmcnt(0)
// drain in the main loop). Ledger: prologue stages t0,t1 (8 in flight).
// Iter t: WB vmcnt(4)+bar (releases exactly tile t; t+1 stays in flight) ->
// frag-read/MFMA tile t -> lgkmcnt(0)+bar (all waves consumed buf[cur]) ->
// stage t+2 into buf[cur]. Last iter waits vmcnt(0).
// ---------------------------------------------------------------------------
template<typename OutT, int EPI, bool SPLITK = false>
__global__ __launch_bounds__(256)
void gemm_bt(const bf16* __restrict__ A, const bf16* __restrict__ Bt,
             OutT* __restrict__ C, const float* __restrict__ bias,
             int M, int N, int K, int lda, int ldb)
{
    __shared__ __align__(16) bf16 As[2][128 * 32];
    __shared__ __align__(16) bf16 Bs[2][128 * 32];

    const int tid  = threadIdx.x;
    const int wave = tid >> 6;
    const int lane = tid & 63;
    const int wr = wave >> 1, wc = wave & 1;
    const int fr = lane & 15, fk = lane >> 4;

    const int nbx = gridDim.x;
    const int nwg = nbx * gridDim.y;
    int id  = blockIdx.y * nbx + blockIdx.x;
    if (nwg >= 8) {
        int cpx = nwg >> 3;
        id = (id & 7) * cpx + (id >> 3);
    }
    const int bxi = id % nbx, byi = id / nbx;
    const long bm = (long)byi * 128;
    const long bn = (long)bxi * 128;

    if constexpr (SPLITK) {
        long ko = (long)blockIdx.z * K;
        A  += ko;
        Bt += ko;
        C  += (size_t)blockIdx.z * M * N;
    }

    const int r0 = tid >> 2,         c0 = (tid & 3) << 3;
    const int r1 = (256 + tid) >> 2, c1 = c0;
    const bf16* pA0 = A  + (bm + r0) * (long)lda + c0;
    const bf16* pA1 = A  + (bm + r1) * (long)lda + c1;
    const bf16* pB0 = Bt + (bn + r0) * (long)ldb + c0;
    const bf16* pB1 = Bt + (bn + r1) * (long)ldb + c1;
    const size_t ld0 = (size_t)(wave * 64) * 8;
    const size_t ld1 = (size_t)(256 + wave * 64) * 8;

    f32x4 acc[4][4] = {};
    const int nt = K >> 5;

#define STG(BUF) do {                             \
        gload_lds16(pA0, &As[BUF][ld0]);          \
        gload_lds16(pB0, &Bs[BUF][ld0]);          \
        gload_lds16(pA1, &As[BUF][ld1]);          \
        gload_lds16(pB1, &Bs[BUF][ld1]);          \
        pA0 += 32; pA1 += 32; pB0 += 32; pB1 += 32; \
    } while (0)

    STG(0);                       // tile 0: 4 in flight
    if (nt > 1) STG(1);           // tile 1: 8 in flight

    int cur = 0;
    for (int t = 0; t < nt; ++t) {
        if (t + 1 < nt)
            asm volatile("s_waitcnt vmcnt(4)\n\ts_barrier" ::: "memory");
        else
            asm volatile("s_waitcnt vmcnt(0)\n\ts_barrier" ::: "memory");

        s16x8 afrag[4], bfrag[4];
        #pragma unroll
        for (int m = 0; m < 4; ++m)
            afrag[m] = *(const s16x8*)&As[cur][(wr * 64 + m * 16 + fr) * 32 + fk * 8];
        #pragma unroll
        for (int n = 0; n < 4; ++n)
            bfrag[n] = *(const s16x8*)&Bs[cur][(wc * 64 + n * 16 + fr) * 32 + fk * 8];

        #pragma unroll
        for (int m = 0; m < 4; ++m)
            #pragma unroll
            for (int n = 0; n < 4; ++n)
                acc[m][n] = __builtin_amdgcn_mfma_f32_16x16x32_bf16(
                    afrag[m], bfrag[n], acc[m][n], 0, 0, 0);

        if (t + 2 < nt) {
            // all waves' reads of buf[cur] are consumed (lgkm waits precede
            // the MFMAs); no vmcnt drain here — t+1's loads stay in flight.
            asm volatile("s_waitcnt lgkmcnt(0)\n\ts_barrier" ::: "memory");
            STG(cur);             // stage tile t+2 into the freed buffer
        }
        cur ^= 1;
    }
#undef STG

    #pragma unroll
    for (int m = 0; m < 4; ++m)
        #pragma unroll
        for (int n = 0; n < 4; ++n) {
            f32x4 v = acc[m][n];
            long row0 = bm + wr * 64 + m * 16 + fk * 4;
            long col  = bn + wc * 64 + n * 16 + fr;
            #pragma unroll
            for (int j = 0; j < 4; ++j) {
                float val = v[j];
                if (EPI == 1) {
                    val += bias[col];
                    val = (val > 20.f) ? val : log1pf(__expf(val));
                }
                if constexpr (sizeof(OutT) == 2)
                    C[(row0 + j) * N + col] = __float2bfloat16(val);
                else
                    C[(row0 + j) * N + col] = val;
            }
        }
}

// ---------------------------------------------------------------------------
// Fused preprocessing: 4 weight transposes + convert_x in ONE kernel
// ---------------------------------------------------------------------------
__device__ __forceinline__ void do_transpose(
    const float* __restrict__ in, bf16* __restrict__ out,
    int R, int C, int Cpad, int bx, int by, int tx, int ty)
{
    __shared__ float tile[32][33];
    int cb = bx * 32, rb = by * 32;
    #pragma unroll
    for (int i = 0; i < 4; ++i) {
        int r = rb + ty + i * 8, c = cb + tx;
        tile[ty + i * 8][tx] = (r < R && c < C) ? in[(long)r * C + c] : 0.f;
    }
    __syncthreads();
    #pragma unroll
    for (int i = 0; i < 4; ++i) {
        int oc = cb + ty + i * 8;
        int orow = rb + tx;
        if (oc < Cpad && orow < R)
            out[(long)oc * R + orow] = __float2bfloat16(tile[tx][ty + i * 8]);
    }
}

__global__ __launch_bounds__(256)
void prep_kernel(const float* __restrict__ W_in,  bf16* __restrict__ WinT,
                 const float* __restrict__ W_x,   bf16* __restrict__ WxT,
                 const float* __restrict__ W_dt,  bf16* __restrict__ WdtT,
                 const float* __restrict__ W_out, bf16* __restrict__ WoutT,
                 const float* __restrict__ x,     bf16* __restrict__ Xb)
{
    const int b  = blockIdx.x;
    const int t  = threadIdx.x;
    const int tx = t & 31, ty = t >> 5;

    if (b < 4096) {                       // W_in (1024,4096) -> (4096,1024)
        do_transpose(W_in, WinT, 1024, 4096, 4096, b & 127, b >> 7, tx, ty);
    } else if (b < 4352) {                // W_x (2048,96) -> (128,2048)
        int b2 = b - 4096;
        do_transpose(W_x, WxT, 2048, 96, 128, b2 & 3, b2 >> 2, tx, ty);
    } else if (b < 4480) {                // W_dt (64,2048) -> (2048,64)
        int b3 = b - 4352;
        do_transpose(W_dt, WdtT, 64, 2048, 2048, b3 & 63, b3 >> 6, tx, ty);
    } else if (b < 6528) {                // W_out (2048,1024) -> (1024,2048)
        int b4 = b - 4480;
        do_transpose(W_out, WoutT, 2048, 1024, 1024, b4 & 31, b4 >> 5, tx, ty);
    } else {                              // x (L,B,DM) -> Xb (B*L,DM) bf16
        int idx = (b - 6528) * 256 + t;
        int c   = idx & (DMODEL - 1);
        int row = idx >> 10;
        int l   = row & (L_SEQ - 1);
        int bb  = row >> 11;
        Xb[idx] = __float2bfloat16(x[((l * NBATCH + bb) << 10) | c]);
    }
}

// depthwise causal conv (d_conv=4) + silu, 8 channels per thread (vectorized)
__global__ void conv_silu_kernel(const bf16* __restrict__ xr, const float* __restrict__ Wc,
                                 const float* __restrict__ bc, bf16* __restrict__ u)
{
    int idx = blockIdx.x * 256 + threadIdx.x;   // MROWS*DINNER/8 threads
    int g   = idx & 255;
    int row = idx >> 8;
    int c   = g << 3;
    int l   = row & (L_SEQ - 1);

    float acc[8];
    f32x4 bi0 = *(const f32x4*)(bc + c);
    f32x4 bi1 = *(const f32x4*)(bc + c + 4);
    #pragma unroll
    for (int j = 0; j < 4; ++j) { acc[j] = bi0[j]; acc[4 + j] = bi1[j]; }

    f32x4 w[8];
    #pragma unroll
    for (int j = 0; j < 8; ++j) w[j] = *(const f32x4*)(Wc + (c + j) * 4);

    #pragma unroll
    for (int t = 0; t < 4; ++t) {
        int ll = l - 3 + t;
        if (ll >= 0) {
            s16x8 v = *(const s16x8*)(xr + (long)(row - 3 + t) * 4096 + c);
            #pragma unroll
            for (int j = 0; j < 8; ++j)
                acc[j] += bf2f(v[j]) * w[j][t];
        }
    }
    s16x8 o;
    #pragma unroll
    for (int j = 0; j < 8; ++j) {
        float a = acc[j];
        float s = a / (1.f + __builtin_amdgcn_exp2f(-LOG2E * a));
        bf16 h = __float2bfloat16(s);
        o[j] = *(short*)&h;
    }
    *(s16x8*)(u + (long)row * DINNER + c) = o;
}

__global__ void reduce_xdbl(const float* __restrict__ part, float* __restrict__ xdbl,
                            bf16* __restrict__ drbf)
{
    int idx = blockIdx.x * 256 + threadIdx.x;
    const size_t stride = (size_t)MROWS * 128;
    float v = part[idx] + part[idx + stride] + part[idx + 2 * stride]
            + part[idx + 3 * stride];
    xdbl[idx] = v;
    int col = idx & 127;
    if (col < 64)
        drbf[(idx >> 7) * 64 + col] = __float2bfloat16(v);
}

__global__ void reduce_out(const float* __restrict__ part, float* __restrict__ out)
{
    int i = blockIdx.x * 256 + threadIdx.x;
    f32x4 a = ((const f32x4*)part)[i];
    f32x4 b = ((const f32x4*)(part + (size_t)MROWS * DMODEL))[i];
    ((f32x4*)out)[i] = a + b;
}

// ---------------------------------------------------------------------------
// Chunked parallel selective scan — round-9 form (frozen). delta bf16.
// FAST PATH (runtime-checked): A[d][n] = -(n+1) => powers of exp(-dl).
// ---------------------------------------------------------------------------
__global__ __launch_bounds__(256)
void scan_phase1(const bf16* __restrict__ delta, const bf16* __restrict__ u,
                 const float* __restrict__ xdbl, const float* __restrict__ A_log,
                 float* __restrict__ AS)
{
    const int idx   = blockIdx.x * 256 + threadIdx.x;
    const int half  = idx & 1;
    const int ch    = idx >> 1;
    const int chunk = blockIdx.y;
    const int d     = ch & (DINNER - 1);
    const int b     = ch >> 11;
    const int n0    = half * 8;

    float A2[8], s[8];
    const f32x4* Arow = (const f32x4*)(A_log + d * DSTATE + n0);
    #pragma unroll
    for (int q = 0; q < 2; ++q) {
        f32x4 v = Arow[q];
        #pragma unroll
        for (int j = 0; j < 4; ++j) A2[q * 4 + j] = -__expf(v[j]) * LOG2E;
    }
    #pragma unroll
    for (int n = 0; n < 8; ++n) s[n] = 0.f;
    float sdl = 0.f;

    bool fastA = true;
    #pragma unroll
    for (int j = 0; j < 8; ++j)
        fastA &= fabsf(A2[j] + (float)(n0 + j + 1) * LOG2E)
                 < 0.01f * (float)(n0 + j + 1);

    const long row0 = (long)b * L_SEQ + chunk * LCHUNK;
    const bf16*  pD = delta + row0 * DINNER + d;
    const bf16*  pU = u     + row0 * DINNER + d;
    const f32x4* pB = (const f32x4*)(xdbl + row0 * 128 + 64 + n0);

    if (fastA) {
        #pragma unroll 4
        for (int l = 0; l < LCHUNK; ++l) {
            float dl = __bfloat162float(*pD);
            float uv = __bfloat162float(*pU);
            f32x4 B0 = pB[0], B1 = pB[1];
            pD += DINNER; pU += DINNER; pB += 32;
            float dbu = dl * uv;
            sdl += dl;
            float b1 = __builtin_amdgcn_exp2f(-LOG2E * dl);   // exp(-dl)
            float b2 = b1 * b1, b3 = b2 * b1, b4 = b2 * b2;
            float b5 = b4 * b1, b6 = b4 * b2, b7 = b4 * b3, b8 = b4 * b4;
            float pre = half ? b8 : 1.f;
            s[0] = pre * b1 * s[0] + dbu * B0[0];
            s[1] = pre * b2 * s[1] + dbu * B0[1];
            s[2] = pre * b3 * s[2] + dbu * B0[2];
            s[3] = pre * b4 * s[3] + dbu * B0[3];
            s[4] = pre * b5 * s[4] + dbu * B1[0];
            s[5] = pre * b6 * s[5] + dbu * B1[1];
            s[6] = pre * b7 * s[6] + dbu * B1[2];
            s[7] = pre * b8 * s[7] + dbu * B1[3];
        }
    } else {
        #pragma unroll 4
        for (int l = 0; l < LCHUNK; ++l) {
            float dl = __bfloat162float(*pD);
            float uv = __bfloat162float(*pU);
            f32x4 B0 = pB[0], B1 = pB[1];
            pD += DINNER; pU += DINNER; pB += 32;
            float dbu = dl * uv;
            sdl += dl;
            #pragma unroll
            for (int j = 0; j < 4; ++j) {
                float e = __builtin_amdgcn_exp2f(dl * A2[j]);
                s[j] = e * s[j] + dbu * B0[j];
            }
            #pragma unroll
            for (int j = 0; j < 4; ++j) {
                float e = __builtin_amdgcn_exp2f(dl * A2[4 + j]);
                s[4 + j] = e * s[4 + j] + dbu * B1[j];
            }
        }
    }
    float ap[8];
    #pragma unroll
    for (int n = 0; n < 8; ++n) ap[n] = __builtin_amdgcn_exp2f(sdl * A2[n]);

    float* o = AS + ((size_t)chunk * 4096 + ch) * 32 + n0;
    *(f32x4*)(o)      = *(f32x4*)&ap[0];
    *(f32x4*)(o + 4)  = *(f32x4*)&ap[4];
    *(f32x4*)(o + 16) = *(f32x4*)&s[0];
    *(f32x4*)(o + 20) = *(f32x4*)&s[4];
}

__global__ __launch_bounds__(256)
void scan_phase2(float* __restrict__ AS)
{
    const int idx = blockIdx.x * 256 + threadIdx.x;
    const int n   = idx & 15;
    const int ch  = idx >> 4;

    float s = 0.f;
    for (int cb = 0; cb < NCHUNK; cb += 16) {
        float av[16], sv[16];
        #pragma unroll
        for (int j = 0; j < 16; ++j) {
            size_t r = ((size_t)(cb + j) * 4096 + ch) * 32 + n;
            av[j] = AS[r];
            sv[j] = AS[r + 16];
        }
        #pragma unroll
        for (int j = 0; j < 16; ++j) {
            AS[((size_t)(cb + j) * 4096 + ch) * 32 + 16 + n] = s;
            s = av[j] * s + sv[j];
        }
    }
}

__global__ __launch_bounds__(256)
void scan_phase3(const bf16* __restrict__ delta, const bf16* __restrict__ u,
                 const float* __restrict__ xdbl, const bf16* __restrict__ xr,
                 const float* __restrict__ AS, const float* __restrict__ A_log,
                 const float* __restrict__ Dp, bf16* __restrict__ ybf)
{
    const int idx   = blockIdx.x * 256 + threadIdx.x;
    const int half  = idx & 1;
    const int ch    = idx >> 1;
    const int chunk = blockIdx.y;
    const int d     = ch & (DINNER - 1);
    const int b     = ch >> 11;
    const int n0    = half * 8;

    float A2[8], s[8];
    const f32x4* Arow = (const f32x4*)(A_log + d * DSTATE + n0);
    #pragma unroll
    for (int q = 0; q < 2; ++q) {
        f32x4 v = Arow[q];
        #pragma unroll
        for (int j = 0; j < 4; ++j) A2[q * 4 + j] = -__expf(v[j]) * LOG2E;
    }
    const float* ip = AS + ((size_t)chunk * 4096 + ch) * 32 + 16 + n0;
    *(f32x4*)&s[0] = *(const f32x4*)(ip);
    *(f32x4*)&s[4] = *(const f32x4*)(ip + 4);

    bool fastA = true;
    #pragma unroll
    for (int j = 0; j < 8; ++j)
        fastA &= fabsf(A2[j] + (float)(n0 + j + 1) * LOG2E)
                 < 0.01f * (float)(n0 + j + 1);

    const float Dd  = Dp[d];
    const long row0 = (long)b * L_SEQ + chunk * LCHUNK;

    const bf16*  pD = delta + row0 * DINNER + d;
    const bf16*  pU = u     + row0 * DINNER + d;
    const bf16*  pR = xr    + row0 * 4096 + 2048 + d;
    const f32x4* pB = (const f32x4*)(xdbl + row0 * 128 + 64 + n0);
    bf16*        pY = ybf   + row0 * DINNER + d;

    if (fastA) {
        #pragma unroll 4
        for (int l = 0; l < LCHUNK; ++l) {
            float dl = __bfloat162float(*pD);
            float uv = __bfloat162float(*pU);
            float rs = __bfloat162float(*pR);
            f32x4 B0 = pB[0], B1 = pB[1];
            f32x4 C0 = pB[4], C1 = pB[5];
            pD += DINNER; pU += DINNER; pR += 4096; pB += 32;
            float dbu = dl * uv;
            float b1 = __builtin_amdgcn_exp2f(-LOG2E * dl);   // exp(-dl)
            float b2 = b1 * b1, b3 = b2 * b1, b4 = b2 * b2;
            float b5 = b4 * b1, b6 = b4 * b2, b7 = b4 * b3, b8 = b4 * b4;
            float pre = half ? b8 : 1.f;
            float y0 = 0.f, y1 = 0.f;
            s[0] = pre * b1 * s[0] + dbu * B0[0];  y0 += s[0] * C0[0];
            s[1] = pre * b2 * s[1] + dbu * B0[1];  y0 += s[1] * C0[1];
            s[2] = pre * b3 * s[2] + dbu * B0[2];  y0 += s[2] * C0[2];
            s[3] = pre * b4 * s[3] + dbu * B0[3];  y0 += s[3] * C0[3];
            s[4] = pre * b5 * s[4] + dbu * B1[0];  y1 += s[4] * C1[0];
            s[5] = pre * b6 * s[5] + dbu * B1[1];  y1 += s[5] * C1[1];
            s[6] = pre * b7 * s[6] + dbu * B1[2];  y1 += s[6] * C1[2];
            s[7] = pre * b8 * s[7] + dbu * B1[3];  y1 += s[7] * C1[3];
            float yh = y0 + y1;
            float yt = yh + __shfl_xor(yh, 1);
            if (half == 0) {
                float yf = yt + uv * Dd;
                yf *= rs / (1.f + __builtin_amdgcn_exp2f(-LOG2E * rs));
                *pY = __float2bfloat16(yf);
            }
            pY += DINNER;
        }
    } else {
        #pragma unroll 4
        for (int l = 0; l < LCHUNK; ++l) {
            float dl = __bfloat162float(*pD);
            float uv = __bfloat162float(*pU);
            float rs = __bfloat162float(*pR);
            f32x4 B0 = pB[0], B1 = pB[1];
            f32x4 C0 = pB[4], C1 = pB[5];
            pD += DINNER; pU += DINNER; pR += 4096; pB += 32;
            float dbu = dl * uv;
            float y0 = 0.f, y1 = 0.f;
            #pragma unroll
            for (int j = 0; j < 4; ++j) {
                float e = __builtin_amdgcn_exp2f(dl * A2[j]);
                s[j] = e * s[j] + dbu * B0[j];
                y0 += s[j] * C0[j];
            }
            #pragma unroll
            for (int j = 0; j < 4; ++j) {
                float e = __builtin_amdgcn_exp2f(dl * A2[4 + j]);
                s[4 + j] = e * s[4 + j] + dbu * B1[j];
                y1 += s[4 + j] * C1[j];
            }
            float yh = y0 + y1;
            float yt = yh + __shfl_xor(yh, 1);
            if (half == 0) {
                float yf = yt + uv * Dd;
                yf *= rs / (1.f + __builtin_amdgcn_exp2f(-LOG2E * rs));
                *pY = __float2bfloat16(yf);
            }
            pY += DINNER;
        }
    }
}

// ---------------------------------------------------------------------------
extern "C" void kernel_launch(void* const* d_in, const int* in_sizes, int n_in,
                              void* d_out, int out_size, void* d_ws, size_t ws_size,
                              hipStream_t stream)
{
    const float* x      = (const float*)d_in[0];
    const float* W_in   = (const float*)d_in[1];
    const float* W_conv = (const float*)d_in[2];
    const float* b_conv = (const float*)d_in[3];
    const float* W_x    = (const float*)d_in[4];
    const float* W_dt   = (const float*)d_in[5];
    const float* b_dt   = (const float*)d_in[6];
    const float* A_log  = (const float*)d_in[7];
    const float* Dp     = (const float*)d_in[8];
    const float* W_out  = (const float*)d_in[9];
    float* out = (float*)d_out;

    char* ws = (char*)d_ws;
    size_t off = 0;
    auto alloc = [&](size_t bytes) {
        void* p = ws + off;
        off = (off + bytes + 255) & ~(size_t)255;
        return p;
    };
    bf16*  Xb    = (bf16*) alloc((size_t)MROWS * DMODEL * 2);
    bf16*  WinT  = (bf16*) alloc((size_t)4096  * DMODEL * 2);
    bf16*  xr    = (bf16*) alloc((size_t)MROWS * 4096  * 2);
    bf16*  ubf   = (bf16*) alloc((size_t)MROWS * DINNER * 2);
    bf16*  WxT   = (bf16*) alloc((size_t)128   * DINNER * 2);
    float* xdbl  = (float*)alloc((size_t)MROWS * 128 * 4);
    float* xdblp = (float*)alloc((size_t)4 * MROWS * 128 * 4);
    bf16*  drbf  = (bf16*) alloc((size_t)MROWS * 64 * 2);
    bf16*  WdtT  = (bf16*) alloc((size_t)DINNER * 64 * 2);
    bf16*  delta = (bf16*) alloc((size_t)MROWS * DINNER * 2);   // bf16
    bf16*  ybf   = (bf16*) alloc((size_t)MROWS * DINNER * 2);
    bf16*  WoutT = (bf16*) alloc((size_t)DMODEL * DINNER * 2);
    float* AS    = (float*)alloc((size_t)NCHUNK * 4096 * 32 * 4); // 32MB; reused
                                                                  // as GEMM4 partials

    // fused prep: 4 transposes + convert_x
    prep_kernel<<<6528 + (MROWS * DMODEL) / 256, 256, 0, stream>>>(
        W_in, WinT, W_x, WxT, W_dt, WdtT, W_out, WoutT, x, Xb);

    // GEMM1: x_and_res = Xb @ W_in -> xr bf16 (4096,4096) — 256² deep-prefetch
    gemm256<<<dim3(4096 / 256, MROWS / 256), 512, 0, stream>>>(
        Xb, WinT, xr, 4096, 1024, 1024, 1024);
    // conv + silu -> u bf16 (vectorized, 8 ch/thread)
    conv_silu_kernel<<<(MROWS * DINNER / 8) / 256, 256, 0, stream>>>(
        xr, W_conv, b_conv, ubf);
    // GEMM2: x_dbl = u @ W_x, split-K x4 -> partials
    gemm_bt<float, 0, true><<<dim3(1, MROWS / 128, 4), 256, 0, stream>>>(
        ubf, WxT, xdblp, nullptr, MROWS, 128, 512, 2048, 2048);
    reduce_xdbl<<<(MROWS * 128) / 256, 256, 0, stream>>>(xdblp, xdbl, drbf);
    // GEMM3: delta = softplus(delta_r @ W_dt + b_dt) -> bf16
    gemm_bt<bf16, 1><<<dim3(DINNER / 128, MROWS / 128), 256, 0, stream>>>(
        drbf, WdtT, delta, b_dt, MROWS, DINNER, 64, 64, 64);
    // chunked parallel selective scan -> ybf bf16
    scan_phase1<<<dim3(32, NCHUNK), 256, 0, stream>>>(delta, ubf, xdbl, A_log, AS);
    scan_phase2<<<256, 256, 0, stream>>>(AS);
    scan_phase3<<<dim3(32, NCHUNK), 256, 0, stream>>>(delta, ubf, xdbl, xr, AS,
                                                      A_log, Dp, ybf);
    // GEMM4: out = y @ W_out, split-K x2 into AS (free after scan), then reduce
    gemm_bt<float, 0, true><<<dim3(DMODEL / 128, MROWS / 128, 2), 256, 0, stream>>>(
        ybf, WoutT, (float*)AS, nullptr, MROWS, DMODEL, 1024, 2048, 2048);
    reduce_out<<<(MROWS * DMODEL) / 1024, 256, 0, stream>>>((float*)AS, out);
}

// Round 15
// 253.161 us; speedup vs baseline: 1.2037x; 1.0300x over previous
//
#include <hip/hip_runtime.h>
#include <hip/hip_bf16.h>

#define L_SEQ  2048
#define NBATCH 2
#define DMODEL 1024
#define DINNER 2048
#define DSTATE 16
#define DTRANK 64
#define MROWS  (L_SEQ * NBATCH)   // 4096
#define NCHUNK 64
#define LCHUNK 32                 // L_SEQ / NCHUNK
#define LOG2E  1.44269504f

using bf16 = __hip_bfloat16;
typedef short s16x8 __attribute__((ext_vector_type(8)));   // 8 bf16 = 16B
typedef float f32x4 __attribute__((ext_vector_type(4)));

__device__ __forceinline__ void gload_lds16(const bf16* g, bf16* l) {
    __builtin_amdgcn_global_load_lds(
        (const __attribute__((address_space(1))) void*)g,
        (__attribute__((address_space(3))) void*)l, 16, 0, 0);
}

__device__ __forceinline__ float bf2f(short v) {
    return __uint_as_float(((unsigned)(unsigned short)v) << 16);
}

// ---------------------------------------------------------------------------
// 256x256 MFMA GEMM, 2-barrier deep pipeline. Ledger (load-pair units, 2
// loads/pair; WB counts single loads):
//   prologue: stage t0 {A0,B0,B1,A1} -> 8 outstanding.
//   iter t: WB(2)+bar  (retires A0,B0,B1 of t; A1 stays in flight)
//           ds-read af0,bf0,bf1 (16 reads) | stage all 4 halves of t+1 (+8)
//           MFMAQ(0,0); MFMAQ(0,1)      (32 MFMA; ds latency hidden)
//           WB(8)+bar  (retires A1 of t — staged a full iter earlier)
//           ds-read af1; MFMAQ(1,1); MFMAQ(1,0)
//   next iter's WB(2) retires A0',B0',B1' (staged 2-3 phases earlier).
// LDS safety: a wave passes the top barrier only after its prev-tile MFMAs
// (register deps force lgkm completion of prev ds-reads), so staging into
// the other buffer after that barrier cannot race any wave's reads.
// XCD RECT swizzle: each XCD gets a 4x8 sub-rect of the 16x16 grid.
// C(M,N) = A(M,K) @ Bt(N,K)^T, bf16 in/out, fp32 acc.
// ---------------------------------------------------------------------------
__global__ __launch_bounds__(512, 2)
void gemm256(const bf16* __restrict__ A, const bf16* __restrict__ Bt,
             bf16* __restrict__ C, int N, int K, int lda, int ldb)
{
    __shared__ __align__(16) bf16 As[2][256 * 64];
    __shared__ __align__(16) bf16 Bs[2][256 * 64];

    const int tid  = threadIdx.x;
    const int wid  = tid >> 6;
    const int lane = tid & 63;
    const int wr = wid >> 2, wc = wid & 3;       // 2x4 wave grid
    const int fr = lane & 15, fk = lane >> 4;

    // rect swizzle (grid is always 16x16 for GEMM1)
    const int orig = blockIdx.y * gridDim.x + blockIdx.x;
    const int xcd  = orig & 7, k = orig >> 3;    // k in [0,32)
    const int byi  = (xcd >> 1) * 4 + (k >> 3);  // 4-row band
    const int bxi  = (xcd & 1) * 8 + (k & 7);    // 8-col band
    const long bm = (long)byi * 256;
    const long bn = (long)bxi * 256;

    const int q0 = tid, q1 = tid + 512;
    const int r0 = q0 >> 3, r1 = q1 >> 3;
    const int c0 = ((q0 & 7) ^ (r0 & 7)) << 3;
    const int c1 = ((q1 & 7) ^ (r1 & 7)) << 3;
    const bf16* sA0h0 = A  + (bm + r0)       * (long)lda + c0;
    const bf16* sA1h0 = A  + (bm + r1)       * (long)lda + c1;
    const bf16* sA0h1 = A  + (bm + 128 + r0) * (long)lda + c0;
    const bf16* sA1h1 = A  + (bm + 128 + r1) * (long)lda + c1;
    const bf16* sB0h0 = Bt + (bn + r0)       * (long)ldb + c0;
    const bf16* sB1h0 = Bt + (bn + r1)       * (long)ldb + c1;
    const bf16* sB0h1 = Bt + (bn + 128 + r0) * (long)ldb + c0;
    const bf16* sB1h1 = Bt + (bn + 128 + r1) * (long)ldb + c1;
    const int dst0 = wid * 512;
    const int dst1 = 4096 + wid * 512;

    const int o0   = ((fk ^ (fr & 7)) << 3);
    const int o1   = o0 ^ 32;
    const int rA64 = (wr * 64 + fr) * 64;
    const int rB64 = (wc * 32 + fr) * 64;

    f32x4 acc[8][4] = {};
    s16x8 af[4][2], bf0[2][2], bf1[2][2];
    const int nt = K >> 6;

#define STAGE(ARR, BUF, H, P0, P1) do {                    \
        gload_lds16(P0, &ARR[BUF][(H) * 8192 + dst0]);     \
        gload_lds16(P1, &ARR[BUF][(H) * 8192 + dst1]);     \
        P0 += 64; P1 += 64;                                \
    } while (0)

#define LOADA(MH, CUR) do {                                   \
        const bf16* ab = &As[CUR][rA64 + (MH) * 8192];        \
        _Pragma("unroll") for (int m = 0; m < 4; ++m) {       \
            af[m][0] = *(const s16x8*)&ab[m * 1024 + o0];     \
            af[m][1] = *(const s16x8*)&ab[m * 1024 + o1]; }   \
    } while (0)

#define LOADB(NH, CUR, BF) do {                               \
        const bf16* bb = &Bs[CUR][rB64 + (NH) * 8192];        \
        _Pragma("unroll") for (int n = 0; n < 2; ++n) {       \
            BF[n][0] = *(const s16x8*)&bb[n * 1024 + o0];     \
            BF[n][1] = *(const s16x8*)&bb[n * 1024 + o1]; }   \
    } while (0)

#define MFMAQ(MH, NH, BF) do {                                               \
        __builtin_amdgcn_s_setprio(1);                                       \
        _Pragma("unroll") for (int ks = 0; ks < 2; ++ks)                     \
        _Pragma("unroll") for (int m = 0; m < 4; ++m)                        \
        _Pragma("unroll") for (int n = 0; n < 2; ++n)                        \
            acc[(MH) * 4 + m][(NH) * 2 + n] =                                \
                __builtin_amdgcn_mfma_f32_16x16x32_bf16(                     \
                    af[m][ks], BF[n][ks], acc[(MH) * 4 + m][(NH) * 2 + n],   \
                    0, 0, 0);                                                \
        __builtin_amdgcn_s_setprio(0);                                       \
    } while (0)

#define WB(NV) asm volatile("s_waitcnt vmcnt(" #NV ")\n\ts_barrier" ::: "memory")

    // prologue: stage tile 0 (order A0,B0,B1,A1) -> buf 0; 8 in flight
    STAGE(As, 0, 0, sA0h0, sA1h0);
    STAGE(Bs, 0, 0, sB0h0, sB1h0);
    STAGE(Bs, 0, 1, sB0h1, sB1h1);
    STAGE(As, 0, 1, sA0h1, sA1h1);

    int cur = 0;
    for (int t = 0; t < nt; ++t) {
        WB(2);                               // A0,B0,B1 of t ready; A1 in flight
        LOADA(0, cur);
        LOADB(0, cur, bf0);
        LOADB(1, cur, bf1);
        if (t + 1 < nt) {                    // stage all of t+1 (+8 in flight)
            STAGE(As, cur ^ 1, 0, sA0h0, sA1h0);
            STAGE(Bs, cur ^ 1, 0, sB0h0, sB1h0);
            STAGE(Bs, cur ^ 1, 1, sB0h1, sB1h1);
            STAGE(As, cur ^ 1, 1, sA0h1, sA1h1);
        }
        MFMAQ(0, 0, bf0);
        MFMAQ(0, 1, bf1);
        if (t + 1 < nt) WB(8); else WB(0);   // A1 of t ready
        LOADA(1, cur);
        MFMAQ(1, 1, bf1);
        MFMAQ(1, 0, bf0);
        cur ^= 1;
    }

#undef STAGE
#undef LOADA
#undef LOADB
#undef MFMAQ
#undef WB

    #pragma unroll
    for (int mh = 0; mh < 2; ++mh)
    #pragma unroll
    for (int m = 0; m < 4; ++m)
    #pragma unroll
    for (int nh = 0; nh < 2; ++nh)
    #pragma unroll
    for (int n = 0; n < 2; ++n) {
        f32x4 v = acc[mh * 4 + m][nh * 2 + n];
        long row0 = bm + wr * 64 + mh * 128 + m * 16 + fk * 4;
        long col  = bn + wc * 32 + nh * 128 + n * 16 + fr;
        #pragma unroll
        for (int j = 0; j < 4; ++j)
            C[(row0 + j) * N + col] = __float2bfloat16(v[j]);
    }
}

// ---------------------------------------------------------------------------
// MFMA bf16 GEMM: 128x128 tile, BK=32, COUNTED 2-deep pipeline (no vmcnt(0)
// drain in the main loop).
// ---------------------------------------------------------------------------
template<typename OutT, int EPI, bool SPLITK = false>
__global__ __launch_bounds__(256)
void gemm_bt(const bf16* __restrict__ A, const bf16* __restrict__ Bt,
             OutT* __restrict__ C, const float* __restrict__ bias,
             int M, int N, int K, int lda, int ldb)
{
    __shared__ __align__(16) bf16 As[2][128 * 32];
    __shared__ __align__(16) bf16 Bs[2][128 * 32];

    const int tid  = threadIdx.x;
    const int wave = tid >> 6;
    const int lane = tid & 63;
    const int wr = wave >> 1, wc = wave & 1;
    const int fr = lane & 15, fk = lane >> 4;

    const int nbx = gridDim.x;
    const int nwg = nbx * gridDim.y;
    int id  = blockIdx.y * nbx + blockIdx.x;
    if (nwg >= 8) {
        int cpx = nwg >> 3;
        id = (id & 7) * cpx + (id >> 3);
    }
    const int bxi = id % nbx, byi = id / nbx;
    const long bm = (long)byi * 128;
    const long bn = (long)bxi * 128;

    if constexpr (SPLITK) {
        long ko = (long)blockIdx.z * K;
        A  += ko;
        Bt += ko;
        C  += (size_t)blockIdx.z * M * N;
    }

    const int r0 = tid >> 2,         c0 = (tid & 3) << 3;
    const int r1 = (256 + tid) >> 2, c1 = c0;
    const bf16* pA0 = A  + (bm + r0) * (long)lda + c0;
    const bf16* pA1 = A  + (bm + r1) * (long)lda + c1;
    const bf16* pB0 = Bt + (bn + r0) * (long)ldb + c0;
    const bf16* pB1 = Bt + (bn + r1) * (long)ldb + c1;
    const size_t ld0 = (size_t)(wave * 64) * 8;
    const size_t ld1 = (size_t)(256 + wave * 64) * 8;

    f32x4 acc[4][4] = {};
    const int nt = K >> 5;

#define STG(BUF) do {                             \
        gload_lds16(pA0, &As[BUF][ld0]);          \
        gload_lds16(pB0, &Bs[BUF][ld0]);          \
        gload_lds16(pA1, &As[BUF][ld1]);          \
        gload_lds16(pB1, &Bs[BUF][ld1]);          \
        pA0 += 32; pA1 += 32; pB0 += 32; pB1 += 32; \
    } while (0)

    STG(0);                       // tile 0: 4 in flight
    if (nt > 1) STG(1);           // tile 1: 8 in flight

    int cur = 0;
    for (int t = 0; t < nt; ++t) {
        if (t + 1 < nt)
            asm volatile("s_waitcnt vmcnt(4)\n\ts_barrier" ::: "memory");
        else
            asm volatile("s_waitcnt vmcnt(0)\n\ts_barrier" ::: "memory");

        s16x8 afrag[4], bfrag[4];
        #pragma unroll
        for (int m = 0; m < 4; ++m)
            afrag[m] = *(const s16x8*)&As[cur][(wr * 64 + m * 16 + fr) * 32 + fk * 8];
        #pragma unroll
        for (int n = 0; n < 4; ++n)
            bfrag[n] = *(const s16x8*)&Bs[cur][(wc * 64 + n * 16 + fr) * 32 + fk * 8];

        #pragma unroll
        for (int m = 0; m < 4; ++m)
            #pragma unroll
            for (int n = 0; n < 4; ++n)
                acc[m][n] = __builtin_amdgcn_mfma_f32_16x16x32_bf16(
                    afrag[m], bfrag[n], acc[m][n], 0, 0, 0);

        if (t + 2 < nt) {
            asm volatile("s_waitcnt lgkmcnt(0)\n\ts_barrier" ::: "memory");
            STG(cur);             // stage tile t+2 into the freed buffer
        }
        cur ^= 1;
    }
#undef STG

    #pragma unroll
    for (int m = 0; m < 4; ++m)
        #pragma unroll
        for (int n = 0; n < 4; ++n) {
            f32x4 v = acc[m][n];
            long row0 = bm + wr * 64 + m * 16 + fk * 4;
            long col  = bn + wc * 64 + n * 16 + fr;
            #pragma unroll
            for (int j = 0; j < 4; ++j) {
                float val = v[j];
                if (EPI == 1) {
                    val += bias[col];
                    val = (val > 20.f) ? val : log1pf(__expf(val));
                }
                if constexpr (sizeof(OutT) == 2)
                    C[(row0 + j) * N + col] = __float2bfloat16(val);
                else
                    C[(row0 + j) * N + col] = val;
            }
        }
}

// ---------------------------------------------------------------------------
// Fused preprocessing: 4 weight transposes + convert_x in ONE kernel
// ---------------------------------------------------------------------------
__device__ __forceinline__ void do_transpose(
    const float* __restrict__ in, bf16* __restrict__ out,
    int R, int C, int Cpad, int bx, int by, int tx, int ty)
{
    __shared__ float tile[32][33];
    int cb = bx * 32, rb = by * 32;
    #pragma unroll
    for (int i = 0; i < 4; ++i) {
        int r = rb + ty + i * 8, c = cb + tx;
        tile[ty + i * 8][tx] = (r < R && c < C) ? in[(long)r * C + c] : 0.f;
    }
    __syncthreads();
    #pragma unroll
    for (int i = 0; i < 4; ++i) {
        int oc = cb + ty + i * 8;
        int orow = rb + tx;
        if (oc < Cpad && orow < R)
            out[(long)oc * R + orow] = __float2bfloat16(tile[tx][ty + i * 8]);
    }
}

__global__ __launch_bounds__(256)
void prep_kernel(const float* __restrict__ W_in,  bf16* __restrict__ WinT,
                 const float* __restrict__ W_x,   bf16* __restrict__ WxT,
                 const float* __restrict__ W_dt,  bf16* __restrict__ WdtT,
                 const float* __restrict__ W_out, bf16* __restrict__ WoutT,
                 const float* __restrict__ x,     bf16* __restrict__ Xb)
{
    const int b  = blockIdx.x;
    const int t  = threadIdx.x;
    const int tx = t & 31, ty = t >> 5;

    if (b < 4096) {                       // W_in (1024,4096) -> (4096,1024)
        do_transpose(W_in, WinT, 1024, 4096, 4096, b & 127, b >> 7, tx, ty);
    } else if (b < 4352) {                // W_x (2048,96) -> (128,2048)
        int b2 = b - 4096;
        do_transpose(W_x, WxT, 2048, 96, 128, b2 & 3, b2 >> 2, tx, ty);
    } else if (b < 4480) {                // W_dt (64,2048) -> (2048,64)
        int b3 = b - 4352;
        do_transpose(W_dt, WdtT, 64, 2048, 2048, b3 & 63, b3 >> 6, tx, ty);
    } else if (b < 6528) {                // W_out (2048,1024) -> (1024,2048)
        int b4 = b - 4480;
        do_transpose(W_out, WoutT, 2048, 1024, 1024, b4 & 31, b4 >> 5, tx, ty);
    } else {                              // x (L,B,DM) -> Xb (B*L,DM) bf16
        int idx = (b - 6528) * 256 + t;
        int c   = idx & (DMODEL - 1);
        int row = idx >> 10;
        int l   = row & (L_SEQ - 1);
        int bb  = row >> 11;
        Xb[idx] = __float2bfloat16(x[((l * NBATCH + bb) << 10) | c]);
    }
}

// depthwise causal conv (d_conv=4) + silu, 8 channels per thread (vectorized)
__global__ void conv_silu_kernel(const bf16* __restrict__ xr, const float* __restrict__ Wc,
                                 const float* __restrict__ bc, bf16* __restrict__ u)
{
    int idx = blockIdx.x * 256 + threadIdx.x;   // MROWS*DINNER/8 threads
    int g   = idx & 255;
    int row = idx >> 8;
    int c   = g << 3;
    int l   = row & (L_SEQ - 1);

    float acc[8];
    f32x4 bi0 = *(const f32x4*)(bc + c);
    f32x4 bi1 = *(const f32x4*)(bc + c + 4);
    #pragma unroll
    for (int j = 0; j < 4; ++j) { acc[j] = bi0[j]; acc[4 + j] = bi1[j]; }

    f32x4 w[8];
    #pragma unroll
    for (int j = 0; j < 8; ++j) w[j] = *(const f32x4*)(Wc + (c + j) * 4);

    #pragma unroll
    for (int t = 0; t < 4; ++t) {
        int ll = l - 3 + t;
        if (ll >= 0) {
            s16x8 v = *(const s16x8*)(xr + (long)(row - 3 + t) * 4096 + c);
            #pragma unroll
            for (int j = 0; j < 8; ++j)
                acc[j] += bf2f(v[j]) * w[j][t];
        }
    }
    s16x8 o;
    #pragma unroll
    for (int j = 0; j < 8; ++j) {
        float a = acc[j];
        float s = a / (1.f + __builtin_amdgcn_exp2f(-LOG2E * a));
        bf16 h = __float2bfloat16(s);
        o[j] = *(short*)&h;
    }
    *(s16x8*)(u + (long)row * DINNER + c) = o;
}

__global__ void reduce_xdbl(const float* __restrict__ part, float* __restrict__ xdbl,
                            bf16* __restrict__ drbf)
{
    int idx = blockIdx.x * 256 + threadIdx.x;
    const size_t stride = (size_t)MROWS * 128;
    float v = part[idx] + part[idx + stride] + part[idx + 2 * stride]
            + part[idx + 3 * stride];
    xdbl[idx] = v;
    int col = idx & 127;
    if (col < 64)
        drbf[(idx >> 7) * 64 + col] = __float2bfloat16(v);
}

__global__ void reduce_out(const float* __restrict__ part, float* __restrict__ out)
{
    int i = blockIdx.x * 256 + threadIdx.x;
    f32x4 a = ((const f32x4*)part)[i];
    f32x4 b = ((const f32x4*)(part + (size_t)MROWS * DMODEL))[i];
    ((f32x4*)out)[i] = a + b;
}

// ---------------------------------------------------------------------------
// Chunked parallel selective scan — round-9 form (frozen). delta bf16.
// FAST PATH (runtime-checked): A[d][n] = -(n+1) => powers of exp(-dl).
// ---------------------------------------------------------------------------
__global__ __launch_bounds__(256)
void scan_phase1(const bf16* __restrict__ delta, const bf16* __restrict__ u,
                 const float* __restrict__ xdbl, const float* __restrict__ A_log,
                 float* __restrict__ AS)
{
    const int idx   = blockIdx.x * 256 + threadIdx.x;
    const int half  = idx & 1;
    const int ch    = idx >> 1;
    const int chunk = blockIdx.y;
    const int d     = ch & (DINNER - 1);
    const int b     = ch >> 11;
    const int n0    = half * 8;

    float A2[8], s[8];
    const f32x4* Arow = (const f32x4*)(A_log + d * DSTATE + n0);
    #pragma unroll
    for (int q = 0; q < 2; ++q) {
        f32x4 v = Arow[q];
        #pragma unroll
        for (int j = 0; j < 4; ++j) A2[q * 4 + j] = -__expf(v[j]) * LOG2E;
    }
    #pragma unroll
    for (int n = 0; n < 8; ++n) s[n] = 0.f;
    float sdl = 0.f;

    bool fastA = true;
    #pragma unroll
    for (int j = 0; j < 8; ++j)
        fastA &= fabsf(A2[j] + (float)(n0 + j + 1) * LOG2E)
                 < 0.01f * (float)(n0 + j + 1);

    const long row0 = (long)b * L_SEQ + chunk * LCHUNK;
    const bf16*  pD = delta + row0 * DINNER + d;
    const bf16*  pU = u     + row0 * DINNER + d;
    const f32x4* pB = (const f32x4*)(xdbl + row0 * 128 + 64 + n0);

    if (fastA) {
        #pragma unroll 4
        for (int l = 0; l < LCHUNK; ++l) {
            float dl = __bfloat162float(*pD);
            float uv = __bfloat162float(*pU);
            f32x4 B0 = pB[0], B1 = pB[1];
            pD += DINNER; pU += DINNER; pB += 32;
            float dbu = dl * uv;
            sdl += dl;
            float b1 = __builtin_amdgcn_exp2f(-LOG2E * dl);   // exp(-dl)
            float b2 = b1 * b1, b3 = b2 * b1, b4 = b2 * b2;
            float b5 = b4 * b1, b6 = b4 * b2, b7 = b4 * b3, b8 = b4 * b4;
            float pre = half ? b8 : 1.f;
            s[0] = pre * b1 * s[0] + dbu * B0[0];
            s[1] = pre * b2 * s[1] + dbu * B0[1];
            s[2] = pre * b3 * s[2] + dbu * B0[2];
            s[3] = pre * b4 * s[3] + dbu * B0[3];
            s[4] = pre * b5 * s[4] + dbu * B1[0];
            s[5] = pre * b6 * s[5] + dbu * B1[1];
            s[6] = pre * b7 * s[6] + dbu * B1[2];
            s[7] = pre * b8 * s[7] + dbu * B1[3];
        }
    } else {
        #pragma unroll 4
        for (int l = 0; l < LCHUNK; ++l) {
            float dl = __bfloat162float(*pD);
            float uv = __bfloat162float(*pU);
            f32x4 B0 = pB[0], B1 = pB[1];
            pD += DINNER; pU += DINNER; pB += 32;
            float dbu = dl * uv;
            sdl += dl;
            #pragma unroll
            for (int j = 0; j < 4; ++j) {
                float e = __builtin_amdgcn_exp2f(dl * A2[j]);
                s[j] = e * s[j] + dbu * B0[j];
            }
            #pragma unroll
            for (int j = 0; j < 4; ++j) {
                float e = __builtin_amdgcn_exp2f(dl * A2[4 + j]);
                s[4 + j] = e * s[4 + j] + dbu * B1[j];
            }
        }
    }
    float ap[8];
    #pragma unroll
    for (int n = 0; n < 8; ++n) ap[n] = __builtin_amdgcn_exp2f(sdl * A2[n]);

    float* o = AS + ((size_t)chunk * 4096 + ch) * 32 + n0;
    *(f32x4*)(o)      = *(f32x4*)&ap[0];
    *(f32x4*)(o + 4)  = *(f32x4*)&ap[4];
    *(f32x4*)(o + 16) = *(f32x4*)&s[0];
    *(f32x4*)(o + 20) = *(f32x4*)&s[4];
}

__global__ __launch_bounds__(256)
void scan_phase2(float* __restrict__ AS)
{
    const int idx = blockIdx.x * 256 + threadIdx.x;
    const int n   = idx & 15;
    const int ch  = idx >> 4;

    float s = 0.f;
    for (int cb = 0; cb < NCHUNK; cb += 16) {
        float av[16], sv[16];
        #pragma unroll
        for (int j = 0; j < 16; ++j) {
            size_t r = ((size_t)(cb + j) * 4096 + ch) * 32 + n;
            av[j] = AS[r];
            sv[j] = AS[r + 16];
        }
        #pragma unroll
        for (int j = 0; j < 16; ++j) {
            AS[((size_t)(cb + j) * 4096 + ch) * 32 + 16 + n] = s;
            s = av[j] * s + sv[j];
        }
    }
}

__global__ __launch_bounds__(256)
void scan_phase3(const bf16* __restrict__ delta, const bf16* __restrict__ u,
                 const float* __restrict__ xdbl, const bf16* __restrict__ xr,
                 const float* __restrict__ AS, const float* __restrict__ A_log,
                 const float* __restrict__ Dp, bf16* __restrict__ ybf)
{
    const int idx   = blockIdx.x * 256 + threadIdx.x;
    const int half  = idx & 1;
    const int ch    = idx >> 1;
    const int chunk = blockIdx.y;
    const int d     = ch & (DINNER - 1);
    const int b     = ch >> 11;
    const int n0    = half * 8;

    float A2[8], s[8];
    const f32x4* Arow = (const f32x4*)(A_log + d * DSTATE + n0);
    #pragma unroll
    for (int q = 0; q < 2; ++q) {
        f32x4 v = Arow[q];
        #pragma unroll
        for (int j = 0; j < 4; ++j) A2[q * 4 + j] = -__expf(v[j]) * LOG2E;
    }
    const float* ip = AS + ((size_t)chunk * 4096 + ch) * 32 + 16 + n0;
    *(f32x4*)&s[0] = *(const f32x4*)(ip);
    *(f32x4*)&s[4] = *(const f32x4*)(ip + 4);

    bool fastA = true;
    #pragma unroll
    for (int j = 0; j < 8; ++j)
        fastA &= fabsf(A2[j] + (float)(n0 + j + 1) * LOG2E)
                 < 0.01f * (float)(n0 + j + 1);

    const float Dd  = Dp[d];
    const long row0 = (long)b * L_SEQ + chunk * LCHUNK;

    const bf16*  pD = delta + row0 * DINNER + d;
    const bf16*  pU = u     + row0 * DINNER + d;
    const bf16*  pR = xr    + row0 * 4096 + 2048 + d;
    const f32x4* pB = (const f32x4*)(xdbl + row0 * 128 + 64 + n0);
    bf16*        pY = ybf   + row0 * DINNER + d;

    if (fastA) {
        #pragma unroll 4
        for (int l = 0; l < LCHUNK; ++l) {
            float dl = __bfloat162float(*pD);
            float uv = __bfloat162float(*pU);
            float rs = __bfloat162float(*pR);
            f32x4 B0 = pB[0], B1 = pB[1];
            f32x4 C0 = pB[4], C1 = pB[5];
            pD += DINNER; pU += DINNER; pR += 4096; pB += 32;
            float dbu = dl * uv;
            float b1 = __builtin_amdgcn_exp2f(-LOG2E * dl);   // exp(-dl)
            float b2 = b1 * b1, b3 = b2 * b1, b4 = b2 * b2;
            float b5 = b4 * b1, b6 = b4 * b2, b7 = b4 * b3, b8 = b4 * b4;
            float pre = half ? b8 : 1.f;
            float y0 = 0.f, y1 = 0.f;
            s[0] = pre * b1 * s[0] + dbu * B0[0];  y0 += s[0] * C0[0];
            s[1] = pre * b2 * s[1] + dbu * B0[1];  y0 += s[1] * C0[1];
            s[2] = pre * b3 * s[2] + dbu * B0[2];  y0 += s[2] * C0[2];
            s[3] = pre * b4 * s[3] + dbu * B0[3];  y0 += s[3] * C0[3];
            s[4] = pre * b5 * s[4] + dbu * B1[0];  y1 += s[4] * C1[0];
            s[5] = pre * b6 * s[5] + dbu * B1[1];  y1 += s[5] * C1[1];
            s[6] = pre * b7 * s[6] + dbu * B1[2];  y1 += s[6] * C1[2];
            s[7] = pre * b8 * s[7] + dbu * B1[3];  y1 += s[7] * C1[3];
            float yh = y0 + y1;
            float yt = yh + __shfl_xor(yh, 1);
            if (half == 0) {
                float yf = yt + uv * Dd;
                yf *= rs / (1.f + __builtin_amdgcn_exp2f(-LOG2E * rs));
                *pY = __float2bfloat16(yf);
            }
            pY += DINNER;
        }
    } else {
        #pragma unroll 4
        for (int l = 0; l < LCHUNK; ++l) {
            float dl = __bfloat162float(*pD);
            float uv = __bfloat162float(*pU);
            float rs = __bfloat162float(*pR);
            f32x4 B0 = pB[0], B1 = pB[1];
            f32x4 C0 = pB[4], C1 = pB[5];
            pD += DINNER; pU += DINNER; pR += 4096; pB += 32;
            float dbu = dl * uv;
            float y0 = 0.f, y1 = 0.f;
            #pragma unroll
            for (int j = 0; j < 4; ++j) {
                float e = __builtin_amdgcn_exp2f(dl * A2[j]);
                s[j] = e * s[j] + dbu * B0[j];
                y0 += s[j] * C0[j];
            }
            #pragma unroll
            for (int j = 0; j < 4; ++j) {
                float e = __builtin_amdgcn_exp2f(dl * A2[4 + j]);
                s[4 + j] = e * s[4 + j] + dbu * B1[j];
                y1 += s[4 + j] * C1[j];
            }
            float yh = y0 + y1;
            float yt = yh + __shfl_xor(yh, 1);
            if (half == 0) {
                float yf = yt + uv * Dd;
                yf *= rs / (1.f + __builtin_amdgcn_exp2f(-LOG2E * rs));
                *pY = __float2bfloat16(yf);
            }
            pY += DINNER;
        }
    }
}

// ---------------------------------------------------------------------------
extern "C" void kernel_launch(void* const* d_in, const int* in_sizes, int n_in,
                              void* d_out, int out_size, void* d_ws, size_t ws_size,
                              hipStream_t stream)
{
    const float* x      = (const float*)d_in[0];
    const float* W_in   = (const float*)d_in[1];
    const float* W_conv = (const float*)d_in[2];
    const float* b_conv = (const float*)d_in[3];
    const float* W_x    = (const float*)d_in[4];
    const float* W_dt   = (const float*)d_in[5];
    const float* b_dt   = (const float*)d_in[6];
    const float* A_log  = (const float*)d_in[7];
    const float* Dp     = (const float*)d_in[8];
    const float* W_out  = (const float*)d_in[9];
    float* out = (float*)d_out;

    char* ws = (char*)d_ws;
    size_t off = 0;
    auto alloc = [&](size_t bytes) {
        void* p = ws + off;
        off = (off + bytes + 255) & ~(size_t)255;
        return p;
    };
    bf16*  Xb    = (bf16*) alloc((size_t)MROWS * DMODEL * 2);
    bf16*  WinT  = (bf16*) alloc((size_t)4096  * DMODEL * 2);
    bf16*  xr    = (bf16*) alloc((size_t)MROWS * 4096  * 2);
    bf16*  ubf   = (bf16*) alloc((size_t)MROWS * DINNER * 2);
    bf16*  WxT   = (bf16*) alloc((size_t)128   * DINNER * 2);
    float* xdbl  = (float*)alloc((size_t)MROWS * 128 * 4);
    float* xdblp = (float*)alloc((size_t)4 * MROWS * 128 * 4);
    bf16*  drbf  = (bf16*) alloc((size_t)MROWS * 64 * 2);
    bf16*  WdtT  = (bf16*) alloc((size_t)DINNER * 64 * 2);
    bf16*  delta = (bf16*) alloc((size_t)MROWS * DINNER * 2);   // bf16
    bf16*  ybf   = (bf16*) alloc((size_t)MROWS * DINNER * 2);
    bf16*  WoutT = (bf16*) alloc((size_t)DMODEL * DINNER * 2);
    float* AS    = (float*)alloc((size_t)NCHUNK * 4096 * 32 * 4); // 32MB; reused
                                                                  // as GEMM4 partials

    // fused prep: 4 transposes + convert_x
    prep_kernel<<<6528 + (MROWS * DMODEL) / 256, 256, 0, stream>>>(
        W_in, WinT, W_x, WxT, W_dt, WdtT, W_out, WoutT, x, Xb);

    // GEMM1: x_and_res = Xb @ W_in -> xr bf16 (4096,4096) — 2-barrier deep pipe
    gemm256<<<dim3(4096 / 256, MROWS / 256), 512, 0, stream>>>(
        Xb, WinT, xr, 4096, 1024, 1024, 1024);
    // conv + silu -> u bf16 (vectorized, 8 ch/thread)
    conv_silu_kernel<<<(MROWS * DINNER / 8) / 256, 256, 0, stream>>>(
        xr, W_conv, b_conv, ubf);
    // GEMM2: x_dbl = u @ W_x, split-K x4 -> partials
    gemm_bt<float, 0, true><<<dim3(1, MROWS / 128, 4), 256, 0, stream>>>(
        ubf, WxT, xdblp, nullptr, MROWS, 128, 512, 2048, 2048);
    reduce_xdbl<<<(MROWS * 128) / 256, 256, 0, stream>>>(xdblp, xdbl, drbf);
    // GEMM3: delta = softplus(delta_r @ W_dt + b_dt) -> bf16
    gemm_bt<bf16, 1><<<dim3(DINNER / 128, MROWS / 128), 256, 0, stream>>>(
        drbf, WdtT, delta, b_dt, MROWS, DINNER, 64, 64, 64);
    // chunked parallel selective scan -> ybf bf16
    scan_phase1<<<dim3(32, NCHUNK), 256, 0, stream>>>(delta, ubf, xdbl, A_log, AS);
    scan_phase2<<<256, 256, 0, stream>>>(AS);
    scan_phase3<<<dim3(32, NCHUNK), 256, 0, stream>>>(delta, ubf, xdbl, xr, AS,
                                                      A_log, Dp, ybf);
    // GEMM4: out = y @ W_out, split-K x2 into AS (free after scan), then reduce
    gemm_bt<float, 0, true><<<dim3(DMODEL / 128, MROWS / 128, 2), 256, 0, stream>>>(
        ybf, WoutT, (float*)AS, nullptr, MROWS, DMODEL, 1024, 2048, 2048);
    reduce_out<<<(MROWS * DMODEL) / 1024, 256, 0, stream>>>((float*)AS, out);
}

// Round 16
// 248.052 us; speedup vs baseline: 1.2285x; 1.0206x over previous
//
#include <hip/hip_runtime.h>
#include <hip/hip_bf16.h>

#define L_SEQ  2048
#define NBATCH 2
#define DMODEL 1024
#define DINNER 2048
#define DSTATE 16
#define DTRANK 64
#define MROWS  (L_SEQ * NBATCH)   // 4096
#define NCHUNK 64
#define LCHUNK 32                 // L_SEQ / NCHUNK
#define LOG2E  1.44269504f

using bf16 = __hip_bfloat16;
typedef short s16x8 __attribute__((ext_vector_type(8)));   // 8 bf16 = 16B
typedef float f32x4 __attribute__((ext_vector_type(4)));

__device__ __forceinline__ void gload_lds16(const bf16* g, bf16* l) {
    __builtin_amdgcn_global_load_lds(
        (const __attribute__((address_space(1))) void*)g,
        (__attribute__((address_space(3))) void*)l, 16, 0, 0);
}

__device__ __forceinline__ float bf2f(short v) {
    return __uint_as_float(((unsigned)(unsigned short)v) << 16);
}

// ---------------------------------------------------------------------------
// 256x256 MFMA GEMM, 2-barrier deep pipeline (unchanged from round 15).
// ---------------------------------------------------------------------------
__global__ __launch_bounds__(512, 2)
void gemm256(const bf16* __restrict__ A, const bf16* __restrict__ Bt,
             bf16* __restrict__ C, int N, int K, int lda, int ldb)
{
    __shared__ __align__(16) bf16 As[2][256 * 64];
    __shared__ __align__(16) bf16 Bs[2][256 * 64];

    const int tid  = threadIdx.x;
    const int wid  = tid >> 6;
    const int lane = tid & 63;
    const int wr = wid >> 2, wc = wid & 3;       // 2x4 wave grid
    const int fr = lane & 15, fk = lane >> 4;

    // rect swizzle (grid is always 16x16 for GEMM1)
    const int orig = blockIdx.y * gridDim.x + blockIdx.x;
    const int xcd  = orig & 7, k = orig >> 3;    // k in [0,32)
    const int byi  = (xcd >> 1) * 4 + (k >> 3);  // 4-row band
    const int bxi  = (xcd & 1) * 8 + (k & 7);    // 8-col band
    const long bm = (long)byi * 256;
    const long bn = (long)bxi * 256;

    const int q0 = tid, q1 = tid + 512;
    const int r0 = q0 >> 3, r1 = q1 >> 3;
    const int c0 = ((q0 & 7) ^ (r0 & 7)) << 3;
    const int c1 = ((q1 & 7) ^ (r1 & 7)) << 3;
    const bf16* sA0h0 = A  + (bm + r0)       * (long)lda + c0;
    const bf16* sA1h0 = A  + (bm + r1)       * (long)lda + c1;
    const bf16* sA0h1 = A  + (bm + 128 + r0) * (long)lda + c0;
    const bf16* sA1h1 = A  + (bm + 128 + r1) * (long)lda + c1;
    const bf16* sB0h0 = Bt + (bn + r0)       * (long)ldb + c0;
    const bf16* sB1h0 = Bt + (bn + r1)       * (long)ldb + c1;
    const bf16* sB0h1 = Bt + (bn + 128 + r0) * (long)ldb + c0;
    const bf16* sB1h1 = Bt + (bn + 128 + r1) * (long)ldb + c1;
    const int dst0 = wid * 512;
    const int dst1 = 4096 + wid * 512;

    const int o0   = ((fk ^ (fr & 7)) << 3);
    const int o1   = o0 ^ 32;
    const int rA64 = (wr * 64 + fr) * 64;
    const int rB64 = (wc * 32 + fr) * 64;

    f32x4 acc[8][4] = {};
    s16x8 af[4][2], bf0[2][2], bf1[2][2];
    const int nt = K >> 6;

#define STAGE(ARR, BUF, H, P0, P1) do {                    \
        gload_lds16(P0, &ARR[BUF][(H) * 8192 + dst0]);     \
        gload_lds16(P1, &ARR[BUF][(H) * 8192 + dst1]);     \
        P0 += 64; P1 += 64;                                \
    } while (0)

#define LOADA(MH, CUR) do {                                   \
        const bf16* ab = &As[CUR][rA64 + (MH) * 8192];        \
        _Pragma("unroll") for (int m = 0; m < 4; ++m) {       \
            af[m][0] = *(const s16x8*)&ab[m * 1024 + o0];     \
            af[m][1] = *(const s16x8*)&ab[m * 1024 + o1]; }   \
    } while (0)

#define LOADB(NH, CUR, BF) do {                               \
        const bf16* bb = &Bs[CUR][rB64 + (NH) * 8192];        \
        _Pragma("unroll") for (int n = 0; n < 2; ++n) {       \
            BF[n][0] = *(const s16x8*)&bb[n * 1024 + o0];     \
            BF[n][1] = *(const s16x8*)&bb[n * 1024 + o1]; }   \
    } while (0)

#define MFMAQ(MH, NH, BF) do {                                               \
        __builtin_amdgcn_s_setprio(1);                                       \
        _Pragma("unroll") for (int ks = 0; ks < 2; ++ks)                     \
        _Pragma("unroll") for (int m = 0; m < 4; ++m)                        \
        _Pragma("unroll") for (int n = 0; n < 2; ++n)                        \
            acc[(MH) * 4 + m][(NH) * 2 + n] =                                \
                __builtin_amdgcn_mfma_f32_16x16x32_bf16(                     \
                    af[m][ks], BF[n][ks], acc[(MH) * 4 + m][(NH) * 2 + n],   \
                    0, 0, 0);                                                \
        __builtin_amdgcn_s_setprio(0);                                       \
    } while (0)

#define WB(NV) asm volatile("s_waitcnt vmcnt(" #NV ")\n\ts_barrier" ::: "memory")

    STAGE(As, 0, 0, sA0h0, sA1h0);
    STAGE(Bs, 0, 0, sB0h0, sB1h0);
    STAGE(Bs, 0, 1, sB0h1, sB1h1);
    STAGE(As, 0, 1, sA0h1, sA1h1);

    int cur = 0;
    for (int t = 0; t < nt; ++t) {
        WB(2);                               // A0,B0,B1 of t ready; A1 in flight
        LOADA(0, cur);
        LOADB(0, cur, bf0);
        LOADB(1, cur, bf1);
        if (t + 1 < nt) {
            STAGE(As, cur ^ 1, 0, sA0h0, sA1h0);
            STAGE(Bs, cur ^ 1, 0, sB0h0, sB1h0);
            STAGE(Bs, cur ^ 1, 1, sB0h1, sB1h1);
            STAGE(As, cur ^ 1, 1, sA0h1, sA1h1);
        }
        MFMAQ(0, 0, bf0);
        MFMAQ(0, 1, bf1);
        if (t + 1 < nt) WB(8); else WB(0);   // A1 of t ready
        LOADA(1, cur);
        MFMAQ(1, 1, bf1);
        MFMAQ(1, 0, bf0);
        cur ^= 1;
    }

#undef STAGE
#undef LOADA
#undef LOADB
#undef MFMAQ
#undef WB

    #pragma unroll
    for (int mh = 0; mh < 2; ++mh)
    #pragma unroll
    for (int m = 0; m < 4; ++m)
    #pragma unroll
    for (int nh = 0; nh < 2; ++nh)
    #pragma unroll
    for (int n = 0; n < 2; ++n) {
        f32x4 v = acc[mh * 4 + m][nh * 2 + n];
        long row0 = bm + wr * 64 + mh * 128 + m * 16 + fk * 4;
        long col  = bn + wc * 32 + nh * 128 + n * 16 + fr;
        #pragma unroll
        for (int j = 0; j < 4; ++j)
            C[(row0 + j) * N + col] = __float2bfloat16(v[j]);
    }
}

// ---------------------------------------------------------------------------
// MFMA bf16 GEMM: 128x128 tile, BK=32, 512 threads = 8 waves (4Mx2N; per-wave
// 32x64), COUNTED 2-deep pipeline. Ledger (2 loads/thread/tile): prologue
// stages t0,t1 (4 outstanding). Iter t: vmcnt(2)+bar releases exactly tile t
// (t+1 stays in flight) -> frag-read/MFMA -> lgkmcnt(0)+bar -> stage t+2.
// Last iter waits vmcnt(0). 8 waves = 2/SIMD even at 1 block/CU.
// ---------------------------------------------------------------------------
template<typename OutT, int EPI, bool SPLITK = false>
__global__ __launch_bounds__(512)
void gemm_bt(const bf16* __restrict__ A, const bf16* __restrict__ Bt,
             OutT* __restrict__ C, const float* __restrict__ bias,
             int M, int N, int K, int lda, int ldb)
{
    __shared__ __align__(16) bf16 As[2][128 * 32];
    __shared__ __align__(16) bf16 Bs[2][128 * 32];

    const int tid  = threadIdx.x;          // 0..511
    const int wid  = tid >> 6;             // 0..7
    const int lane = tid & 63;
    const int wr = wid >> 1, wc = wid & 1; // 4x2 wave grid, per-wave 32x64
    const int fr = lane & 15, fk = lane >> 4;

    const int nbx = gridDim.x;
    const int nwg = nbx * gridDim.y;
    int id  = blockIdx.y * nbx + blockIdx.x;
    if (nwg >= 8) {
        int cpx = nwg >> 3;
        id = (id & 7) * cpx + (id >> 3);
    }
    const int bxi = id % nbx, byi = id / nbx;
    const long bm = (long)byi * 128;
    const long bn = (long)bxi * 128;

    if constexpr (SPLITK) {
        long ko = (long)blockIdx.z * K;
        A  += ko;
        Bt += ko;
        C  += (size_t)blockIdx.z * M * N;
    }

    // staging: thread q loads A chunk q and B chunk q (row q>>2, col (q&3)*8)
    const int r0 = tid >> 2, c0 = (tid & 3) << 3;
    const bf16* pA = A  + (bm + r0) * (long)lda + c0;
    const bf16* pB = Bt + (bn + r0) * (long)ldb + c0;
    const size_t ld = (size_t)wid * 512;   // elements; lanes append 16B each

    f32x4 acc[2][4] = {};
    const int nt = K >> 5;

#define STG(BUF) do {                             \
        gload_lds16(pA, &As[BUF][ld]);            \
        gload_lds16(pB, &Bs[BUF][ld]);            \
        pA += 32; pB += 32;                       \
    } while (0)

    STG(0);                       // tile 0: 2 in flight
    if (nt > 1) STG(1);           // tile 1: 4 in flight

    int cur = 0;
    for (int t = 0; t < nt; ++t) {
        if (t + 1 < nt)
            asm volatile("s_waitcnt vmcnt(2)\n\ts_barrier" ::: "memory");
        else
            asm volatile("s_waitcnt vmcnt(0)\n\ts_barrier" ::: "memory");

        s16x8 afrag[2], bfrag[4];
        #pragma unroll
        for (int m = 0; m < 2; ++m)
            afrag[m] = *(const s16x8*)&As[cur][(wr * 32 + m * 16 + fr) * 32 + fk * 8];
        #pragma unroll
        for (int n = 0; n < 4; ++n)
            bfrag[n] = *(const s16x8*)&Bs[cur][(wc * 64 + n * 16 + fr) * 32 + fk * 8];

        #pragma unroll
        for (int m = 0; m < 2; ++m)
            #pragma unroll
            for (int n = 0; n < 4; ++n)
                acc[m][n] = __builtin_amdgcn_mfma_f32_16x16x32_bf16(
                    afrag[m], bfrag[n], acc[m][n], 0, 0, 0);

        if (t + 2 < nt) {
            asm volatile("s_waitcnt lgkmcnt(0)\n\ts_barrier" ::: "memory");
            STG(cur);             // stage tile t+2 into the freed buffer
        }
        cur ^= 1;
    }
#undef STG

    #pragma unroll
    for (int m = 0; m < 2; ++m)
        #pragma unroll
        for (int n = 0; n < 4; ++n) {
            f32x4 v = acc[m][n];
            long row0 = bm + wr * 32 + m * 16 + fk * 4;
            long col  = bn + wc * 64 + n * 16 + fr;
            #pragma unroll
            for (int j = 0; j < 4; ++j) {
                float val = v[j];
                if (EPI == 1) {
                    val += bias[col];
                    val = (val > 20.f) ? val : log1pf(__expf(val));
                }
                if constexpr (sizeof(OutT) == 2)
                    C[(row0 + j) * N + col] = __float2bfloat16(val);
                else
                    C[(row0 + j) * N + col] = val;
            }
        }
}

// ---------------------------------------------------------------------------
// Fused preprocessing: 4 weight transposes + convert_x in ONE kernel
// ---------------------------------------------------------------------------
__device__ __forceinline__ void do_transpose(
    const float* __restrict__ in, bf16* __restrict__ out,
    int R, int C, int Cpad, int bx, int by, int tx, int ty)
{
    __shared__ float tile[32][33];
    int cb = bx * 32, rb = by * 32;
    #pragma unroll
    for (int i = 0; i < 4; ++i) {
        int r = rb + ty + i * 8, c = cb + tx;
        tile[ty + i * 8][tx] = (r < R && c < C) ? in[(long)r * C + c] : 0.f;
    }
    __syncthreads();
    #pragma unroll
    for (int i = 0; i < 4; ++i) {
        int oc = cb + ty + i * 8;
        int orow = rb + tx;
        if (oc < Cpad && orow < R)
            out[(long)oc * R + orow] = __float2bfloat16(tile[tx][ty + i * 8]);
    }
}

__global__ __launch_bounds__(256)
void prep_kernel(const float* __restrict__ W_in,  bf16* __restrict__ WinT,
                 const float* __restrict__ W_x,   bf16* __restrict__ WxT,
                 const float* __restrict__ W_dt,  bf16* __restrict__ WdtT,
                 const float* __restrict__ W_out, bf16* __restrict__ WoutT,
                 const float* __restrict__ x,     bf16* __restrict__ Xb)
{
    const int b  = blockIdx.x;
    const int t  = threadIdx.x;
    const int tx = t & 31, ty = t >> 5;

    if (b < 4096) {                       // W_in (1024,4096) -> (4096,1024)
        do_transpose(W_in, WinT, 1024, 4096, 4096, b & 127, b >> 7, tx, ty);
    } else if (b < 4352) {                // W_x (2048,96) -> (128,2048)
        int b2 = b - 4096;
        do_transpose(W_x, WxT, 2048, 96, 128, b2 & 3, b2 >> 2, tx, ty);
    } else if (b < 4480) {                // W_dt (64,2048) -> (2048,64)
        int b3 = b - 4352;
        do_transpose(W_dt, WdtT, 64, 2048, 2048, b3 & 63, b3 >> 6, tx, ty);
    } else if (b < 6528) {                // W_out (2048,1024) -> (1024,2048)
        int b4 = b - 4480;
        do_transpose(W_out, WoutT, 2048, 1024, 1024, b4 & 31, b4 >> 5, tx, ty);
    } else {                              // x (L,B,DM) -> Xb (B*L,DM) bf16
        int idx = (b - 6528) * 256 + t;
        int c   = idx & (DMODEL - 1);
        int row = idx >> 10;
        int l   = row & (L_SEQ - 1);
        int bb  = row >> 11;
        Xb[idx] = __float2bfloat16(x[((l * NBATCH + bb) << 10) | c]);
    }
}

// depthwise causal conv (d_conv=4) + silu, 8 channels per thread (vectorized)
__global__ void conv_silu_kernel(const bf16* __restrict__ xr, const float* __restrict__ Wc,
                                 const float* __restrict__ bc, bf16* __restrict__ u)
{
    int idx = blockIdx.x * 256 + threadIdx.x;   // MROWS*DINNER/8 threads
    int g   = idx & 255;
    int row = idx >> 8;
    int c   = g << 3;
    int l   = row & (L_SEQ - 1);

    float acc[8];
    f32x4 bi0 = *(const f32x4*)(bc + c);
    f32x4 bi1 = *(const f32x4*)(bc + c + 4);
    #pragma unroll
    for (int j = 0; j < 4; ++j) { acc[j] = bi0[j]; acc[4 + j] = bi1[j]; }

    f32x4 w[8];
    #pragma unroll
    for (int j = 0; j < 8; ++j) w[j] = *(const f32x4*)(Wc + (c + j) * 4);

    #pragma unroll
    for (int t = 0; t < 4; ++t) {
        int ll = l - 3 + t;
        if (ll >= 0) {
            s16x8 v = *(const s16x8*)(xr + (long)(row - 3 + t) * 4096 + c);
            #pragma unroll
            for (int j = 0; j < 8; ++j)
                acc[j] += bf2f(v[j]) * w[j][t];
        }
    }
    s16x8 o;
    #pragma unroll
    for (int j = 0; j < 8; ++j) {
        float a = acc[j];
        float s = a / (1.f + __builtin_amdgcn_exp2f(-LOG2E * a));
        bf16 h = __float2bfloat16(s);
        o[j] = *(short*)&h;
    }
    *(s16x8*)(u + (long)row * DINNER + c) = o;
}

// sum 8 split-K partials -> xdbl fp32; also emit drbf (cols 0..63 as bf16)
__global__ void reduce_xdbl(const float* __restrict__ part, float* __restrict__ xdbl,
                            bf16* __restrict__ drbf)
{
    int idx = blockIdx.x * 256 + threadIdx.x;
    const size_t stride = (size_t)MROWS * 128;
    float v = 0.f;
    #pragma unroll
    for (int z = 0; z < 8; ++z)
        v += part[idx + z * stride];
    xdbl[idx] = v;
    int col = idx & 127;
    if (col < 64)
        drbf[(idx >> 7) * 64 + col] = __float2bfloat16(v);
}

// ---------------------------------------------------------------------------
// Chunked parallel selective scan — round-9 form (frozen). delta bf16.
// FAST PATH (runtime-checked): A[d][n] = -(n+1) => powers of exp(-dl).
// ---------------------------------------------------------------------------
__global__ __launch_bounds__(256)
void scan_phase1(const bf16* __restrict__ delta, const bf16* __restrict__ u,
                 const float* __restrict__ xdbl, const float* __restrict__ A_log,
                 float* __restrict__ AS)
{
    const int idx   = blockIdx.x * 256 + threadIdx.x;
    const int half  = idx & 1;
    const int ch    = idx >> 1;
    const int chunk = blockIdx.y;
    const int d     = ch & (DINNER - 1);
    const int b     = ch >> 11;
    const int n0    = half * 8;

    float A2[8], s[8];
    const f32x4* Arow = (const f32x4*)(A_log + d * DSTATE + n0);
    #pragma unroll
    for (int q = 0; q < 2; ++q) {
        f32x4 v = Arow[q];
        #pragma unroll
        for (int j = 0; j < 4; ++j) A2[q * 4 + j] = -__expf(v[j]) * LOG2E;
    }
    #pragma unroll
    for (int n = 0; n < 8; ++n) s[n] = 0.f;
    float sdl = 0.f;

    bool fastA = true;
    #pragma unroll
    for (int j = 0; j < 8; ++j)
        fastA &= fabsf(A2[j] + (float)(n0 + j + 1) * LOG2E)
                 < 0.01f * (float)(n0 + j + 1);

    const long row0 = (long)b * L_SEQ + chunk * LCHUNK;
    const bf16*  pD = delta + row0 * DINNER + d;
    const bf16*  pU = u     + row0 * DINNER + d;
    const f32x4* pB = (const f32x4*)(xdbl + row0 * 128 + 64 + n0);

    if (fastA) {
        #pragma unroll 4
        for (int l = 0; l < LCHUNK; ++l) {
            float dl = __bfloat162float(*pD);
            float uv = __bfloat162float(*pU);
            f32x4 B0 = pB[0], B1 = pB[1];
            pD += DINNER; pU += DINNER; pB += 32;
            float dbu = dl * uv;
            sdl += dl;
            float b1 = __builtin_amdgcn_exp2f(-LOG2E * dl);   // exp(-dl)
            float b2 = b1 * b1, b3 = b2 * b1, b4 = b2 * b2;
            float b5 = b4 * b1, b6 = b4 * b2, b7 = b4 * b3, b8 = b4 * b4;
            float pre = half ? b8 : 1.f;
            s[0] = pre * b1 * s[0] + dbu * B0[0];
            s[1] = pre * b2 * s[1] + dbu * B0[1];
            s[2] = pre * b3 * s[2] + dbu * B0[2];
            s[3] = pre * b4 * s[3] + dbu * B0[3];
            s[4] = pre * b5 * s[4] + dbu * B1[0];
            s[5] = pre * b6 * s[5] + dbu * B1[1];
            s[6] = pre * b7 * s[6] + dbu * B1[2];
            s[7] = pre * b8 * s[7] + dbu * B1[3];
        }
    } else {
        #pragma unroll 4
        for (int l = 0; l < LCHUNK; ++l) {
            float dl = __bfloat162float(*pD);
            float uv = __bfloat162float(*pU);
            f32x4 B0 = pB[0], B1 = pB[1];
            pD += DINNER; pU += DINNER; pB += 32;
            float dbu = dl * uv;
            sdl += dl;
            #pragma unroll
            for (int j = 0; j < 4; ++j) {
                float e = __builtin_amdgcn_exp2f(dl * A2[j]);
                s[j] = e * s[j] + dbu * B0[j];
            }
            #pragma unroll
            for (int j = 0; j < 4; ++j) {
                float e = __builtin_amdgcn_exp2f(dl * A2[4 + j]);
                s[4 + j] = e * s[4 + j] + dbu * B1[j];
            }
        }
    }
    float ap[8];
    #pragma unroll
    for (int n = 0; n < 8; ++n) ap[n] = __builtin_amdgcn_exp2f(sdl * A2[n]);

    float* o = AS + ((size_t)chunk * 4096 + ch) * 32 + n0;
    *(f32x4*)(o)      = *(f32x4*)&ap[0];
    *(f32x4*)(o + 4)  = *(f32x4*)&ap[4];
    *(f32x4*)(o + 16) = *(f32x4*)&s[0];
    *(f32x4*)(o + 20) = *(f32x4*)&s[4];
}

__global__ __launch_bounds__(256)
void scan_phase2(float* __restrict__ AS)
{
    const int idx = blockIdx.x * 256 + threadIdx.x;
    const int n   = idx & 15;
    const int ch  = idx >> 4;

    float s = 0.f;
    for (int cb = 0; cb < NCHUNK; cb += 16) {
        float av[16], sv[16];
        #pragma unroll
        for (int j = 0; j < 16; ++j) {
            size_t r = ((size_t)(cb + j) * 4096 + ch) * 32 + n;
            av[j] = AS[r];
            sv[j] = AS[r + 16];
        }
        #pragma unroll
        for (int j = 0; j < 16; ++j) {
            AS[((size_t)(cb + j) * 4096 + ch) * 32 + 16 + n] = s;
            s = av[j] * s + sv[j];
        }
    }
}

__global__ __launch_bounds__(256)
void scan_phase3(const bf16* __restrict__ delta, const bf16* __restrict__ u,
                 const float* __restrict__ xdbl, const bf16* __restrict__ xr,
                 const float* __restrict__ AS, const float* __restrict__ A_log,
                 const float* __restrict__ Dp, bf16* __restrict__ ybf)
{
    const int idx   = blockIdx.x * 256 + threadIdx.x;
    const int half  = idx & 1;
    const int ch    = idx >> 1;
    const int chunk = blockIdx.y;
    const int d     = ch & (DINNER - 1);
    const int b     = ch >> 11;
    const int n0    = half * 8;

    float A2[8], s[8];
    const f32x4* Arow = (const f32x4*)(A_log + d * DSTATE + n0);
    #pragma unroll
    for (int q = 0; q < 2; ++q) {
        f32x4 v = Arow[q];
        #pragma unroll
        for (int j = 0; j < 4; ++j) A2[q * 4 + j] = -__expf(v[j]) * LOG2E;
    }
    const float* ip = AS + ((size_t)chunk * 4096 + ch) * 32 + 16 + n0;
    *(f32x4*)&s[0] = *(const f32x4*)(ip);
    *(f32x4*)&s[4] = *(const f32x4*)(ip + 4);

    bool fastA = true;
    #pragma unroll
    for (int j = 0; j < 8; ++j)
        fastA &= fabsf(A2[j] + (float)(n0 + j + 1) * LOG2E)
                 < 0.01f * (float)(n0 + j + 1);

    const float Dd  = Dp[d];
    const long row0 = (long)b * L_SEQ + chunk * LCHUNK;

    const bf16*  pD = delta + row0 * DINNER + d;
    const bf16*  pU = u     + row0 * DINNER + d;
    const bf16*  pR = xr    + row0 * 4096 + 2048 + d;
    const f32x4* pB = (const f32x4*)(xdbl + row0 * 128 + 64 + n0);
    bf16*        pY = ybf   + row0 * DINNER + d;

    if (fastA) {
        #pragma unroll 4
        for (int l = 0; l < LCHUNK; ++l) {
            float dl = __bfloat162float(*pD);
            float uv = __bfloat162float(*pU);
            float rs = __bfloat162float(*pR);
            f32x4 B0 = pB[0], B1 = pB[1];
            f32x4 C0 = pB[4], C1 = pB[5];
            pD += DINNER; pU += DINNER; pR += 4096; pB += 32;
            float dbu = dl * uv;
            float b1 = __builtin_amdgcn_exp2f(-LOG2E * dl);   // exp(-dl)
            float b2 = b1 * b1, b3 = b2 * b1, b4 = b2 * b2;
            float b5 = b4 * b1, b6 = b4 * b2, b7 = b4 * b3, b8 = b4 * b4;
            float pre = half ? b8 : 1.f;
            float y0 = 0.f, y1 = 0.f;
            s[0] = pre * b1 * s[0] + dbu * B0[0];  y0 += s[0] * C0[0];
            s[1] = pre * b2 * s[1] + dbu * B0[1];  y0 += s[1] * C0[1];
            s[2] = pre * b3 * s[2] + dbu * B0[2];  y0 += s[2] * C0[2];
            s[3] = pre * b4 * s[3] + dbu * B0[3];  y0 += s[3] * C0[3];
            s[4] = pre * b5 * s[4] + dbu * B1[0];  y1 += s[4] * C1[0];
            s[5] = pre * b6 * s[5] + dbu * B1[1];  y1 += s[5] * C1[1];
            s[6] = pre * b7 * s[6] + dbu * B1[2];  y1 += s[6] * C1[2];
            s[7] = pre * b8 * s[7] + dbu * B1[3];  y1 += s[7] * C1[3];
            float yh = y0 + y1;
            float yt = yh + __shfl_xor(yh, 1);
            if (half == 0) {
                float yf = yt + uv * Dd;
                yf *= rs / (1.f + __builtin_amdgcn_exp2f(-LOG2E * rs));
                *pY = __float2bfloat16(yf);
            }
            pY += DINNER;
        }
    } else {
        #pragma unroll 4
        for (int l = 0; l < LCHUNK; ++l) {
            float dl = __bfloat162float(*pD);
            float uv = __bfloat162float(*pU);
            float rs = __bfloat162float(*pR);
            f32x4 B0 = pB[0], B1 = pB[1];
            f32x4 C0 = pB[4], C1 = pB[5];
            pD += DINNER; pU += DINNER; pR += 4096; pB += 32;
            float dbu = dl * uv;
            float y0 = 0.f, y1 = 0.f;
            #pragma unroll
            for (int j = 0; j < 4; ++j) {
                float e = __builtin_amdgcn_exp2f(dl * A2[j]);
                s[j] = e * s[j] + dbu * B0[j];
                y0 += s[j] * C0[j];
            }
            #pragma unroll
            for (int j = 0; j < 4; ++j) {
                float e = __builtin_amdgcn_exp2f(dl * A2[4 + j]);
                s[4 + j] = e * s[4 + j] + dbu * B1[j];
                y1 += s[4 + j] * C1[j];
            }
            float yh = y0 + y1;
            float yt = yh + __shfl_xor(yh, 1);
            if (half == 0) {
                float yf = yt + uv * Dd;
                yf *= rs / (1.f + __builtin_amdgcn_exp2f(-LOG2E * rs));
                *pY = __float2bfloat16(yf);
            }
            pY += DINNER;
        }
    }
}

// ---------------------------------------------------------------------------
extern "C" void kernel_launch(void* const* d_in, const int* in_sizes, int n_in,
                              void* d_out, int out_size, void* d_ws, size_t ws_size,
                              hipStream_t stream)
{
    const float* x      = (const float*)d_in[0];
    const float* W_in   = (const float*)d_in[1];
    const float* W_conv = (const float*)d_in[2];
    const float* b_conv = (const float*)d_in[3];
    const float* W_x    = (const float*)d_in[4];
    const float* W_dt   = (const float*)d_in[5];
    const float* b_dt   = (const float*)d_in[6];
    const float* A_log  = (const float*)d_in[7];
    const float* Dp     = (const float*)d_in[8];
    const float* W_out  = (const float*)d_in[9];
    float* out = (float*)d_out;

    char* ws = (char*)d_ws;
    size_t off = 0;
    auto alloc = [&](size_t bytes) {
        void* p = ws + off;
        off = (off + bytes + 255) & ~(size_t)255;
        return p;
    };
    bf16*  Xb    = (bf16*) alloc((size_t)MROWS * DMODEL * 2);
    bf16*  WinT  = (bf16*) alloc((size_t)4096  * DMODEL * 2);
    bf16*  xr    = (bf16*) alloc((size_t)MROWS * 4096  * 2);
    bf16*  ubf   = (bf16*) alloc((size_t)MROWS * DINNER * 2);
    bf16*  WxT   = (bf16*) alloc((size_t)128   * DINNER * 2);
    float* xdbl  = (float*)alloc((size_t)MROWS * 128 * 4);
    float* xdblp = (float*)alloc((size_t)8 * MROWS * 128 * 4);  // 8 split-K slices
    bf16*  drbf  = (bf16*) alloc((size_t)MROWS * 64 * 2);
    bf16*  WdtT  = (bf16*) alloc((size_t)DINNER * 64 * 2);
    bf16*  delta = (bf16*) alloc((size_t)MROWS * DINNER * 2);   // bf16
    bf16*  ybf   = (bf16*) alloc((size_t)MROWS * DINNER * 2);
    bf16*  WoutT = (bf16*) alloc((size_t)DMODEL * DINNER * 2);
    float* AS    = (float*)alloc((size_t)NCHUNK * 4096 * 32 * 4); // 32MB scan state

    // fused prep: 4 transposes + convert_x
    prep_kernel<<<6528 + (MROWS * DMODEL) / 256, 256, 0, stream>>>(
        W_in, WinT, W_x, WxT, W_dt, WdtT, W_out, WoutT, x, Xb);

    // GEMM1: x_and_res = Xb @ W_in -> xr bf16 (4096,4096) — 2-barrier deep pipe
    gemm256<<<dim3(4096 / 256, MROWS / 256), 512, 0, stream>>>(
        Xb, WinT, xr, 4096, 1024, 1024, 1024);
    // conv + silu -> u bf16 (vectorized, 8 ch/thread)
    conv_silu_kernel<<<(MROWS * DINNER / 8) / 256, 256, 0, stream>>>(
        xr, W_conv, b_conv, ubf);
    // GEMM2: x_dbl = u @ W_x, split-K x8 (256 blocks) -> partials
    gemm_bt<float, 0, true><<<dim3(1, MROWS / 128, 8), 512, 0, stream>>>(
        ubf, WxT, xdblp, nullptr, MROWS, 128, 256, 2048, 2048);
    reduce_xdbl<<<(MROWS * 128) / 256, 256, 0, stream>>>(xdblp, xdbl, drbf);
    // GEMM3: delta = softplus(delta_r @ W_dt + b_dt) -> bf16
    gemm_bt<bf16, 1><<<dim3(DINNER / 128, MROWS / 128), 512, 0, stream>>>(
        drbf, WdtT, delta, b_dt, MROWS, DINNER, 64, 64, 64);
    // chunked parallel selective scan -> ybf bf16
    scan_phase1<<<dim3(32, NCHUNK), 256, 0, stream>>>(delta, ubf, xdbl, A_log, AS);
    scan_phase2<<<256, 256, 0, stream>>>(AS);
    scan_phase3<<<dim3(32, NCHUNK), 256, 0, stream>>>(delta, ubf, xdbl, xr, AS,
                                                      A_log, Dp, ybf);
    // GEMM4: out = y @ W_out -> fp32 d_out, DIRECT (no split-K, no reduce)
    gemm_bt<float, 0><<<dim3(DMODEL / 128, MROWS / 128), 512, 0, stream>>>(
        ybf, WoutT, out, nullptr, MROWS, DMODEL, 2048, 2048, 2048);
}